// Round 10
// baseline (374.343 us; speedup 1.0000x reference)
//
#include <hip/hip_runtime.h>
#include <cstdint>
#include <cstddef>

#define NN 50000
#define NE 800000
#define GB 196        // coarse buckets = ceil(NN/256)
#define TILE1 4096    // edges per part1 block
#define CAP 8192      // max edges per bucket in part2 LDS (mean 4082)

typedef __attribute__((ext_vector_type(8))) short short8;
typedef __attribute__((ext_vector_type(4))) float floatx4;

__device__ __forceinline__ float lrelu_f(float x){ return x >= 0.f ? x : 0.2f*x; }
__device__ __forceinline__ float elu_f(float x){ return x > 0.f ? x : __expf(x) - 1.f; }

__device__ __forceinline__ unsigned short f2bf(float f){
  unsigned int u = __float_as_uint(f);
  u += 0x7FFFu + ((u >> 16) & 1u);
  return (unsigned short)(u >> 16);
}
__device__ __forceinline__ float bf2f(unsigned int us){
  return __uint_as_float(us << 16);
}
__device__ __forceinline__ float4 bf4_load(const unsigned short* p){
  uint2 q = *(const uint2*)p;
  return make_float4(bf2f(q.x & 0xffffu), bf2f(q.x >> 16),
                     bf2f(q.y & 0xffffu), bf2f(q.y >> 16));
}
__device__ __forceinline__ uint2 bf4_pack(float4 o){
  uint2 p;
  p.x = (unsigned)f2bf(o.x) | ((unsigned)f2bf(o.y) << 16);
  p.y = (unsigned)f2bf(o.z) | ((unsigned)f2bf(o.w) << 16);
  return p;
}
__device__ __forceinline__ void split_bf(float a, unsigned short& h, unsigned short& l){
  h = f2bf(a);
  l = f2bf(a - bf2f(h));
}

// v_dot2_f32_bf16: acc += a.bf16[0]*b.bf16[0] + a.bf16[1]*b.bf16[1]
__device__ __forceinline__ float dot2bf(float acc, unsigned a, unsigned b){
  asm("v_dot2_f32_bf16 %0, %1, %2, %0" : "+v"(acc) : "v"(a), "v"(b));
  return acc;
}

// process one edge PAIR (bf16 operands stay packed; sums stay within-lane)
__device__ __forceinline__ void agg_pair(float (&acc)[4][8], float (&den)[4],
                                         uint4 q0, uint4 q1, uint2 w0, uint2 w1){
  const unsigned ONE2 = 0x3F803F80u;  // packed bf16 (1.0, 1.0)
  unsigned wp[4];
  wp[0] = __builtin_amdgcn_perm(w1.x, w0.x, 0x05040100u);
  wp[1] = __builtin_amdgcn_perm(w1.x, w0.x, 0x07060302u);
  wp[2] = __builtin_amdgcn_perm(w1.y, w0.y, 0x05040100u);
  wp[3] = __builtin_amdgcn_perm(w1.y, w0.y, 0x07060302u);
  unsigned xp[8];
  xp[0] = __builtin_amdgcn_perm(q1.x, q0.x, 0x05040100u);
  xp[1] = __builtin_amdgcn_perm(q1.x, q0.x, 0x07060302u);
  xp[2] = __builtin_amdgcn_perm(q1.y, q0.y, 0x05040100u);
  xp[3] = __builtin_amdgcn_perm(q1.y, q0.y, 0x07060302u);
  xp[4] = __builtin_amdgcn_perm(q1.z, q0.z, 0x05040100u);
  xp[5] = __builtin_amdgcn_perm(q1.z, q0.z, 0x07060302u);
  xp[6] = __builtin_amdgcn_perm(q1.w, q0.w, 0x05040100u);
  xp[7] = __builtin_amdgcn_perm(q1.w, q0.w, 0x07060302u);
  #pragma unroll
  for (int h=0;h<4;h++){
    den[h] = dot2bf(den[h], wp[h], ONE2);
    #pragma unroll
    for (int c=0;c<8;c++) acc[h][c] = dot2bf(acc[h][c], wp[h], xp[c]);
  }
}

// ---------------- two-level bucket sort of edges by dst ----------------
__global__ __launch_bounds__(256) void ghist_kernel(const int* __restrict__ e0,
                                                    const int* __restrict__ e1,
                                                    int* __restrict__ ghist){
  const int ty = blockIdx.y;
  const int* e = ty ? e1 : e0;
  __shared__ int h[GB];
  for (int j=threadIdx.x; j<GB; j+=256) h[j]=0;
  __syncthreads();
  for (int i = blockIdx.x*256 + threadIdx.x; i < NE; i += 256*256)
    atomicAdd(&h[e[NE+i]>>8], 1);
  __syncthreads();
  for (int j=threadIdx.x; j<GB; j+=256) if (h[j]) atomicAdd(&ghist[ty*200+j], h[j]);
}

__global__ __launch_bounds__(256) void gscan_kernel(const int* __restrict__ ghist,
                                                    int* __restrict__ gbase,
                                                    int* __restrict__ gcur){
  __shared__ int wb[4];
  const int t = threadIdx.x, wv = t>>6, l = t&63;
  for (int ty=0; ty<2; ++ty){
    int v = (t < GB) ? ghist[ty*200+t] : 0;
    int sum = v;
    #pragma unroll
    for (int off=1; off<64; off<<=1){
      int x = __shfl_up(sum, off, 64);
      if (l >= off) sum += x;
    }
    if (l == 63) wb[wv] = sum;
    __syncthreads();
    int wbase = 0;
    #pragma unroll
    for (int w=0; w<4; ++w) if (w < wv) wbase += wb[w];
    int excl = wbase + sum - v;
    if (t <= GB) gbase[ty*200+t] = excl;
    if (t <  GB) gcur [ty*200+t] = excl;
    __syncthreads();
  }
}

// partition with LDS staging: global writes are contiguous per-bucket runs
__global__ __launch_bounds__(256) void part1_kernel(const int* __restrict__ e0,
                                                    const int* __restrict__ e1,
                                                    int* __restrict__ gcur,
                                                    int2* __restrict__ p0,
                                                    int2* __restrict__ p1){
  const int ty = blockIdx.y;
  const int* e = ty ? e1 : e0;
  int2* pairs = ty ? p1 : p0;
  __shared__ int cnt[256];
  __shared__ int lstart[256];
  __shared__ int lcur[256];
  __shared__ int curg[GB];
  __shared__ int lsrc[TILE1];
  __shared__ int ldst[TILE1];
  __shared__ int wb[4];
  const int t = threadIdx.x;
  cnt[t] = 0;
  __syncthreads();
  int dreg[16], sreg[16];
  const int base = blockIdx.x*TILE1;
  const int ntile = min(TILE1, NE - base);
  #pragma unroll
  for (int it=0; it<16; ++it){
    int i = base + it*256 + t;
    int d = -1, s = 0;
    if (i < NE){ d = e[NE+i]; s = e[i]; atomicAdd(&cnt[d>>8], 1); }
    dreg[it] = d; sreg[it] = s;
  }
  __syncthreads();
  int c = cnt[t], sum = c;
  #pragma unroll
  for (int off=1; off<64; off<<=1){
    int x = __shfl_up(sum, off, 64);
    if ((t&63) >= off) sum += x;
  }
  if ((t&63) == 63) wb[t>>6] = sum;
  __syncthreads();
  int wbase = 0;
  #pragma unroll
  for (int w=0; w<4; ++w) if (w < (t>>6)) wbase += wb[w];
  int excl = wbase + sum - c;
  lstart[t] = excl;
  lcur[t] = excl;
  if (t < GB && c > 0) curg[t] = atomicAdd(&gcur[ty*200+t], c);
  __syncthreads();
  #pragma unroll
  for (int it=0; it<16; ++it){
    int d = dreg[it];
    if (d >= 0){
      int pos = atomicAdd(&lcur[d>>8], 1);
      lsrc[pos] = sreg[it];
      ldst[pos] = d;
    }
  }
  __syncthreads();
  for (int i=t; i<ntile; i+=256){
    int d = ldst[i];
    int j = d>>8;
    pairs[curg[j] + (i - lstart[j])] = make_int2(lsrc[i], d);
  }
}

// per-bucket LDS bin by dst + CSR offsets + fused layer-0 softmax weights (bf16).
struct Part2Job {
  const int2* pairs; const int* gbase;
  const float* als; const float* ald;   // [NN,4]
  int* ssrc; int* offs; unsigned short* coef;  // coef: [E,4] bf16
};
__global__ __launch_bounds__(256) void part2_kernel(Part2Job j0, Part2Job j1){
  const Part2Job jb = blockIdx.y ? j1 : j0;
  const int b = blockIdx.x;
  const int t = threadIdx.x;
  __shared__ int lcnt[256];
  __shared__ int lcur[256];
  __shared__ int wb[4];
  __shared__ int sorted_src[CAP];
  __shared__ unsigned char sorted_dl[CAP];
  const int gb0 = jb.gbase[b], gb1 = jb.gbase[b+1];
  const int n = gb1 - gb0;
  lcnt[t] = 0;
  __syncthreads();
  for (int i=t; i<n; i+=256)
    atomicAdd(&lcnt[jb.pairs[gb0+i].y - (b<<8)], 1);
  __syncthreads();
  int c = lcnt[t], sum = c;
  #pragma unroll
  for (int off=1; off<64; off<<=1){
    int x = __shfl_up(sum, off, 64);
    if ((t&63) >= off) sum += x;
  }
  if ((t&63) == 63) wb[t>>6] = sum;
  __syncthreads();
  int wbase = 0;
  #pragma unroll
  for (int w=0; w<4; ++w) if (w < (t>>6)) wbase += wb[w];
  int excl = wbase + sum - c;
  lcur[t] = excl;
  int g = (b<<8) + t;
  if (g <= NN) jb.offs[g] = gb0 + excl;
  __syncthreads();
  for (int i=t; i<n; i+=256){
    int2 pr = jb.pairs[gb0+i];
    int dl = pr.y - (b<<8);
    int pos = atomicAdd(&lcur[dl], 1);
    sorted_src[pos] = pr.x;
    sorted_dl[pos] = (unsigned char)dl;
  }
  __syncthreads();
  const float4* als4 = (const float4*)jb.als;
  const float4* ald4 = (const float4*)jb.ald;
  for (int i=t; i<n; i+=256){
    int s  = sorted_src[i];
    int dl = sorted_dl[i];
    float4 a  = als4[s];
    float4 ad = ald4[(b<<8)+dl];
    // no max-shift: |alpha| small at this model scale; softmax shift-invariant.
    float4 w;
    w.x = __expf(lrelu_f(a.x+ad.x));
    w.y = __expf(lrelu_f(a.y+ad.y));
    w.z = __expf(lrelu_f(a.z+ad.z));
    w.w = __expf(lrelu_f(a.w+ad.w));
    ((uint2*)jb.coef)[gb0+i] = bf4_pack(w);
    jb.ssrc[gb0+i] = s;
  }
}

// ---------------- weight pre-conversion: W[K][N] f32 -> transposed bf16 hi/lo ----
// mode 0: plain. mode 1: Wc build (n<32: Ws[k*32+n], n==32: cwS[k], n==33: cwD[k], else 0)
struct WcvJob {
  const float* W; const float* cwS; const float* cwD;
  unsigned short* Wth; unsigned short* Wtl;
  int K; int N; int mode;
};
struct WcvArgs { WcvJob j[6]; };
__global__ __launch_bounds__(256) void wconv_kernel(WcvArgs args){
  WcvJob jb = args.j[blockIdx.y];
  int idx = blockIdx.x*256 + threadIdx.x;
  if (idx >= jb.K * jb.N) return;
  int k = idx / jb.N, n = idx % jb.N;
  float val;
  if (jb.mode == 0) val = jb.W[(size_t)k*jb.N + n];
  else {
    if (n < 32)       val = jb.W[(size_t)k*32 + n];
    else if (n == 32) val = jb.cwS[k];
    else if (n == 33) val = jb.cwD[k];
    else              val = 0.f;
  }
  unsigned short h, g;
  split_bf(val, h, g);
  jb.Wth[(size_t)n*jb.K + k] = h;
  jb.Wtl[(size_t)n*jb.K + k] = g;
}

// ---------------- proj GEMM, single-phase: C = elu(A[M,128] @ W[128,64] + b) ----
// Full K=128 staged at once (Ah/Al/Bh/Bl [64][136], 69.6KB): ONE barrier per
// block instead of 4, then all 48 MFMAs. Accumulation order over k unchanged
// (0,32,64,96) => bit-identical numerics. Fused layer-0 logits (LOGIT path).
struct PgJob {
  const float* A;                    // f32 [M,128]
  const unsigned short* Wth;         // [64][128] bf16 hi (transposed)
  const unsigned short* Wtl;         // [64][128] bf16 lo
  const float* bias;                 // [64]
  unsigned short* C;                 // bf16 [M,64]
  float* outA; float* outB;          // logits [M,4] each
  const float* cwS; const float* cwD;// [4][64]
};
__global__ __launch_bounds__(256) void pgemm_kernel(PgJob j0, PgJob j1, int M){
  const PgJob jb = blockIdx.z ? j1 : j0;
  __shared__ __align__(16) unsigned short Ah[64*136];
  __shared__ __align__(16) unsigned short Al[64*136];
  __shared__ __align__(16) unsigned short Bh[64*136];
  __shared__ __align__(16) unsigned short Bl[64*136];
  __shared__ float CwS[256];
  __shared__ float CwD[256];
  const int t = threadIdx.x;
  const int m0 = blockIdx.x*64;
  const int wv = t>>6, l = t&63;
  const int lr = l&15, lq = l>>4;
  CwS[t] = jb.cwS[t]; CwD[t] = jb.cwD[t];
  // A stage: 4 threads per row, 32 f32 (8 float4) each; split f32->bf16 hi/lo
  {
    int r  = t >> 2;
    int cq = (t & 3) * 32;
    bool ok = (m0 + r < M);
    const float* Arow = jb.A + (size_t)(m0 + (ok ? r : 0)) * 128 + cq;
    #pragma unroll
    for (int j=0;j<8;j++){
      float4 v = ok ? *(const float4*)(Arow + j*4) : make_float4(0.f,0.f,0.f,0.f);
      unsigned short h0,h1,h2,h3,g0,g1,g2,g3;
      split_bf(v.x,h0,g0); split_bf(v.y,h1,g1);
      split_bf(v.z,h2,g2); split_bf(v.w,h3,g3);
      uint2 ph = { (unsigned)h0 | ((unsigned)h1<<16), (unsigned)h2 | ((unsigned)h3<<16) };
      uint2 pl = { (unsigned)g0 | ((unsigned)g1<<16), (unsigned)g2 | ((unsigned)g3<<16) };
      *(uint2*)&Ah[r*136 + cq + j*4] = ph;
      *(uint2*)&Al[r*136 + cq + j*4] = pl;
    }
  }
  // B stage: pure copy of preconverted bf16 hi/lo (64 rows x 128 k, 16B chunks)
  #pragma unroll
  for (int i=0;i<4;i++){
    int c  = t + i*256;
    int n  = c >> 4;
    int k8 = (c & 15) * 8;
    *(short8*)&Bh[n*136 + k8] = *(const short8*)(jb.Wth + (size_t)n*128 + k8);
    *(short8*)&Bl[n*136 + k8] = *(const short8*)(jb.Wtl + (size_t)n*128 + k8);
  }
  __syncthreads();   // the ONLY barrier
  floatx4 acc[4];
  #pragma unroll
  for (int i=0;i<4;i++) acc[i] = (floatx4){0.f,0.f,0.f,0.f};
  #pragma unroll
  for (int ks=0; ks<4; ks++){
    const int koff = ks*32 + lq*8;
    short8 a_h = *(const short8*)&Ah[(wv*16+lr)*136 + koff];
    short8 a_l = *(const short8*)&Al[(wv*16+lr)*136 + koff];
    #pragma unroll
    for (int nt=0; nt<4; nt++){
      short8 b_h = *(const short8*)&Bh[(nt*16+lr)*136 + koff];
      short8 b_l = *(const short8*)&Bl[(nt*16+lr)*136 + koff];
      acc[nt] = __builtin_amdgcn_mfma_f32_16x16x32_bf16(a_h, b_h, acc[nt], 0,0,0);
      acc[nt] = __builtin_amdgcn_mfma_f32_16x16x32_bf16(a_h, b_l, acc[nt], 0,0,0);
      acc[nt] = __builtin_amdgcn_mfma_f32_16x16x32_bf16(a_l, b_h, acc[nt], 0,0,0);
    }
  }
  // epilogue: bias + ELU + bf16 store + fused dual logit dot products
  float ls[4][4], ld_[4][4];   // [r][h]
  #pragma unroll
  for (int r=0;r<4;r++)
    #pragma unroll
    for (int h=0;h<4;h++){ ls[r][h]=0.f; ld_[r][h]=0.f; }
  #pragma unroll
  for (int nt=0; nt<4; nt++){
    int n = nt*16 + lr;
    float bv = jb.bias[n];
    #pragma unroll
    for (int r=0;r<4;r++){
      int m = m0 + wv*16 + lq*4 + r;
      if (m < M){
        float o = elu_f(acc[nt][r] + bv);
        jb.C[(size_t)m*64 + n] = f2bf(o);
        #pragma unroll
        for (int h=0;h<4;h++){
          ls[r][h]  = fmaf(o, CwS[h*64 + n], ls[r][h]);
          ld_[r][h] = fmaf(o, CwD[h*64 + n], ld_[r][h]);
        }
      }
    }
  }
  // reduce over the 16 lr-lanes (channels), then lane lr==0 writes 4 rows x 4 heads
  #pragma unroll
  for (int r=0;r<4;r++)
    #pragma unroll
    for (int h=0;h<4;h++){
      float a = ls[r][h], d = ld_[r][h];
      #pragma unroll
      for (int off=1; off<16; off<<=1){
        a += __shfl_xor(a, off, 64);
        d += __shfl_xor(d, off, 64);
      }
      ls[r][h]=a; ld_[r][h]=d;
    }
  if (lr == 0){
    #pragma unroll
    for (int r=0;r<4;r++){
      int m = m0 + wv*16 + lq*4 + r;
      if (m < M){
        #pragma unroll
        for (int h=0;h<4;h++){
          jb.outA[(size_t)m*4 + h] = ls[r][h];
          jb.outB[(size_t)m*4 + h] = ld_[r][h];
        }
      }
    }
  }
}

// ---------------- MFMA GEMM (layer-1 LG): C = A[M,K] @ W[K,N] ----------------
// LDS-staged; B staging is a pure copy from preconverted transposed images.
// LG: GEMM N=48; cols 0..31 -> bf16 C (stride 32), col 32 -> outA, col 33 -> outB.
struct MgJob {
  const void* A;                     // bf16 [M,KK]
  const unsigned short* Wth;         // [N][KK] bf16 hi (transposed)
  const unsigned short* Wtl;         // [N][KK] bf16 lo
  const float* bias;
  void* C; float* outA; float* outB;
};
template<int NT, int KK, bool ELU, bool BF16OUT, bool LG>
__global__ __launch_bounds__(256) void mgemm_kernel(MgJob j0, MgJob j1,
                                                    int M, int N)
{
  const MgJob jb = blockIdx.z ? j1 : j0;
  constexpr int TN = NT*16;
  __shared__ __align__(16) unsigned short Ah[64*72];
  __shared__ __align__(16) unsigned short Bh[TN*72];
  __shared__ __align__(16) unsigned short Bl[TN*72];
  const int t = threadIdx.x;
  const int m0 = blockIdx.x*64;
  const int n0 = blockIdx.y*TN;
  const int wv = t>>6, l = t&63;
  const int lr = l&15, lq = l>>4;
  floatx4 acc[NT];
  #pragma unroll
  for (int i=0;i<NT;i++) acc[i] = (floatx4){0.f,0.f,0.f,0.f};

  #pragma unroll
  for (int kt=0; kt<KK; kt+=64){
    const unsigned short* A = (const unsigned short*)jb.A;
    #pragma unroll
    for (int i=0;i<2;i++){
      int li = t + i*256;
      int r = li >> 3, c8 = (li & 7)*8;
      short8 v = {0,0,0,0,0,0,0,0};
      if (m0 + r < M) v = *(const short8*)(A + (size_t)(m0+r)*KK + kt + c8);
      *(short8*)&Ah[r*72 + c8] = v;
    }
    // B-stage: pure copy of preconverted bf16 hi/lo (16B chunks).
    for (int c = t; c < TN*8; c += 256){
      int n  = c >> 3;
      int k8 = (c & 7) * 8;
      *(short8*)&Bh[n*72 + k8] =
          *(const short8*)(jb.Wth + (size_t)(n0 + n)*KK + kt + k8);
      *(short8*)&Bl[n*72 + k8] =
          *(const short8*)(jb.Wtl + (size_t)(n0 + n)*KK + kt + k8);
    }
    __syncthreads();
    #pragma unroll
    for (int ks=0; ks<2; ks++){
      const int koff = ks*32 + lq*8;
      short8 a_h = *(const short8*)&Ah[(wv*16+lr)*72 + koff];
      #pragma unroll
      for (int nt=0; nt<NT; nt++){
        short8 b_h = *(const short8*)&Bh[(nt*16+lr)*72 + koff];
        short8 b_l = *(const short8*)&Bl[(nt*16+lr)*72 + koff];
        acc[nt] = __builtin_amdgcn_mfma_f32_16x16x32_bf16(a_h, b_h, acc[nt], 0,0,0);
        acc[nt] = __builtin_amdgcn_mfma_f32_16x16x32_bf16(a_h, b_l, acc[nt], 0,0,0);
      }
    }
    __syncthreads();
  }
  #pragma unroll
  for (int nt=0; nt<NT; nt++){
    int n = n0 + nt*16 + lr;
    float bv = jb.bias ? jb.bias[n] : 0.f;
    #pragma unroll
    for (int r=0;r<4;r++){
      int m = m0 + wv*16 + lq*4 + r;
      if (m < M){
        float o = acc[nt][r] + bv;
        if (ELU) o = elu_f(o);
        if constexpr (LG){
          if (n < 32)       ((unsigned short*)jb.C)[(size_t)m*32 + n] = f2bf(o);
          else if (n == 32) jb.outA[m] = o;
          else if (n == 33) jb.outB[m] = o;
        } else {
          if (BF16OUT) ((unsigned short*)jb.C)[(size_t)m*N + n] = f2bf(o);
          else         ((float*)jb.C)[(size_t)m*N + n] = o;
        }
      }
    }
  }
}

// ---------------- per-head block GEMM: hi1[m, h*64+n] = elu((agg_h @ Ws_h)/den + b) ----
struct HgJob {
  const unsigned short* A;            // bf16 [M,256]
  const unsigned short* Wth;          // [256][64] bf16 hi (transposed, n-major)
  const unsigned short* Wtl;
  const float* den;                   // [M,4]
  const float* bias; unsigned short* out;   // out bf16 [M,256]
};
__global__ __launch_bounds__(256) void hgemm_kernel(HgJob j0, HgJob j1){
  const HgJob jb = blockIdx.z ? j1 : j0;
  const int head = blockIdx.y;
  const int m0 = blockIdx.x*64;
  __shared__ __align__(16) unsigned short Ah[64*72];
  __shared__ __align__(16) unsigned short Bh[64*72];
  __shared__ __align__(16) unsigned short Bl[64*72];
  const int t = threadIdx.x;
  const int wv = t>>6, l = t&63;
  const int lr = l&15, lq = l>>4;
  floatx4 acc[4];
  #pragma unroll
  for (int i=0;i<4;i++) acc[i] = (floatx4){0.f,0.f,0.f,0.f};
  #pragma unroll
  for (int i=0;i<2;i++){
    int li = t + i*256;
    int r = li >> 3, c8 = (li & 7)*8;
    short8 v = {0,0,0,0,0,0,0,0};
    if (m0 + r < NN) v = *(const short8*)(jb.A + (size_t)(m0+r)*256 + head*64 + c8);
    *(short8*)&Ah[r*72 + c8] = v;
  }
  // B-stage: copy head slice rows (head*64 + n), K=64
  #pragma unroll
  for (int i=0;i<2;i++){
    int c  = t + i*256;
    int n  = c >> 3;
    int k8 = (c & 7) * 8;
    *(short8*)&Bh[n*72 + k8] =
        *(const short8*)(jb.Wth + (size_t)(head*64 + n)*64 + k8);
    *(short8*)&Bl[n*72 + k8] =
        *(const short8*)(jb.Wtl + (size_t)(head*64 + n)*64 + k8);
  }
  __syncthreads();
  #pragma unroll
  for (int ks=0; ks<2; ks++){
    const int koff = ks*32 + lq*8;
    short8 a_h = *(const short8*)&Ah[(wv*16+lr)*72 + koff];
    #pragma unroll
    for (int nt=0; nt<4; nt++){
      short8 b_h = *(const short8*)&Bh[(nt*16+lr)*72 + koff];
      short8 b_l = *(const short8*)&Bl[(nt*16+lr)*72 + koff];
      acc[nt] = __builtin_amdgcn_mfma_f32_16x16x32_bf16(a_h, b_h, acc[nt], 0,0,0);
      acc[nt] = __builtin_amdgcn_mfma_f32_16x16x32_bf16(a_h, b_l, acc[nt], 0,0,0);
    }
  }
  float inv[4];
  #pragma unroll
  for (int r=0;r<4;r++){
    int m = m0 + wv*16 + lq*4 + r;
    inv[r] = (m < NN) ? 1.f/(jb.den[(size_t)m*4 + head] + 1e-16f) : 0.f;
  }
  #pragma unroll
  for (int nt=0; nt<4; nt++){
    int col = head*64 + nt*16 + lr;
    float bv = jb.bias[col];
    #pragma unroll
    for (int r=0;r<4;r++){
      int m = m0 + wv*16 + lq*4 + r;
      if (m < NN)
        jb.out[(size_t)m*256 + col] = f2bf(elu_f(acc[nt][r]*inv[r] + bv));
    }
  }
}

// ---------------- collapse attention vectors ----------------
struct CollapseJob { const float* W; const float* a; float* out; int K,H,C; };
struct CollapseArgs { CollapseJob j[8]; };
__global__ void collapse_kernel(CollapseArgs args){
  CollapseJob jb = args.j[blockIdx.x];
  int t = threadIdx.x;
  if (t < jb.K * jb.H){
    int k = t / jb.H, h = t % jb.H;
    const float* wr = jb.W + (size_t)k * (jb.H*jb.C) + h*jb.C;
    const float* ar = jb.a + h*jb.C;
    float s = 0.f;
    for (int c=0;c<jb.C;c++) s += wr[c]*ar[c];
    jb.out[h*jb.K + k] = s;   // layout [H,K]
  }
}

// ---------------- layer-0 pre-aggregation over hu/hi rows ----------------
// 8 dsts per wave, 8 lanes per dst, 8 channels per lane: edge-sum is fully
// within-lane => no cross-lane reduction epilogue. Unroll-4 edge loop: 4
// x-row gathers in flight per iteration (gather-latency hiding).
struct AggPJob {
  const int* offs; const int* ssrc;
  const unsigned short* x;     // bf16 [NN,64]
  const unsigned short* coef;  // bf16 [E,4]
  unsigned short* agg;         // bf16 [NN,256]
  float* den;                  // fp32 [NN,4]
};
__global__ __launch_bounds__(256) void aggpre_kernel(AggPJob ja, AggPJob jbb){
  const AggPJob jb = blockIdx.y ? jbb : ja;
  const int tid = threadIdx.x;
  const int lane = tid & 63, wid = tid >> 6;
  const int grp = lane >> 3;       // dst group within wave (0..7)
  const int cl  = lane & 7;        // channel lane within group
  const int c8  = cl * 8;          // channel base (8 bf16 = 16B per lane)
  const int dst = blockIdx.x*32 + wid*8 + grp;
  if (dst >= NN) return;
  const int b0 = jb.offs[dst], b1 = jb.offs[dst+1];
  float acc[4][8];
  float den[4] = {0.f,0.f,0.f,0.f};
  #pragma unroll
  for (int h=0;h<4;h++)
    #pragma unroll
    for (int c=0;c<8;c++) acc[h][c]=0.f;
  int e = b0;
  // unroll-4: batch 4 independent x gathers + coef loads per iteration
  for (; e+3 < b1; e += 4){
    int s0 = jb.ssrc[e];
    int s1 = jb.ssrc[e+1];
    int s2 = jb.ssrc[e+2];
    int s3 = jb.ssrc[e+3];
    uint4 q0 = *(const uint4*)(jb.x + ((size_t)s0<<6) + c8);
    uint4 q1 = *(const uint4*)(jb.x + ((size_t)s1<<6) + c8);
    uint4 q2 = *(const uint4*)(jb.x + ((size_t)s2<<6) + c8);
    uint4 q3 = *(const uint4*)(jb.x + ((size_t)s3<<6) + c8);
    uint2 w0 = *(const uint2*)(jb.coef + (size_t)e*4);
    uint2 w1 = *(const uint2*)(jb.coef + (size_t)(e+1)*4);
    uint2 w2 = *(const uint2*)(jb.coef + (size_t)(e+2)*4);
    uint2 w3 = *(const uint2*)(jb.coef + (size_t)(e+3)*4);
    agg_pair(acc, den, q0, q1, w0, w1);
    agg_pair(acc, den, q2, q3, w2, w3);
  }
  if (e+1 < b1){
    int s0 = jb.ssrc[e];
    int s1 = jb.ssrc[e+1];
    uint4 q0 = *(const uint4*)(jb.x + ((size_t)s0<<6) + c8);
    uint4 q1 = *(const uint4*)(jb.x + ((size_t)s1<<6) + c8);
    uint2 w0 = *(const uint2*)(jb.coef + (size_t)e*4);
    uint2 w1 = *(const uint2*)(jb.coef + (size_t)(e+1)*4);
    agg_pair(acc, den, q0, q1, w0, w1);
    e += 2;
  }
  if (e < b1){  // odd-degree tail: single edge, scalar path
    int s = jb.ssrc[e];
    uint4 q = *(const uint4*)(jb.x + ((size_t)s<<6) + c8);
    uint2 w = *(const uint2*)(jb.coef + (size_t)e*4);
    float wf[4] = { bf2f(w.x & 0xffffu), bf2f(w.x >> 16),
                    bf2f(w.y & 0xffffu), bf2f(w.y >> 16) };
    float xf[8] = { bf2f(q.x & 0xffffu), bf2f(q.x >> 16),
                    bf2f(q.y & 0xffffu), bf2f(q.y >> 16),
                    bf2f(q.z & 0xffffu), bf2f(q.z >> 16),
                    bf2f(q.w & 0xffffu), bf2f(q.w >> 16) };
    #pragma unroll
    for (int h=0;h<4;h++){
      den[h] += wf[h];
      #pragma unroll
      for (int c=0;c<8;c++) acc[h][c] += wf[h]*xf[c];
    }
  }
  // epilogue: pack + store only (no shuffles)
  #pragma unroll
  for (int h=0;h<4;h++){
    uint2 plo = bf4_pack(make_float4(acc[h][0],acc[h][1],acc[h][2],acc[h][3]));
    uint2 phi = bf4_pack(make_float4(acc[h][4],acc[h][5],acc[h][6],acc[h][7]));
    uint4 pk = { plo.x, plo.y, phi.x, phi.y };
    *(uint4*)(jb.agg + (size_t)dst*256 + h*64 + c8) = pk;
  }
  if (cl == 0)
    *(float4*)(jb.den + (size_t)dst*4) = make_float4(den[0],den[1],den[2],den[3]);
}

// ---------------- layer-1 aggregation (softmax weight fused inline) ----------------
struct Agg1Job {
  const int* offs; const int* ssrc;
  const unsigned short* hs;   // bf16 [NN,32]
  const float* als; const float* ald;  // layer-1 logits
  const float* bias; float* out;
};
__global__ __launch_bounds__(256) void agg1_kernel(Agg1Job ja, Agg1Job jbb){
  const Agg1Job jb = blockIdx.y ? jbb : ja;
  const int wid = threadIdx.x>>6, lane = threadIdx.x&63;
  const int dst = blockIdx.x*4 + wid;
  if (dst >= NN) return;
  const int b0 = jb.offs[dst], b1 = jb.offs[dst+1];
  const float ad = jb.ald[dst];
  const int slot = lane>>3, c4 = (lane&7)*4;
  float4 acc = make_float4(0.f,0.f,0.f,0.f);
  float den = 0.f;
  int e = b0 + slot;
  for (; e+8 < b1; e += 16){
    int s0 = jb.ssrc[e], s1 = jb.ssrc[e+8];
    float a0 = jb.als[s0];
    float a1 = jb.als[s1];
    float4 v0 = bf4_load(jb.hs + ((size_t)s0<<5) + c4);
    float4 v1 = bf4_load(jb.hs + ((size_t)s1<<5) + c4);
    float w0 = __expf(lrelu_f(a0 + ad));
    float w1 = __expf(lrelu_f(a1 + ad));
    acc.x += w0*v0.x + w1*v1.x;
    acc.y += w0*v0.y + w1*v1.y;
    acc.z += w0*v0.z + w1*v1.z;
    acc.w += w0*v0.w + w1*v1.w;
    den += w0 + w1;
  }
  if (e < b1){
    int s = jb.ssrc[e];
    float w = __expf(lrelu_f(jb.als[s] + ad));
    float4 v = bf4_load(jb.hs + ((size_t)s<<5) + c4);
    acc.x += w*v.x; acc.y += w*v.y; acc.z += w*v.z; acc.w += w*v.w;
    den += w;
  }
  #pragma unroll
  for (int off=32; off>=8; off>>=1){
    acc.x += __shfl_xor(acc.x, off, 64);
    acc.y += __shfl_xor(acc.y, off, 64);
    acc.z += __shfl_xor(acc.z, off, 64);
    acc.w += __shfl_xor(acc.w, off, 64);
    den   += __shfl_xor(den,   off, 64);
  }
  if (lane < 8){
    const float inv = 1.f/(den + 1e-16f);
    float4 b = *(const float4*)(jb.bias + c4);
    float4 o = make_float4(acc.x*inv+b.x, acc.y*inv+b.y, acc.z*inv+b.z, acc.w*inv+b.w);
    *(float4*)(jb.out + (size_t)dst*32 + c4) = o;
  }
}

// ---------------- host glue ----------------
extern "C" void kernel_launch(void* const* d_in, const int* in_sizes, int n_in,
                              void* d_out, int out_size, void* d_ws, size_t ws_size,
                              hipStream_t stream)
{
  (void)in_sizes; (void)n_in; (void)out_size; (void)ws_size;
  const float* x_user   = (const float*)d_in[0];
  const float* x_item   = (const float*)d_in[1];
  const int*   e_u2i    = (const int*)  d_in[2];
  const int*   e_i2u    = (const int*)  d_in[3];
  const float* p_user_w = (const float*)d_in[4];
  const float* p_user_b = (const float*)d_in[5];
  const float* p_item_w = (const float*)d_in[6];
  const float* p_item_b = (const float*)d_in[7];
  const float* l0_u2i_ws=(const float*)d_in[8];
  const float* l0_u2i_wd=(const float*)d_in[9];
  const float* l0_u2i_as=(const float*)d_in[10];
  const float* l0_u2i_ad=(const float*)d_in[11];
  const float* l0_u2i_b =(const float*)d_in[12];
  const float* l0_i2u_ws=(const float*)d_in[13];
  const float* l0_i2u_wd=(const float*)d_in[14];
  const float* l0_i2u_as=(const float*)d_in[15];
  const float* l0_i2u_ad=(const float*)d_in[16];
  const float* l0_i2u_b =(const float*)d_in[17];
  const float* l1_u2i_ws=(const float*)d_in[18];
  const float* l1_u2i_wd=(const float*)d_in[19];
  const float* l1_u2i_as=(const float*)d_in[20];
  const float* l1_u2i_ad=(const float*)d_in[21];
  const float* l1_u2i_b =(const float*)d_in[22];
  const float* l1_i2u_ws=(const float*)d_in[23];
  const float* l1_i2u_wd=(const float*)d_in[24];
  const float* l1_i2u_as=(const float*)d_in[25];
  const float* l1_i2u_ad=(const float*)d_in[26];
  const float* l1_i2u_b =(const float*)d_in[27];

  char* base = (char*)d_ws;
  size_t off = 0;
  auto alloc = [&](size_t bytes)->void*{
    void* p = base + off;
    off += (bytes + 255) & ~(size_t)255;
    return p;
  };
  int* offs_u2i = (int*)alloc((size_t)(NN+1)*sizeof(int));
  int* offs_i2u = (int*)alloc((size_t)(NN+1)*sizeof(int));
  int* ssrc_u2i = (int*)alloc((size_t)NE*sizeof(int));
  int* ssrc_i2u = (int*)alloc((size_t)NE*sizeof(int));
  int* ghist    = (int*)alloc((size_t)2*200*sizeof(int));
  int* gbase    = (int*)alloc((size_t)2*200*sizeof(int));
  int* gcur     = (int*)alloc((size_t)2*200*sizeof(int));
  unsigned short* coef0_u2i = (unsigned short*)alloc((size_t)NE*4*sizeof(unsigned short));
  unsigned short* coef0_i2u = (unsigned short*)alloc((size_t)NE*4*sizeof(unsigned short));
  unsigned short* hu = (unsigned short*)alloc((size_t)NN*64*sizeof(unsigned short));
  unsigned short* hi = (unsigned short*)alloc((size_t)NN*64*sizeof(unsigned short));
  unsigned short* agg_u2i = (unsigned short*)alloc((size_t)NN*256*sizeof(unsigned short));
  unsigned short* agg_i2u = (unsigned short*)alloc((size_t)NN*256*sizeof(unsigned short));
  float* den_u2i = (float*)alloc((size_t)NN*4*sizeof(float));
  float* den_i2u = (float*)alloc((size_t)NN*4*sizeof(float));
  unsigned short* hu1 = (unsigned short*)alloc((size_t)NN*256*sizeof(unsigned short));
  unsigned short* hi1 = (unsigned short*)alloc((size_t)NN*256*sizeof(unsigned short));
  unsigned short* hs1_u2i = (unsigned short*)alloc((size_t)NN*32*sizeof(unsigned short));
  unsigned short* hs1_i2u = (unsigned short*)alloc((size_t)NN*32*sizeof(unsigned short));
  float* als0_u2i = (float*)alloc((size_t)NN*4*sizeof(float));
  float* ald0_u2i = (float*)alloc((size_t)NN*4*sizeof(float));
  float* als0_i2u = (float*)alloc((size_t)NN*4*sizeof(float));
  float* ald0_i2u = (float*)alloc((size_t)NN*4*sizeof(float));
  float* als1_u2i = (float*)alloc((size_t)NN*sizeof(float));
  float* ald1_u2i = (float*)alloc((size_t)NN*sizeof(float));
  float* als1_i2u = (float*)alloc((size_t)NN*sizeof(float));
  float* ald1_i2u = (float*)alloc((size_t)NN*sizeof(float));
  float* cw0s_u2i = (float*)alloc(256*sizeof(float));
  float* cw0d_u2i = (float*)alloc(256*sizeof(float));
  float* cw0s_i2u = (float*)alloc(256*sizeof(float));
  float* cw0d_i2u = (float*)alloc(256*sizeof(float));
  float* cw1s_u2i = (float*)alloc(256*sizeof(float));
  float* cw1d_u2i = (float*)alloc(256*sizeof(float));
  float* cw1s_i2u = (float*)alloc(256*sizeof(float));
  float* cw1d_i2u = (float*)alloc(256*sizeof(float));
  // transposed bf16 hi/lo weight images
  unsigned short* wt_pu_h  = (unsigned short*)alloc((size_t)64*128*sizeof(unsigned short));
  unsigned short* wt_pu_l  = (unsigned short*)alloc((size_t)64*128*sizeof(unsigned short));
  unsigned short* wt_pi_h  = (unsigned short*)alloc((size_t)64*128*sizeof(unsigned short));
  unsigned short* wt_pi_l  = (unsigned short*)alloc((size_t)64*128*sizeof(unsigned short));
  unsigned short* wt_l0u_h = (unsigned short*)alloc((size_t)256*64*sizeof(unsigned short));
  unsigned short* wt_l0u_l = (unsigned short*)alloc((size_t)256*64*sizeof(unsigned short));
  unsigned short* wt_l0i_h = (unsigned short*)alloc((size_t)256*64*sizeof(unsigned short));
  unsigned short* wt_l0i_l = (unsigned short*)alloc((size_t)256*64*sizeof(unsigned short));
  unsigned short* wt_wcu_h = (unsigned short*)alloc((size_t)48*256*sizeof(unsigned short));
  unsigned short* wt_wcu_l = (unsigned short*)alloc((size_t)48*256*sizeof(unsigned short));
  unsigned short* wt_wci_h = (unsigned short*)alloc((size_t)48*256*sizeof(unsigned short));
  unsigned short* wt_wci_l = (unsigned short*)alloc((size_t)48*256*sizeof(unsigned short));
  // pairs scratch aliases hu1/hi1: consumed by part2 before hgemm writes them
  int2* pairs_u2i = (int2*)hu1;
  int2* pairs_i2u = pairs_u2i + NE;

  const int GM = (NN + 63)/64;

  // ---- bucket sort stage A ----
  hipMemsetAsync(ghist, 0, (size_t)2*200*sizeof(int), stream);
  ghist_kernel<<<dim3(256,2), 256, 0, stream>>>(e_u2i, e_i2u, ghist);
  gscan_kernel<<<1, 256, 0, stream>>>(ghist, gbase, gcur);
  part1_kernel<<<dim3((NE+TILE1-1)/TILE1,2), 256, 0, stream>>>(
      e_u2i, e_i2u, gcur, pairs_u2i, pairs_i2u);

  // ---- collapse attention vectors ----
  CollapseArgs ca;
  ca.j[0] = {l0_u2i_ws, l0_u2i_as, cw0s_u2i, 64, 4, 64};
  ca.j[1] = {l0_u2i_wd, l0_u2i_ad, cw0d_u2i, 64, 4, 64};
  ca.j[2] = {l0_i2u_ws, l0_i2u_as, cw0s_i2u, 64, 4, 64};
  ca.j[3] = {l0_i2u_wd, l0_i2u_ad, cw0d_i2u, 64, 4, 64};
  ca.j[4] = {l1_u2i_ws, l1_u2i_as, cw1s_u2i, 256, 1, 32};
  ca.j[5] = {l1_u2i_wd, l1_u2i_ad, cw1d_u2i, 256, 1, 32};
  ca.j[6] = {l1_i2u_ws, l1_i2u_as, cw1s_i2u, 256, 1, 32};
  ca.j[7] = {l1_i2u_wd, l1_i2u_ad, cw1d_i2u, 256, 1, 32};
  collapse_kernel<<<8, 256, 0, stream>>>(ca);

  // ---- weight pre-conversion (transposed bf16 hi/lo; Wc built with cw cols) ----
  WcvArgs wa;
  wa.j[0] = {p_user_w,  nullptr,   nullptr,   wt_pu_h,  wt_pu_l,  128, 64, 0};
  wa.j[1] = {p_item_w,  nullptr,   nullptr,   wt_pi_h,  wt_pi_l,  128, 64, 0};
  wa.j[2] = {l0_u2i_ws, nullptr,   nullptr,   wt_l0u_h, wt_l0u_l, 64, 256, 0};
  wa.j[3] = {l0_i2u_ws, nullptr,   nullptr,   wt_l0i_h, wt_l0i_l, 64, 256, 0};
  wa.j[4] = {l1_u2i_ws, cw1s_u2i,  cw1d_i2u,  wt_wcu_h, wt_wcu_l, 256, 48, 1};
  wa.j[5] = {l1_i2u_ws, cw1s_i2u,  cw1d_u2i,  wt_wci_h, wt_wci_l, 256, 48, 1};
  wconv_kernel<<<dim3(64,6), 256, 0, stream>>>(wa);

  // ---- input projections (+bias +ELU) -> bf16, fused layer-0 logits ----
  // single-phase full-K staging: 1 barrier per block
  pgemm_kernel<<<dim3(GM,1,2), 256, 0, stream>>>(
      PgJob{x_user, wt_pu_h, wt_pu_l, p_user_b, hu, als0_u2i, ald0_i2u, cw0s_u2i, cw0d_i2u},
      PgJob{x_item, wt_pi_h, wt_pi_l, p_item_b, hi, als0_i2u, ald0_u2i, cw0s_i2u, cw0d_u2i},
      NN);

  // ---- bucket sort stage B ----
  part2_kernel<<<dim3(GB,2), 256, 0, stream>>>(
      Part2Job{pairs_u2i, gbase,       als0_u2i, ald0_u2i, ssrc_u2i, offs_u2i, coef0_u2i},
      Part2Job{pairs_i2u, gbase + 200, als0_i2u, ald0_i2u, ssrc_i2u, offs_i2u, coef0_i2u});

  // ---- layer 0: pre-aggregate hu/hi rows (8 dst/wave, unroll-4 gathers) ----
  aggpre_kernel<<<dim3((NN+31)/32,2), 256, 0, stream>>>(
      AggPJob{offs_u2i, ssrc_u2i, hu, coef0_u2i, agg_u2i, den_u2i},
      AggPJob{offs_i2u, ssrc_i2u, hi, coef0_i2u, agg_i2u, den_i2u});

  // ---- layer 0: per-head GEMM + den-divide + bias + ELU -> hi1/hu1 bf16 ----
  hgemm_kernel<<<dim3(GM,4,2), 256, 0, stream>>>(
      HgJob{agg_u2i, wt_l0u_h, wt_l0u_l, den_u2i, l0_u2i_b, hi1},
      HgJob{agg_i2u, wt_l0i_h, wt_l0i_l, den_i2u, l0_i2u_b, hu1});

  // ---- layer 1: feature GEMMs with fused logit columns ----
  mgemm_kernel<3,256,false,true,true><<<dim3(GM,1,2), 256, 0, stream>>>(
      MgJob{hu1, wt_wcu_h, wt_wcu_l, nullptr, hs1_u2i, als1_u2i, ald1_i2u},
      MgJob{hi1, wt_wci_h, wt_wci_l, nullptr, hs1_i2u, als1_i2u, ald1_u2i},
      NN, 48);

  // ---- layer 1: aggregate (+bias), softmax weights computed inline ----
  float* hu2 = (float*)d_out;                  // first tuple element (users, i2u dst)
  float* hi2 = (float*)d_out + (size_t)NN*32;  // second tuple element (items, u2i dst)
  agg1_kernel<<<dim3(NN/4,2), 256, 0, stream>>>(
      Agg1Job{offs_u2i, ssrc_u2i, hs1_u2i, als1_u2i, ald1_u2i, l1_u2i_b, hi2},
      Agg1Job{offs_i2u, ssrc_i2u, hs1_i2u, als1_i2u, ald1_i2u, l1_i2u_b, hu2});
}

// Round 11
// 349.258 us; speedup vs baseline: 1.0718x; 1.0718x over previous
//
#include <hip/hip_runtime.h>
#include <cstdint>
#include <cstddef>

#define NN 50000
#define NE 800000
#define GB 196        // coarse buckets = ceil(NN/256)
#define TILE1 4096    // edges per part1 block
#define CAP 8192      // max edges per bucket in part2 LDS (mean 4082)

typedef __attribute__((ext_vector_type(8))) short short8;
typedef __attribute__((ext_vector_type(4))) float floatx4;

__device__ __forceinline__ float lrelu_f(float x){ return x >= 0.f ? x : 0.2f*x; }
__device__ __forceinline__ float elu_f(float x){ return x > 0.f ? x : __expf(x) - 1.f; }

__device__ __forceinline__ unsigned short f2bf(float f){
  unsigned int u = __float_as_uint(f);
  u += 0x7FFFu + ((u >> 16) & 1u);
  return (unsigned short)(u >> 16);
}
__device__ __forceinline__ float bf2f(unsigned int us){
  return __uint_as_float(us << 16);
}
__device__ __forceinline__ float4 bf4_load(const unsigned short* p){
  uint2 q = *(const uint2*)p;
  return make_float4(bf2f(q.x & 0xffffu), bf2f(q.x >> 16),
                     bf2f(q.y & 0xffffu), bf2f(q.y >> 16));
}
__device__ __forceinline__ uint2 bf4_pack(float4 o){
  uint2 p;
  p.x = (unsigned)f2bf(o.x) | ((unsigned)f2bf(o.y) << 16);
  p.y = (unsigned)f2bf(o.z) | ((unsigned)f2bf(o.w) << 16);
  return p;
}
__device__ __forceinline__ void split_bf(float a, unsigned short& h, unsigned short& l){
  h = f2bf(a);
  l = f2bf(a - bf2f(h));
}

// v_dot2_f32_bf16: acc += a.bf16[0]*b.bf16[0] + a.bf16[1]*b.bf16[1]
__device__ __forceinline__ float dot2bf(float acc, unsigned a, unsigned b){
  asm("v_dot2_f32_bf16 %0, %1, %2, %0" : "+v"(acc) : "v"(a), "v"(b));
  return acc;
}

// process one edge PAIR (bf16 operands stay packed; sums stay within-lane)
__device__ __forceinline__ void agg_pair(float (&acc)[4][8], float (&den)[4],
                                         uint4 q0, uint4 q1, uint2 w0, uint2 w1){
  const unsigned ONE2 = 0x3F803F80u;  // packed bf16 (1.0, 1.0)
  unsigned wp[4];
  wp[0] = __builtin_amdgcn_perm(w1.x, w0.x, 0x05040100u);
  wp[1] = __builtin_amdgcn_perm(w1.x, w0.x, 0x07060302u);
  wp[2] = __builtin_amdgcn_perm(w1.y, w0.y, 0x05040100u);
  wp[3] = __builtin_amdgcn_perm(w1.y, w0.y, 0x07060302u);
  unsigned xp[8];
  xp[0] = __builtin_amdgcn_perm(q1.x, q0.x, 0x05040100u);
  xp[1] = __builtin_amdgcn_perm(q1.x, q0.x, 0x07060302u);
  xp[2] = __builtin_amdgcn_perm(q1.y, q0.y, 0x05040100u);
  xp[3] = __builtin_amdgcn_perm(q1.y, q0.y, 0x07060302u);
  xp[4] = __builtin_amdgcn_perm(q1.z, q0.z, 0x05040100u);
  xp[5] = __builtin_amdgcn_perm(q1.z, q0.z, 0x07060302u);
  xp[6] = __builtin_amdgcn_perm(q1.w, q0.w, 0x05040100u);
  xp[7] = __builtin_amdgcn_perm(q1.w, q0.w, 0x07060302u);
  #pragma unroll
  for (int h=0;h<4;h++){
    den[h] = dot2bf(den[h], wp[h], ONE2);
    #pragma unroll
    for (int c=0;c<8;c++) acc[h][c] = dot2bf(acc[h][c], wp[h], xp[c]);
  }
}

// ---------------- two-level bucket sort of edges by dst ----------------
__global__ __launch_bounds__(256) void ghist_kernel(const int* __restrict__ e0,
                                                    const int* __restrict__ e1,
                                                    int* __restrict__ ghist){
  const int ty = blockIdx.y;
  const int* e = ty ? e1 : e0;
  __shared__ int h[GB];
  for (int j=threadIdx.x; j<GB; j+=256) h[j]=0;
  __syncthreads();
  for (int i = blockIdx.x*256 + threadIdx.x; i < NE; i += 256*256)
    atomicAdd(&h[e[NE+i]>>8], 1);
  __syncthreads();
  for (int j=threadIdx.x; j<GB; j+=256) if (h[j]) atomicAdd(&ghist[ty*200+j], h[j]);
}

__global__ __launch_bounds__(256) void gscan_kernel(const int* __restrict__ ghist,
                                                    int* __restrict__ gbase,
                                                    int* __restrict__ gcur){
  __shared__ int wb[4];
  const int t = threadIdx.x, wv = t>>6, l = t&63;
  for (int ty=0; ty<2; ++ty){
    int v = (t < GB) ? ghist[ty*200+t] : 0;
    int sum = v;
    #pragma unroll
    for (int off=1; off<64; off<<=1){
      int x = __shfl_up(sum, off, 64);
      if (l >= off) sum += x;
    }
    if (l == 63) wb[wv] = sum;
    __syncthreads();
    int wbase = 0;
    #pragma unroll
    for (int w=0; w<4; ++w) if (w < wv) wbase += wb[w];
    int excl = wbase + sum - v;
    if (t <= GB) gbase[ty*200+t] = excl;
    if (t <  GB) gcur [ty*200+t] = excl;
    __syncthreads();
  }
}

// partition with LDS staging: global writes are contiguous per-bucket runs
__global__ __launch_bounds__(256) void part1_kernel(const int* __restrict__ e0,
                                                    const int* __restrict__ e1,
                                                    int* __restrict__ gcur,
                                                    int2* __restrict__ p0,
                                                    int2* __restrict__ p1){
  const int ty = blockIdx.y;
  const int* e = ty ? e1 : e0;
  int2* pairs = ty ? p1 : p0;
  __shared__ int cnt[256];
  __shared__ int lstart[256];
  __shared__ int lcur[256];
  __shared__ int curg[GB];
  __shared__ int lsrc[TILE1];
  __shared__ int ldst[TILE1];
  __shared__ int wb[4];
  const int t = threadIdx.x;
  cnt[t] = 0;
  __syncthreads();
  int dreg[16], sreg[16];
  const int base = blockIdx.x*TILE1;
  const int ntile = min(TILE1, NE - base);
  #pragma unroll
  for (int it=0; it<16; ++it){
    int i = base + it*256 + t;
    int d = -1, s = 0;
    if (i < NE){ d = e[NE+i]; s = e[i]; atomicAdd(&cnt[d>>8], 1); }
    dreg[it] = d; sreg[it] = s;
  }
  __syncthreads();
  int c = cnt[t], sum = c;
  #pragma unroll
  for (int off=1; off<64; off<<=1){
    int x = __shfl_up(sum, off, 64);
    if ((t&63) >= off) sum += x;
  }
  if ((t&63) == 63) wb[t>>6] = sum;
  __syncthreads();
  int wbase = 0;
  #pragma unroll
  for (int w=0; w<4; ++w) if (w < (t>>6)) wbase += wb[w];
  int excl = wbase + sum - c;
  lstart[t] = excl;
  lcur[t] = excl;
  if (t < GB && c > 0) curg[t] = atomicAdd(&gcur[ty*200+t], c);
  __syncthreads();
  #pragma unroll
  for (int it=0; it<16; ++it){
    int d = dreg[it];
    if (d >= 0){
      int pos = atomicAdd(&lcur[d>>8], 1);
      lsrc[pos] = sreg[it];
      ldst[pos] = d;
    }
  }
  __syncthreads();
  for (int i=t; i<ntile; i+=256){
    int d = ldst[i];
    int j = d>>8;
    pairs[curg[j] + (i - lstart[j])] = make_int2(lsrc[i], d);
  }
}

// per-bucket LDS bin by dst + CSR offsets + fused layer-0 softmax weights (bf16).
struct Part2Job {
  const int2* pairs; const int* gbase;
  const float* als; const float* ald;   // [NN,4]
  int* ssrc; int* offs; unsigned short* coef;  // coef: [E,4] bf16
};
__global__ __launch_bounds__(256) void part2_kernel(Part2Job j0, Part2Job j1){
  const Part2Job jb = blockIdx.y ? j1 : j0;
  const int b = blockIdx.x;
  const int t = threadIdx.x;
  __shared__ int lcnt[256];
  __shared__ int lcur[256];
  __shared__ int wb[4];
  __shared__ int sorted_src[CAP];
  __shared__ unsigned char sorted_dl[CAP];
  const int gb0 = jb.gbase[b], gb1 = jb.gbase[b+1];
  const int n = gb1 - gb0;
  lcnt[t] = 0;
  __syncthreads();
  for (int i=t; i<n; i+=256)
    atomicAdd(&lcnt[jb.pairs[gb0+i].y - (b<<8)], 1);
  __syncthreads();
  int c = lcnt[t], sum = c;
  #pragma unroll
  for (int off=1; off<64; off<<=1){
    int x = __shfl_up(sum, off, 64);
    if ((t&63) >= off) sum += x;
  }
  if ((t&63) == 63) wb[t>>6] = sum;
  __syncthreads();
  int wbase = 0;
  #pragma unroll
  for (int w=0; w<4; ++w) if (w < (t>>6)) wbase += wb[w];
  int excl = wbase + sum - c;
  lcur[t] = excl;
  int g = (b<<8) + t;
  if (g <= NN) jb.offs[g] = gb0 + excl;
  __syncthreads();
  for (int i=t; i<n; i+=256){
    int2 pr = jb.pairs[gb0+i];
    int dl = pr.y - (b<<8);
    int pos = atomicAdd(&lcur[dl], 1);
    sorted_src[pos] = pr.x;
    sorted_dl[pos] = (unsigned char)dl;
  }
  __syncthreads();
  const float4* als4 = (const float4*)jb.als;
  const float4* ald4 = (const float4*)jb.ald;
  for (int i=t; i<n; i+=256){
    int s  = sorted_src[i];
    int dl = sorted_dl[i];
    float4 a  = als4[s];
    float4 ad = ald4[(b<<8)+dl];
    // no max-shift: |alpha| small at this model scale; softmax shift-invariant.
    float4 w;
    w.x = __expf(lrelu_f(a.x+ad.x));
    w.y = __expf(lrelu_f(a.y+ad.y));
    w.z = __expf(lrelu_f(a.z+ad.z));
    w.w = __expf(lrelu_f(a.w+ad.w));
    ((uint2*)jb.coef)[gb0+i] = bf4_pack(w);
    jb.ssrc[gb0+i] = s;
  }
}

// ---------------- weight pre-conversion: W[K][N] f32 -> transposed bf16 hi/lo ----
// mode 0: plain. mode 1: Wc build (n<32: Ws[k*32+n], n==32: cwS[k], n==33: cwD[k], else 0)
struct WcvJob {
  const float* W; const float* cwS; const float* cwD;
  unsigned short* Wth; unsigned short* Wtl;
  int K; int N; int mode;
};
struct WcvArgs { WcvJob j[6]; };
__global__ __launch_bounds__(256) void wconv_kernel(WcvArgs args){
  WcvJob jb = args.j[blockIdx.y];
  int idx = blockIdx.x*256 + threadIdx.x;
  if (idx >= jb.K * jb.N) return;
  int k = idx / jb.N, n = idx % jb.N;
  float val;
  if (jb.mode == 0) val = jb.W[(size_t)k*jb.N + n];
  else {
    if (n < 32)       val = jb.W[(size_t)k*32 + n];
    else if (n == 32) val = jb.cwS[k];
    else if (n == 33) val = jb.cwD[k];
    else              val = 0.f;
  }
  unsigned short h, g;
  split_bf(val, h, g);
  jb.Wth[(size_t)n*jb.K + k] = h;
  jb.Wtl[(size_t)n*jb.K + k] = g;
}

// ---------------- MFMA GEMM: C = act(A[M,K] @ W[K,N] (+bias)) ----------------
// Two-phase LDS-staged structure (round-9 proven: occupancy-bound, NOT
// barrier-bound — 4 blocks/CU at 38.9KB LDS beats 1-barrier/72KB variant).
// B staging is a pure copy from preconverted transposed bf16 hi/lo images.
struct MgJob {
  const void* A;                     // f32 [M,KK] if !BF16A else bf16 [M,KK]
  const unsigned short* Wth;         // [N][KK] bf16 hi (transposed)
  const unsigned short* Wtl;         // [N][KK] bf16 lo
  const float* bias;
  void* C; float* outA; float* outB;
  const float* cwS; const float* cwD;
};
template<int NT, int KK, bool ELU, bool BF16OUT, bool BF16A, bool LG, bool LOGIT>
__global__ __launch_bounds__(256) void mgemm_kernel(MgJob j0, MgJob j1,
                                                    int M, int N)
{
  const MgJob jb = blockIdx.z ? j1 : j0;
  constexpr int TN = NT*16;
  __shared__ __align__(16) unsigned short Ah[64*72];
  __shared__ __align__(16) unsigned short Al[BF16A ? 8 : 64*72];
  __shared__ __align__(16) unsigned short Bh[TN*72];
  __shared__ __align__(16) unsigned short Bl[TN*72];
  __shared__ float CwS[LOGIT ? 256 : 1];
  __shared__ float CwD[LOGIT ? 256 : 1];
  const int t = threadIdx.x;
  const int m0 = blockIdx.x*64;
  const int n0 = blockIdx.y*TN;
  const int wv = t>>6, l = t&63;
  const int lr = l&15, lq = l>>4;
  if constexpr (LOGIT){ CwS[t] = jb.cwS[t]; CwD[t] = jb.cwD[t]; }
  floatx4 acc[NT];
  #pragma unroll
  for (int i=0;i<NT;i++) acc[i] = (floatx4){0.f,0.f,0.f,0.f};

  #pragma unroll
  for (int kt=0; kt<KK; kt+=64){
    if constexpr (BF16A){
      const unsigned short* A = (const unsigned short*)jb.A;
      #pragma unroll
      for (int i=0;i<2;i++){
        int li = t + i*256;
        int r = li >> 3, c8 = (li & 7)*8;
        short8 v = {0,0,0,0,0,0,0,0};
        if (m0 + r < M) v = *(const short8*)(A + (size_t)(m0+r)*KK + kt + c8);
        *(short8*)&Ah[r*72 + c8] = v;
      }
    } else {
      const float* A = (const float*)jb.A;
      #pragma unroll
      for (int i=0;i<4;i++){
        int li = t + i*256;
        int r = li >> 4, c4 = (li & 15)*4;
        float4 v = make_float4(0.f,0.f,0.f,0.f);
        if (m0 + r < M) v = *(const float4*)(A + (size_t)(m0+r)*KK + kt + c4);
        unsigned short h0,h1,h2,h3,g0,g1,g2,g3;
        split_bf(v.x,h0,g0); split_bf(v.y,h1,g1);
        split_bf(v.z,h2,g2); split_bf(v.w,h3,g3);
        uint2 ph = { (unsigned)h0 | ((unsigned)h1<<16), (unsigned)h2 | ((unsigned)h3<<16) };
        uint2 pl = { (unsigned)g0 | ((unsigned)g1<<16), (unsigned)g2 | ((unsigned)g3<<16) };
        *(uint2*)&Ah[r*72 + c4] = ph;
        *(uint2*)&Al[r*72 + c4] = pl;
      }
    }
    // B-stage: pure copy of preconverted bf16 hi/lo (16B chunks).
    for (int c = t; c < TN*8; c += 256){
      int n  = c >> 3;
      int k8 = (c & 7) * 8;
      *(short8*)&Bh[n*72 + k8] =
          *(const short8*)(jb.Wth + (size_t)(n0 + n)*KK + kt + k8);
      *(short8*)&Bl[n*72 + k8] =
          *(const short8*)(jb.Wtl + (size_t)(n0 + n)*KK + kt + k8);
    }
    __syncthreads();
    #pragma unroll
    for (int ks=0; ks<2; ks++){
      const int koff = ks*32 + lq*8;
      short8 a_h = *(const short8*)&Ah[(wv*16+lr)*72 + koff];
      short8 a_l;
      if constexpr (!BF16A) a_l = *(const short8*)&Al[(wv*16+lr)*72 + koff];
      #pragma unroll
      for (int nt=0; nt<NT; nt++){
        short8 b_h = *(const short8*)&Bh[(nt*16+lr)*72 + koff];
        short8 b_l = *(const short8*)&Bl[(nt*16+lr)*72 + koff];
        acc[nt] = __builtin_amdgcn_mfma_f32_16x16x32_bf16(a_h, b_h, acc[nt], 0,0,0);
        acc[nt] = __builtin_amdgcn_mfma_f32_16x16x32_bf16(a_h, b_l, acc[nt], 0,0,0);
        if constexpr (!BF16A)
          acc[nt] = __builtin_amdgcn_mfma_f32_16x16x32_bf16(a_l, b_h, acc[nt], 0,0,0);
      }
    }
    __syncthreads();
  }
  float ls[LOGIT ? 4 : 1][LOGIT ? 4 : 1];   // [r][h]
  float ld_[LOGIT ? 4 : 1][LOGIT ? 4 : 1];
  if constexpr (LOGIT){
    #pragma unroll
    for (int r=0;r<4;r++)
      #pragma unroll
      for (int h=0;h<4;h++){ ls[r][h]=0.f; ld_[r][h]=0.f; }
  }
  #pragma unroll
  for (int nt=0; nt<NT; nt++){
    int n = n0 + nt*16 + lr;
    float bv = jb.bias ? jb.bias[n] : 0.f;
    #pragma unroll
    for (int r=0;r<4;r++){
      int m = m0 + wv*16 + lq*4 + r;
      if (m < M){
        float o = acc[nt][r] + bv;
        if (ELU) o = elu_f(o);
        if constexpr (LG){
          if (n < 32)       ((unsigned short*)jb.C)[(size_t)m*32 + n] = f2bf(o);
          else if (n == 32) jb.outA[m] = o;
          else if (n == 33) jb.outB[m] = o;
        } else {
          if (BF16OUT) ((unsigned short*)jb.C)[(size_t)m*N + n] = f2bf(o);
          else         ((float*)jb.C)[(size_t)m*N + n] = o;
        }
        if constexpr (LOGIT){
          #pragma unroll
          for (int h=0;h<4;h++){
            ls[r][h]  = fmaf(o, CwS[h*64 + n], ls[r][h]);
            ld_[r][h] = fmaf(o, CwD[h*64 + n], ld_[r][h]);
          }
        }
      }
    }
  }
  if constexpr (LOGIT){
    // reduce over the 16 lr-lanes (channels), then lane lr==0 writes 4 rows x 4 heads
    #pragma unroll
    for (int r=0;r<4;r++)
      #pragma unroll
      for (int h=0;h<4;h++){
        float a = ls[r][h], d = ld_[r][h];
        #pragma unroll
        for (int off=1; off<16; off<<=1){
          a += __shfl_xor(a, off, 64);
          d += __shfl_xor(d, off, 64);
        }
        ls[r][h]=a; ld_[r][h]=d;
      }
    if (lr == 0){
      #pragma unroll
      for (int r=0;r<4;r++){
        int m = m0 + wv*16 + lq*4 + r;
        if (m < M){
          #pragma unroll
          for (int h=0;h<4;h++){
            jb.outA[(size_t)m*4 + h] = ls[r][h];
            jb.outB[(size_t)m*4 + h] = ld_[r][h];
          }
        }
      }
    }
  }
}

// ---------------- per-head block GEMM: hi1[m, h*64+n] = elu((agg_h @ Ws_h)/den + b) ----
struct HgJob {
  const unsigned short* A;            // bf16 [M,256]
  const unsigned short* Wth;          // [256][64] bf16 hi (transposed, n-major)
  const unsigned short* Wtl;
  const float* den;                   // [M,4]
  const float* bias; unsigned short* out;   // out bf16 [M,256]
};
__global__ __launch_bounds__(256) void hgemm_kernel(HgJob j0, HgJob j1){
  const HgJob jb = blockIdx.z ? j1 : j0;
  const int head = blockIdx.y;
  const int m0 = blockIdx.x*64;
  __shared__ __align__(16) unsigned short Ah[64*72];
  __shared__ __align__(16) unsigned short Bh[64*72];
  __shared__ __align__(16) unsigned short Bl[64*72];
  const int t = threadIdx.x;
  const int wv = t>>6, l = t&63;
  const int lr = l&15, lq = l>>4;
  floatx4 acc[4];
  #pragma unroll
  for (int i=0;i<4;i++) acc[i] = (floatx4){0.f,0.f,0.f,0.f};
  #pragma unroll
  for (int i=0;i<2;i++){
    int li = t + i*256;
    int r = li >> 3, c8 = (li & 7)*8;
    short8 v = {0,0,0,0,0,0,0,0};
    if (m0 + r < NN) v = *(const short8*)(jb.A + (size_t)(m0+r)*256 + head*64 + c8);
    *(short8*)&Ah[r*72 + c8] = v;
  }
  // B-stage: copy head slice rows (head*64 + n), K=64
  #pragma unroll
  for (int i=0;i<2;i++){
    int c  = t + i*256;
    int n  = c >> 3;
    int k8 = (c & 7) * 8;
    *(short8*)&Bh[n*72 + k8] =
        *(const short8*)(jb.Wth + (size_t)(head*64 + n)*64 + k8);
    *(short8*)&Bl[n*72 + k8] =
        *(const short8*)(jb.Wtl + (size_t)(head*64 + n)*64 + k8);
  }
  __syncthreads();
  #pragma unroll
  for (int ks=0; ks<2; ks++){
    const int koff = ks*32 + lq*8;
    short8 a_h = *(const short8*)&Ah[(wv*16+lr)*72 + koff];
    #pragma unroll
    for (int nt=0; nt<4; nt++){
      short8 b_h = *(const short8*)&Bh[(nt*16+lr)*72 + koff];
      short8 b_l = *(const short8*)&Bl[(nt*16+lr)*72 + koff];
      acc[nt] = __builtin_amdgcn_mfma_f32_16x16x32_bf16(a_h, b_h, acc[nt], 0,0,0);
      acc[nt] = __builtin_amdgcn_mfma_f32_16x16x32_bf16(a_h, b_l, acc[nt], 0,0,0);
    }
  }
  float inv[4];
  #pragma unroll
  for (int r=0;r<4;r++){
    int m = m0 + wv*16 + lq*4 + r;
    inv[r] = (m < NN) ? 1.f/(jb.den[(size_t)m*4 + head] + 1e-16f) : 0.f;
  }
  #pragma unroll
  for (int nt=0; nt<4; nt++){
    int col = head*64 + nt*16 + lr;
    float bv = jb.bias[col];
    #pragma unroll
    for (int r=0;r<4;r++){
      int m = m0 + wv*16 + lq*4 + r;
      if (m < NN)
        jb.out[(size_t)m*256 + col] = f2bf(elu_f(acc[nt][r]*inv[r] + bv));
    }
  }
}

// ---------------- collapse attention vectors ----------------
struct CollapseJob { const float* W; const float* a; float* out; int K,H,C; };
struct CollapseArgs { CollapseJob j[8]; };
__global__ void collapse_kernel(CollapseArgs args){
  CollapseJob jb = args.j[blockIdx.x];
  int t = threadIdx.x;
  if (t < jb.K * jb.H){
    int k = t / jb.H, h = t % jb.H;
    const float* wr = jb.W + (size_t)k * (jb.H*jb.C) + h*jb.C;
    const float* ar = jb.a + h*jb.C;
    float s = 0.f;
    for (int c=0;c<jb.C;c++) s += wr[c]*ar[c];
    jb.out[h*jb.K + k] = s;   // layout [H,K]
  }
}

// ---------------- layer-0 pre-aggregation over hu/hi rows ----------------
// 8 dsts per wave, 8 lanes per dst, 8 channels per lane: edge-sum is fully
// within-lane => no cross-lane reduction epilogue. Unroll-4 edge loop: 4
// x-row gathers in flight per iteration (gather-latency hiding).
struct AggPJob {
  const int* offs; const int* ssrc;
  const unsigned short* x;     // bf16 [NN,64]
  const unsigned short* coef;  // bf16 [E,4]
  unsigned short* agg;         // bf16 [NN,256]
  float* den;                  // fp32 [NN,4]
};
__global__ __launch_bounds__(256) void aggpre_kernel(AggPJob ja, AggPJob jbb){
  const AggPJob jb = blockIdx.y ? jbb : ja;
  const int tid = threadIdx.x;
  const int lane = tid & 63, wid = tid >> 6;
  const int grp = lane >> 3;       // dst group within wave (0..7)
  const int cl  = lane & 7;        // channel lane within group
  const int c8  = cl * 8;          // channel base (8 bf16 = 16B per lane)
  const int dst = blockIdx.x*32 + wid*8 + grp;
  if (dst >= NN) return;
  const int b0 = jb.offs[dst], b1 = jb.offs[dst+1];
  float acc[4][8];
  float den[4] = {0.f,0.f,0.f,0.f};
  #pragma unroll
  for (int h=0;h<4;h++)
    #pragma unroll
    for (int c=0;c<8;c++) acc[h][c]=0.f;
  int e = b0;
  // unroll-4: batch 4 independent x gathers + coef loads per iteration
  for (; e+3 < b1; e += 4){
    int s0 = jb.ssrc[e];
    int s1 = jb.ssrc[e+1];
    int s2 = jb.ssrc[e+2];
    int s3 = jb.ssrc[e+3];
    uint4 q0 = *(const uint4*)(jb.x + ((size_t)s0<<6) + c8);
    uint4 q1 = *(const uint4*)(jb.x + ((size_t)s1<<6) + c8);
    uint4 q2 = *(const uint4*)(jb.x + ((size_t)s2<<6) + c8);
    uint4 q3 = *(const uint4*)(jb.x + ((size_t)s3<<6) + c8);
    uint2 w0 = *(const uint2*)(jb.coef + (size_t)e*4);
    uint2 w1 = *(const uint2*)(jb.coef + (size_t)(e+1)*4);
    uint2 w2 = *(const uint2*)(jb.coef + (size_t)(e+2)*4);
    uint2 w3 = *(const uint2*)(jb.coef + (size_t)(e+3)*4);
    agg_pair(acc, den, q0, q1, w0, w1);
    agg_pair(acc, den, q2, q3, w2, w3);
  }
  if (e+1 < b1){
    int s0 = jb.ssrc[e];
    int s1 = jb.ssrc[e+1];
    uint4 q0 = *(const uint4*)(jb.x + ((size_t)s0<<6) + c8);
    uint4 q1 = *(const uint4*)(jb.x + ((size_t)s1<<6) + c8);
    uint2 w0 = *(const uint2*)(jb.coef + (size_t)e*4);
    uint2 w1 = *(const uint2*)(jb.coef + (size_t)(e+1)*4);
    agg_pair(acc, den, q0, q1, w0, w1);
    e += 2;
  }
  if (e < b1){  // odd-degree tail: single edge, scalar path
    int s = jb.ssrc[e];
    uint4 q = *(const uint4*)(jb.x + ((size_t)s<<6) + c8);
    uint2 w = *(const uint2*)(jb.coef + (size_t)e*4);
    float wf[4] = { bf2f(w.x & 0xffffu), bf2f(w.x >> 16),
                    bf2f(w.y & 0xffffu), bf2f(w.y >> 16) };
    float xf[8] = { bf2f(q.x & 0xffffu), bf2f(q.x >> 16),
                    bf2f(q.y & 0xffffu), bf2f(q.y >> 16),
                    bf2f(q.z & 0xffffu), bf2f(q.z >> 16),
                    bf2f(q.w & 0xffffu), bf2f(q.w >> 16) };
    #pragma unroll
    for (int h=0;h<4;h++){
      den[h] += wf[h];
      #pragma unroll
      for (int c=0;c<8;c++) acc[h][c] += wf[h]*xf[c];
    }
  }
  // epilogue: pack + store only (no shuffles)
  #pragma unroll
  for (int h=0;h<4;h++){
    uint2 plo = bf4_pack(make_float4(acc[h][0],acc[h][1],acc[h][2],acc[h][3]));
    uint2 phi = bf4_pack(make_float4(acc[h][4],acc[h][5],acc[h][6],acc[h][7]));
    uint4 pk = { plo.x, plo.y, phi.x, phi.y };
    *(uint4*)(jb.agg + (size_t)dst*256 + h*64 + c8) = pk;
  }
  if (cl == 0)
    *(float4*)(jb.den + (size_t)dst*4) = make_float4(den[0],den[1],den[2],den[3]);
}

// ---------------- layer-1 aggregation (aggpre-style: 8 dst/wave, shuffle-free) ----
// 8 lanes per dst, 4 f32 cols per lane (32 cols total). Edge-sum fully
// within-lane; softmax weight computed inline (redundant x8, cheap); epilogue
// is a single float4 store. Unroll-4 edge loop for gather MLP.
struct Agg1Job {
  const int* offs; const int* ssrc;
  const unsigned short* hs;   // bf16 [NN,32]
  const float* als; const float* ald;  // layer-1 logits
  const float* bias; float* out;
};
__global__ __launch_bounds__(256) void agg1_kernel(Agg1Job ja, Agg1Job jbb){
  const Agg1Job jb = blockIdx.y ? jbb : ja;
  const int tid = threadIdx.x;
  const int lane = tid & 63, wid = tid >> 6;
  const int grp = lane >> 3;       // dst group within wave (0..7)
  const int cl  = lane & 7;        // col lane within group
  const int c4  = cl * 4;          // col base (4 f32 outputs per lane)
  const int dst = blockIdx.x*32 + wid*8 + grp;
  if (dst >= NN) return;
  const int b0 = jb.offs[dst], b1 = jb.offs[dst+1];
  const float ad = jb.ald[dst];
  float acc[4] = {0.f,0.f,0.f,0.f};
  float den = 0.f;
  int e = b0;
  for (; e+3 < b1; e += 4){
    int s0 = jb.ssrc[e];
    int s1 = jb.ssrc[e+1];
    int s2 = jb.ssrc[e+2];
    int s3 = jb.ssrc[e+3];
    float a0 = jb.als[s0];
    float a1 = jb.als[s1];
    float a2 = jb.als[s2];
    float a3 = jb.als[s3];
    float4 v0 = bf4_load(jb.hs + ((size_t)s0<<5) + c4);
    float4 v1 = bf4_load(jb.hs + ((size_t)s1<<5) + c4);
    float4 v2 = bf4_load(jb.hs + ((size_t)s2<<5) + c4);
    float4 v3 = bf4_load(jb.hs + ((size_t)s3<<5) + c4);
    float w0 = __expf(lrelu_f(a0 + ad));
    float w1 = __expf(lrelu_f(a1 + ad));
    float w2 = __expf(lrelu_f(a2 + ad));
    float w3 = __expf(lrelu_f(a3 + ad));
    acc[0] += w0*v0.x + w1*v1.x + w2*v2.x + w3*v3.x;
    acc[1] += w0*v0.y + w1*v1.y + w2*v2.y + w3*v3.y;
    acc[2] += w0*v0.z + w1*v1.z + w2*v2.z + w3*v3.z;
    acc[3] += w0*v0.w + w1*v1.w + w2*v2.w + w3*v3.w;
    den += (w0 + w1) + (w2 + w3);
  }
  for (; e < b1; ++e){
    int s = jb.ssrc[e];
    float w = __expf(lrelu_f(jb.als[s] + ad));
    float4 v = bf4_load(jb.hs + ((size_t)s<<5) + c4);
    acc[0] += w*v.x; acc[1] += w*v.y; acc[2] += w*v.z; acc[3] += w*v.w;
    den += w;
  }
  const float inv = 1.f/(den + 1e-16f);
  float4 b = *(const float4*)(jb.bias + c4);
  float4 o = make_float4(acc[0]*inv+b.x, acc[1]*inv+b.y,
                         acc[2]*inv+b.z, acc[3]*inv+b.w);
  *(float4*)(jb.out + (size_t)dst*32 + c4) = o;
}

// ---------------- host glue ----------------
extern "C" void kernel_launch(void* const* d_in, const int* in_sizes, int n_in,
                              void* d_out, int out_size, void* d_ws, size_t ws_size,
                              hipStream_t stream)
{
  (void)in_sizes; (void)n_in; (void)out_size; (void)ws_size;
  const float* x_user   = (const float*)d_in[0];
  const float* x_item   = (const float*)d_in[1];
  const int*   e_u2i    = (const int*)  d_in[2];
  const int*   e_i2u    = (const int*)  d_in[3];
  const float* p_user_w = (const float*)d_in[4];
  const float* p_user_b = (const float*)d_in[5];
  const float* p_item_w = (const float*)d_in[6];
  const float* p_item_b = (const float*)d_in[7];
  const float* l0_u2i_ws=(const float*)d_in[8];
  const float* l0_u2i_wd=(const float*)d_in[9];
  const float* l0_u2i_as=(const float*)d_in[10];
  const float* l0_u2i_ad=(const float*)d_in[11];
  const float* l0_u2i_b =(const float*)d_in[12];
  const float* l0_i2u_ws=(const float*)d_in[13];
  const float* l0_i2u_wd=(const float*)d_in[14];
  const float* l0_i2u_as=(const float*)d_in[15];
  const float* l0_i2u_ad=(const float*)d_in[16];
  const float* l0_i2u_b =(const float*)d_in[17];
  const float* l1_u2i_ws=(const float*)d_in[18];
  const float* l1_u2i_wd=(const float*)d_in[19];
  const float* l1_u2i_as=(const float*)d_in[20];
  const float* l1_u2i_ad=(const float*)d_in[21];
  const float* l1_u2i_b =(const float*)d_in[22];
  const float* l1_i2u_ws=(const float*)d_in[23];
  const float* l1_i2u_wd=(const float*)d_in[24];
  const float* l1_i2u_as=(const float*)d_in[25];
  const float* l1_i2u_ad=(const float*)d_in[26];
  const float* l1_i2u_b =(const float*)d_in[27];

  char* base = (char*)d_ws;
  size_t off = 0;
  auto alloc = [&](size_t bytes)->void*{
    void* p = base + off;
    off += (bytes + 255) & ~(size_t)255;
    return p;
  };
  int* offs_u2i = (int*)alloc((size_t)(NN+1)*sizeof(int));
  int* offs_i2u = (int*)alloc((size_t)(NN+1)*sizeof(int));
  int* ssrc_u2i = (int*)alloc((size_t)NE*sizeof(int));
  int* ssrc_i2u = (int*)alloc((size_t)NE*sizeof(int));
  int* ghist    = (int*)alloc((size_t)2*200*sizeof(int));
  int* gbase    = (int*)alloc((size_t)2*200*sizeof(int));
  int* gcur     = (int*)alloc((size_t)2*200*sizeof(int));
  unsigned short* coef0_u2i = (unsigned short*)alloc((size_t)NE*4*sizeof(unsigned short));
  unsigned short* coef0_i2u = (unsigned short*)alloc((size_t)NE*4*sizeof(unsigned short));
  unsigned short* hu = (unsigned short*)alloc((size_t)NN*64*sizeof(unsigned short));
  unsigned short* hi = (unsigned short*)alloc((size_t)NN*64*sizeof(unsigned short));
  unsigned short* agg_u2i = (unsigned short*)alloc((size_t)NN*256*sizeof(unsigned short));
  unsigned short* agg_i2u = (unsigned short*)alloc((size_t)NN*256*sizeof(unsigned short));
  float* den_u2i = (float*)alloc((size_t)NN*4*sizeof(float));
  float* den_i2u = (float*)alloc((size_t)NN*4*sizeof(float));
  unsigned short* hu1 = (unsigned short*)alloc((size_t)NN*256*sizeof(unsigned short));
  unsigned short* hi1 = (unsigned short*)alloc((size_t)NN*256*sizeof(unsigned short));
  unsigned short* hs1_u2i = (unsigned short*)alloc((size_t)NN*32*sizeof(unsigned short));
  unsigned short* hs1_i2u = (unsigned short*)alloc((size_t)NN*32*sizeof(unsigned short));
  float* als0_u2i = (float*)alloc((size_t)NN*4*sizeof(float));
  float* ald0_u2i = (float*)alloc((size_t)NN*4*sizeof(float));
  float* als0_i2u = (float*)alloc((size_t)NN*4*sizeof(float));
  float* ald0_i2u = (float*)alloc((size_t)NN*4*sizeof(float));
  float* als1_u2i = (float*)alloc((size_t)NN*sizeof(float));
  float* ald1_u2i = (float*)alloc((size_t)NN*sizeof(float));
  float* als1_i2u = (float*)alloc((size_t)NN*sizeof(float));
  float* ald1_i2u = (float*)alloc((size_t)NN*sizeof(float));
  float* cw0s_u2i = (float*)alloc(256*sizeof(float));
  float* cw0d_u2i = (float*)alloc(256*sizeof(float));
  float* cw0s_i2u = (float*)alloc(256*sizeof(float));
  float* cw0d_i2u = (float*)alloc(256*sizeof(float));
  float* cw1s_u2i = (float*)alloc(256*sizeof(float));
  float* cw1d_u2i = (float*)alloc(256*sizeof(float));
  float* cw1s_i2u = (float*)alloc(256*sizeof(float));
  float* cw1d_i2u = (float*)alloc(256*sizeof(float));
  // transposed bf16 hi/lo weight images
  unsigned short* wt_pu_h  = (unsigned short*)alloc((size_t)64*128*sizeof(unsigned short));
  unsigned short* wt_pu_l  = (unsigned short*)alloc((size_t)64*128*sizeof(unsigned short));
  unsigned short* wt_pi_h  = (unsigned short*)alloc((size_t)64*128*sizeof(unsigned short));
  unsigned short* wt_pi_l  = (unsigned short*)alloc((size_t)64*128*sizeof(unsigned short));
  unsigned short* wt_l0u_h = (unsigned short*)alloc((size_t)256*64*sizeof(unsigned short));
  unsigned short* wt_l0u_l = (unsigned short*)alloc((size_t)256*64*sizeof(unsigned short));
  unsigned short* wt_l0i_h = (unsigned short*)alloc((size_t)256*64*sizeof(unsigned short));
  unsigned short* wt_l0i_l = (unsigned short*)alloc((size_t)256*64*sizeof(unsigned short));
  unsigned short* wt_wcu_h = (unsigned short*)alloc((size_t)48*256*sizeof(unsigned short));
  unsigned short* wt_wcu_l = (unsigned short*)alloc((size_t)48*256*sizeof(unsigned short));
  unsigned short* wt_wci_h = (unsigned short*)alloc((size_t)48*256*sizeof(unsigned short));
  unsigned short* wt_wci_l = (unsigned short*)alloc((size_t)48*256*sizeof(unsigned short));
  // pairs scratch aliases hu1/hi1: consumed by part2 before hgemm writes them
  int2* pairs_u2i = (int2*)hu1;
  int2* pairs_i2u = pairs_u2i + NE;

  const int GM = (NN + 63)/64;

  // ---- bucket sort stage A ----
  hipMemsetAsync(ghist, 0, (size_t)2*200*sizeof(int), stream);
  ghist_kernel<<<dim3(256,2), 256, 0, stream>>>(e_u2i, e_i2u, ghist);
  gscan_kernel<<<1, 256, 0, stream>>>(ghist, gbase, gcur);
  part1_kernel<<<dim3((NE+TILE1-1)/TILE1,2), 256, 0, stream>>>(
      e_u2i, e_i2u, gcur, pairs_u2i, pairs_i2u);

  // ---- collapse attention vectors ----
  CollapseArgs ca;
  ca.j[0] = {l0_u2i_ws, l0_u2i_as, cw0s_u2i, 64, 4, 64};
  ca.j[1] = {l0_u2i_wd, l0_u2i_ad, cw0d_u2i, 64, 4, 64};
  ca.j[2] = {l0_i2u_ws, l0_i2u_as, cw0s_i2u, 64, 4, 64};
  ca.j[3] = {l0_i2u_wd, l0_i2u_ad, cw0d_i2u, 64, 4, 64};
  ca.j[4] = {l1_u2i_ws, l1_u2i_as, cw1s_u2i, 256, 1, 32};
  ca.j[5] = {l1_u2i_wd, l1_u2i_ad, cw1d_u2i, 256, 1, 32};
  ca.j[6] = {l1_i2u_ws, l1_i2u_as, cw1s_i2u, 256, 1, 32};
  ca.j[7] = {l1_i2u_wd, l1_i2u_ad, cw1d_i2u, 256, 1, 32};
  collapse_kernel<<<8, 256, 0, stream>>>(ca);

  // ---- weight pre-conversion (transposed bf16 hi/lo; Wc built with cw cols) ----
  WcvArgs wa;
  wa.j[0] = {p_user_w,  nullptr,   nullptr,   wt_pu_h,  wt_pu_l,  128, 64, 0};
  wa.j[1] = {p_item_w,  nullptr,   nullptr,   wt_pi_h,  wt_pi_l,  128, 64, 0};
  wa.j[2] = {l0_u2i_ws, nullptr,   nullptr,   wt_l0u_h, wt_l0u_l, 64, 256, 0};
  wa.j[3] = {l0_i2u_ws, nullptr,   nullptr,   wt_l0i_h, wt_l0i_l, 64, 256, 0};
  wa.j[4] = {l1_u2i_ws, cw1s_u2i,  cw1d_i2u,  wt_wcu_h, wt_wcu_l, 256, 48, 1};
  wa.j[5] = {l1_i2u_ws, cw1s_i2u,  cw1d_u2i,  wt_wci_h, wt_wci_l, 256, 48, 1};
  wconv_kernel<<<dim3(64,6), 256, 0, stream>>>(wa);

  // ---- input projections (+bias +ELU) -> bf16, with fused layer-0 logits ----
  mgemm_kernel<4,128,true,true,false,false,true><<<dim3(GM,1,2), 256, 0, stream>>>(
      MgJob{x_user, wt_pu_h, wt_pu_l, p_user_b, hu, als0_u2i, ald0_i2u, cw0s_u2i, cw0d_i2u},
      MgJob{x_item, wt_pi_h, wt_pi_l, p_item_b, hi, als0_i2u, ald0_u2i, cw0s_i2u, cw0d_u2i},
      NN, 64);

  // ---- bucket sort stage B ----
  part2_kernel<<<dim3(GB,2), 256, 0, stream>>>(
      Part2Job{pairs_u2i, gbase,       als0_u2i, ald0_u2i, ssrc_u2i, offs_u2i, coef0_u2i},
      Part2Job{pairs_i2u, gbase + 200, als0_i2u, ald0_i2u, ssrc_i2u, offs_i2u, coef0_i2u});

  // ---- layer 0: pre-aggregate hu/hi rows (8 dst/wave, unroll-4 gathers) ----
  aggpre_kernel<<<dim3((NN+31)/32,2), 256, 0, stream>>>(
      AggPJob{offs_u2i, ssrc_u2i, hu, coef0_u2i, agg_u2i, den_u2i},
      AggPJob{offs_i2u, ssrc_i2u, hi, coef0_i2u, agg_i2u, den_i2u});

  // ---- layer 0: per-head GEMM + den-divide + bias + ELU -> hi1/hu1 bf16 ----
  hgemm_kernel<<<dim3(GM,4,2), 256, 0, stream>>>(
      HgJob{agg_u2i, wt_l0u_h, wt_l0u_l, den_u2i, l0_u2i_b, hi1},
      HgJob{agg_i2u, wt_l0i_h, wt_l0i_l, den_i2u, l0_i2u_b, hu1});

  // ---- layer 1: feature GEMMs with fused logit columns ----
  mgemm_kernel<3,256,false,true,true,true,false><<<dim3(GM,1,2), 256, 0, stream>>>(
      MgJob{hu1, wt_wcu_h, wt_wcu_l, nullptr, hs1_u2i, als1_u2i, ald1_i2u, nullptr, nullptr},
      MgJob{hi1, wt_wci_h, wt_wci_l, nullptr, hs1_i2u, als1_i2u, ald1_u2i, nullptr, nullptr},
      NN, 48);

  // ---- layer 1: aggregate (+bias), shuffle-free 8 dst/wave ----
  float* hu2 = (float*)d_out;                  // first tuple element (users, i2u dst)
  float* hi2 = (float*)d_out + (size_t)NN*32;  // second tuple element (items, u2i dst)
  agg1_kernel<<<dim3((NN+31)/32,2), 256, 0, stream>>>(
      Agg1Job{offs_u2i, ssrc_u2i, hs1_u2i, als1_u2i, ald1_u2i, l1_u2i_b, hi2},
      Agg1Job{offs_i2u, ssrc_i2u, hs1_i2u, als1_i2u, ald1_i2u, l1_i2u_b, hu2});
}

// Round 12
// 348.795 us; speedup vs baseline: 1.0732x; 1.0013x over previous
//
#include <hip/hip_runtime.h>
#include <cstdint>
#include <cstddef>

#define NN 50000
#define NE 800000
#define GB 196        // coarse buckets = ceil(NN/256)
#define TILE1 4096    // edges per part1 block
#define CAP 8192      // max edges per bucket in part2 LDS (mean 4082)

typedef __attribute__((ext_vector_type(8))) short short8;
typedef __attribute__((ext_vector_type(4))) float floatx4;

__device__ __forceinline__ float lrelu_f(float x){ return x >= 0.f ? x : 0.2f*x; }
__device__ __forceinline__ float elu_f(float x){ return x > 0.f ? x : __expf(x) - 1.f; }

__device__ __forceinline__ unsigned short f2bf(float f){
  unsigned int u = __float_as_uint(f);
  u += 0x7FFFu + ((u >> 16) & 1u);
  return (unsigned short)(u >> 16);
}
__device__ __forceinline__ float bf2f(unsigned int us){
  return __uint_as_float(us << 16);
}
__device__ __forceinline__ float4 bf4_load(const unsigned short* p){
  uint2 q = *(const uint2*)p;
  return make_float4(bf2f(q.x & 0xffffu), bf2f(q.x >> 16),
                     bf2f(q.y & 0xffffu), bf2f(q.y >> 16));
}
__device__ __forceinline__ uint2 bf4_pack(float4 o){
  uint2 p;
  p.x = (unsigned)f2bf(o.x) | ((unsigned)f2bf(o.y) << 16);
  p.y = (unsigned)f2bf(o.z) | ((unsigned)f2bf(o.w) << 16);
  return p;
}
__device__ __forceinline__ void split_bf(float a, unsigned short& h, unsigned short& l){
  h = f2bf(a);
  l = f2bf(a - bf2f(h));
}

// v_dot2_f32_bf16: acc += a.bf16[0]*b.bf16[0] + a.bf16[1]*b.bf16[1]
__device__ __forceinline__ float dot2bf(float acc, unsigned a, unsigned b){
  asm("v_dot2_f32_bf16 %0, %1, %2, %0" : "+v"(acc) : "v"(a), "v"(b));
  return acc;
}

// process one edge PAIR (bf16 operands stay packed; sums stay within-lane)
__device__ __forceinline__ void agg_pair(float (&acc)[4][8], float (&den)[4],
                                         uint4 q0, uint4 q1, uint2 w0, uint2 w1){
  const unsigned ONE2 = 0x3F803F80u;  // packed bf16 (1.0, 1.0)
  unsigned wp[4];
  wp[0] = __builtin_amdgcn_perm(w1.x, w0.x, 0x05040100u);
  wp[1] = __builtin_amdgcn_perm(w1.x, w0.x, 0x07060302u);
  wp[2] = __builtin_amdgcn_perm(w1.y, w0.y, 0x05040100u);
  wp[3] = __builtin_amdgcn_perm(w1.y, w0.y, 0x07060302u);
  unsigned xp[8];
  xp[0] = __builtin_amdgcn_perm(q1.x, q0.x, 0x05040100u);
  xp[1] = __builtin_amdgcn_perm(q1.x, q0.x, 0x07060302u);
  xp[2] = __builtin_amdgcn_perm(q1.y, q0.y, 0x05040100u);
  xp[3] = __builtin_amdgcn_perm(q1.y, q0.y, 0x07060302u);
  xp[4] = __builtin_amdgcn_perm(q1.z, q0.z, 0x05040100u);
  xp[5] = __builtin_amdgcn_perm(q1.z, q0.z, 0x07060302u);
  xp[6] = __builtin_amdgcn_perm(q1.w, q0.w, 0x05040100u);
  xp[7] = __builtin_amdgcn_perm(q1.w, q0.w, 0x07060302u);
  #pragma unroll
  for (int h=0;h<4;h++){
    den[h] = dot2bf(den[h], wp[h], ONE2);
    #pragma unroll
    for (int c=0;c<8;c++) acc[h][c] = dot2bf(acc[h][c], wp[h], xp[c]);
  }
}

// ---------------- two-level bucket sort of edges by dst ----------------
__global__ __launch_bounds__(256) void ghist_kernel(const int* __restrict__ e0,
                                                    const int* __restrict__ e1,
                                                    int* __restrict__ ghist){
  const int ty = blockIdx.y;
  const int* e = ty ? e1 : e0;
  __shared__ int h[GB];
  for (int j=threadIdx.x; j<GB; j+=256) h[j]=0;
  __syncthreads();
  for (int i = blockIdx.x*256 + threadIdx.x; i < NE; i += 256*256)
    atomicAdd(&h[e[NE+i]>>8], 1);
  __syncthreads();
  for (int j=threadIdx.x; j<GB; j+=256) if (h[j]) atomicAdd(&ghist[ty*200+j], h[j]);
}

__global__ __launch_bounds__(256) void gscan_kernel(const int* __restrict__ ghist,
                                                    int* __restrict__ gbase,
                                                    int* __restrict__ gcur){
  __shared__ int wb[4];
  const int t = threadIdx.x, wv = t>>6, l = t&63;
  for (int ty=0; ty<2; ++ty){
    int v = (t < GB) ? ghist[ty*200+t] : 0;
    int sum = v;
    #pragma unroll
    for (int off=1; off<64; off<<=1){
      int x = __shfl_up(sum, off, 64);
      if (l >= off) sum += x;
    }
    if (l == 63) wb[wv] = sum;
    __syncthreads();
    int wbase = 0;
    #pragma unroll
    for (int w=0; w<4; ++w) if (w < wv) wbase += wb[w];
    int excl = wbase + sum - v;
    if (t <= GB) gbase[ty*200+t] = excl;
    if (t <  GB) gcur [ty*200+t] = excl;
    __syncthreads();
  }
}

// partition with LDS staging: global writes are contiguous per-bucket runs
__global__ __launch_bounds__(256) void part1_kernel(const int* __restrict__ e0,
                                                    const int* __restrict__ e1,
                                                    int* __restrict__ gcur,
                                                    int2* __restrict__ p0,
                                                    int2* __restrict__ p1){
  const int ty = blockIdx.y;
  const int* e = ty ? e1 : e0;
  int2* pairs = ty ? p1 : p0;
  __shared__ int cnt[256];
  __shared__ int lstart[256];
  __shared__ int lcur[256];
  __shared__ int curg[GB];
  __shared__ int lsrc[TILE1];
  __shared__ int ldst[TILE1];
  __shared__ int wb[4];
  const int t = threadIdx.x;
  cnt[t] = 0;
  __syncthreads();
  int dreg[16], sreg[16];
  const int base = blockIdx.x*TILE1;
  const int ntile = min(TILE1, NE - base);
  #pragma unroll
  for (int it=0; it<16; ++it){
    int i = base + it*256 + t;
    int d = -1, s = 0;
    if (i < NE){ d = e[NE+i]; s = e[i]; atomicAdd(&cnt[d>>8], 1); }
    dreg[it] = d; sreg[it] = s;
  }
  __syncthreads();
  int c = cnt[t], sum = c;
  #pragma unroll
  for (int off=1; off<64; off<<=1){
    int x = __shfl_up(sum, off, 64);
    if ((t&63) >= off) sum += x;
  }
  if ((t&63) == 63) wb[t>>6] = sum;
  __syncthreads();
  int wbase = 0;
  #pragma unroll
  for (int w=0; w<4; ++w) if (w < (t>>6)) wbase += wb[w];
  int excl = wbase + sum - c;
  lstart[t] = excl;
  lcur[t] = excl;
  if (t < GB && c > 0) curg[t] = atomicAdd(&gcur[ty*200+t], c);
  __syncthreads();
  #pragma unroll
  for (int it=0; it<16; ++it){
    int d = dreg[it];
    if (d >= 0){
      int pos = atomicAdd(&lcur[d>>8], 1);
      lsrc[pos] = sreg[it];
      ldst[pos] = d;
    }
  }
  __syncthreads();
  for (int i=t; i<ntile; i+=256){
    int d = ldst[i];
    int j = d>>8;
    pairs[curg[j] + (i - lstart[j])] = make_int2(lsrc[i], d);
  }
}

// per-bucket LDS bin by dst + CSR offsets + fused layer-0 softmax weights (bf16).
struct Part2Job {
  const int2* pairs; const int* gbase;
  const float* als; const float* ald;   // [NN,4]
  int* ssrc; int* offs; unsigned short* coef;  // coef: [E,4] bf16
};
__global__ __launch_bounds__(256) void part2_kernel(Part2Job j0, Part2Job j1){
  const Part2Job jb = blockIdx.y ? j1 : j0;
  const int b = blockIdx.x;
  const int t = threadIdx.x;
  __shared__ int lcnt[256];
  __shared__ int lcur[256];
  __shared__ int wb[4];
  __shared__ int sorted_src[CAP];
  __shared__ unsigned char sorted_dl[CAP];
  const int gb0 = jb.gbase[b], gb1 = jb.gbase[b+1];
  const int n = gb1 - gb0;
  lcnt[t] = 0;
  __syncthreads();
  for (int i=t; i<n; i+=256)
    atomicAdd(&lcnt[jb.pairs[gb0+i].y - (b<<8)], 1);
  __syncthreads();
  int c = lcnt[t], sum = c;
  #pragma unroll
  for (int off=1; off<64; off<<=1){
    int x = __shfl_up(sum, off, 64);
    if ((t&63) >= off) sum += x;
  }
  if ((t&63) == 63) wb[t>>6] = sum;
  __syncthreads();
  int wbase = 0;
  #pragma unroll
  for (int w=0; w<4; ++w) if (w < (t>>6)) wbase += wb[w];
  int excl = wbase + sum - c;
  lcur[t] = excl;
  int g = (b<<8) + t;
  if (g <= NN) jb.offs[g] = gb0 + excl;
  __syncthreads();
  for (int i=t; i<n; i+=256){
    int2 pr = jb.pairs[gb0+i];
    int dl = pr.y - (b<<8);
    int pos = atomicAdd(&lcur[dl], 1);
    sorted_src[pos] = pr.x;
    sorted_dl[pos] = (unsigned char)dl;
  }
  __syncthreads();
  const float4* als4 = (const float4*)jb.als;
  const float4* ald4 = (const float4*)jb.ald;
  for (int i=t; i<n; i+=256){
    int s  = sorted_src[i];
    int dl = sorted_dl[i];
    float4 a  = als4[s];
    float4 ad = ald4[(b<<8)+dl];
    // no max-shift: |alpha| small at this model scale; softmax shift-invariant.
    float4 w;
    w.x = __expf(lrelu_f(a.x+ad.x));
    w.y = __expf(lrelu_f(a.y+ad.y));
    w.z = __expf(lrelu_f(a.z+ad.z));
    w.w = __expf(lrelu_f(a.w+ad.w));
    ((uint2*)jb.coef)[gb0+i] = bf4_pack(w);
    jb.ssrc[gb0+i] = s;
  }
}

// ---------------- weight pre-conversion: W[K][N] f32 -> transposed bf16 hi/lo ----
// mode 0: plain. mode 1: Wc build (n<32: Ws[k*32+n], n==32: cwS[k], n==33: cwD[k], else 0)
struct WcvJob {
  const float* W; const float* cwS; const float* cwD;
  unsigned short* Wth; unsigned short* Wtl;
  int K; int N; int mode;
};
struct WcvArgs { WcvJob j[6]; };
__global__ __launch_bounds__(256) void wconv_kernel(WcvArgs args){
  WcvJob jb = args.j[blockIdx.y];
  int idx = blockIdx.x*256 + threadIdx.x;
  if (idx >= jb.K * jb.N) return;
  int k = idx / jb.N, n = idx % jb.N;
  float val;
  if (jb.mode == 0) val = jb.W[(size_t)k*jb.N + n];
  else {
    if (n < 32)       val = jb.W[(size_t)k*32 + n];
    else if (n == 32) val = jb.cwS[k];
    else if (n == 33) val = jb.cwD[k];
    else              val = 0.f;
  }
  unsigned short h, g;
  split_bf(val, h, g);
  jb.Wth[(size_t)n*jb.K + k] = h;
  jb.Wtl[(size_t)n*jb.K + k] = g;
}

// ---------------- MFMA GEMM (proj): C = act(A[M,K] @ W[K,N] (+bias)) ----------------
// Two-phase LDS-staged structure (round-9 proven).
struct MgJob {
  const void* A;                     // f32 [M,KK] if !BF16A else bf16 [M,KK]
  const unsigned short* Wth;         // [N][KK] bf16 hi (transposed)
  const unsigned short* Wtl;         // [N][KK] bf16 lo
  const float* bias;
  void* C; float* outA; float* outB;
  const float* cwS; const float* cwD;
};
template<int NT, int KK, bool ELU, bool BF16OUT, bool BF16A, bool LG, bool LOGIT>
__global__ __launch_bounds__(256) void mgemm_kernel(MgJob j0, MgJob j1,
                                                    int M, int N)
{
  const MgJob jb = blockIdx.z ? j1 : j0;
  constexpr int TN = NT*16;
  __shared__ __align__(16) unsigned short Ah[64*72];
  __shared__ __align__(16) unsigned short Al[BF16A ? 8 : 64*72];
  __shared__ __align__(16) unsigned short Bh[TN*72];
  __shared__ __align__(16) unsigned short Bl[TN*72];
  __shared__ float CwS[LOGIT ? 256 : 1];
  __shared__ float CwD[LOGIT ? 256 : 1];
  const int t = threadIdx.x;
  const int m0 = blockIdx.x*64;
  const int n0 = blockIdx.y*TN;
  const int wv = t>>6, l = t&63;
  const int lr = l&15, lq = l>>4;
  if constexpr (LOGIT){ CwS[t] = jb.cwS[t]; CwD[t] = jb.cwD[t]; }
  floatx4 acc[NT];
  #pragma unroll
  for (int i=0;i<NT;i++) acc[i] = (floatx4){0.f,0.f,0.f,0.f};

  #pragma unroll
  for (int kt=0; kt<KK; kt+=64){
    if constexpr (BF16A){
      const unsigned short* A = (const unsigned short*)jb.A;
      #pragma unroll
      for (int i=0;i<2;i++){
        int li = t + i*256;
        int r = li >> 3, c8 = (li & 7)*8;
        short8 v = {0,0,0,0,0,0,0,0};
        if (m0 + r < M) v = *(const short8*)(A + (size_t)(m0+r)*KK + kt + c8);
        *(short8*)&Ah[r*72 + c8] = v;
      }
    } else {
      const float* A = (const float*)jb.A;
      #pragma unroll
      for (int i=0;i<4;i++){
        int li = t + i*256;
        int r = li >> 4, c4 = (li & 15)*4;
        float4 v = make_float4(0.f,0.f,0.f,0.f);
        if (m0 + r < M) v = *(const float4*)(A + (size_t)(m0+r)*KK + kt + c4);
        unsigned short h0,h1,h2,h3,g0,g1,g2,g3;
        split_bf(v.x,h0,g0); split_bf(v.y,h1,g1);
        split_bf(v.z,h2,g2); split_bf(v.w,h3,g3);
        uint2 ph = { (unsigned)h0 | ((unsigned)h1<<16), (unsigned)h2 | ((unsigned)h3<<16) };
        uint2 pl = { (unsigned)g0 | ((unsigned)g1<<16), (unsigned)g2 | ((unsigned)g3<<16) };
        *(uint2*)&Ah[r*72 + c4] = ph;
        *(uint2*)&Al[r*72 + c4] = pl;
      }
    }
    // B-stage: pure copy of preconverted bf16 hi/lo (16B chunks).
    for (int c = t; c < TN*8; c += 256){
      int n  = c >> 3;
      int k8 = (c & 7) * 8;
      *(short8*)&Bh[n*72 + k8] =
          *(const short8*)(jb.Wth + (size_t)(n0 + n)*KK + kt + k8);
      *(short8*)&Bl[n*72 + k8] =
          *(const short8*)(jb.Wtl + (size_t)(n0 + n)*KK + kt + k8);
    }
    __syncthreads();
    #pragma unroll
    for (int ks=0; ks<2; ks++){
      const int koff = ks*32 + lq*8;
      short8 a_h = *(const short8*)&Ah[(wv*16+lr)*72 + koff];
      short8 a_l;
      if constexpr (!BF16A) a_l = *(const short8*)&Al[(wv*16+lr)*72 + koff];
      #pragma unroll
      for (int nt=0; nt<NT; nt++){
        short8 b_h = *(const short8*)&Bh[(nt*16+lr)*72 + koff];
        short8 b_l = *(const short8*)&Bl[(nt*16+lr)*72 + koff];
        acc[nt] = __builtin_amdgcn_mfma_f32_16x16x32_bf16(a_h, b_h, acc[nt], 0,0,0);
        acc[nt] = __builtin_amdgcn_mfma_f32_16x16x32_bf16(a_h, b_l, acc[nt], 0,0,0);
        if constexpr (!BF16A)
          acc[nt] = __builtin_amdgcn_mfma_f32_16x16x32_bf16(a_l, b_h, acc[nt], 0,0,0);
      }
    }
    __syncthreads();
  }
  float ls[LOGIT ? 4 : 1][LOGIT ? 4 : 1];   // [r][h]
  float ld_[LOGIT ? 4 : 1][LOGIT ? 4 : 1];
  if constexpr (LOGIT){
    #pragma unroll
    for (int r=0;r<4;r++)
      #pragma unroll
      for (int h=0;h<4;h++){ ls[r][h]=0.f; ld_[r][h]=0.f; }
  }
  #pragma unroll
  for (int nt=0; nt<NT; nt++){
    int n = n0 + nt*16 + lr;
    float bv = jb.bias ? jb.bias[n] : 0.f;
    #pragma unroll
    for (int r=0;r<4;r++){
      int m = m0 + wv*16 + lq*4 + r;
      if (m < M){
        float o = acc[nt][r] + bv;
        if (ELU) o = elu_f(o);
        if constexpr (LG){
          if (n < 32)       ((unsigned short*)jb.C)[(size_t)m*32 + n] = f2bf(o);
          else if (n == 32) jb.outA[m] = o;
          else if (n == 33) jb.outB[m] = o;
        } else {
          if (BF16OUT) ((unsigned short*)jb.C)[(size_t)m*N + n] = f2bf(o);
          else         ((float*)jb.C)[(size_t)m*N + n] = o;
        }
        if constexpr (LOGIT){
          #pragma unroll
          for (int h=0;h<4;h++){
            ls[r][h]  = fmaf(o, CwS[h*64 + n], ls[r][h]);
            ld_[r][h] = fmaf(o, CwD[h*64 + n], ld_[r][h]);
          }
        }
      }
    }
  }
  if constexpr (LOGIT){
    // reduce over the 16 lr-lanes (channels), then lane lr==0 writes 4 rows x 4 heads
    #pragma unroll
    for (int r=0;r<4;r++)
      #pragma unroll
      for (int h=0;h<4;h++){
        float a = ls[r][h], d = ld_[r][h];
        #pragma unroll
        for (int off=1; off<16; off<<=1){
          a += __shfl_xor(a, off, 64);
          d += __shfl_xor(d, off, 64);
        }
        ls[r][h]=a; ld_[r][h]=d;
      }
    if (lr == 0){
      #pragma unroll
      for (int r=0;r<4;r++){
        int m = m0 + wv*16 + lq*4 + r;
        if (m < M){
          #pragma unroll
          for (int h=0;h<4;h++){
            jb.outA[(size_t)m*4 + h] = ls[r][h];
            jb.outB[(size_t)m*4 + h] = ld_[r][h];
          }
        }
      }
    }
  }
}

// ---------------- fused layer-0 head GEMMs + layer-1 feature GEMM ----------------
// Per 64-row block: 4 head phases compute hi1 rows = elu((agg_h @ W0_h)/den + b0)
// into an LDS buffer H1 [64][264] (bf16, never materialized to global), then a
// 4-phase K=256 GEMM vs Wc produces hs1 (cols 0..31) + logit cols 32/33.
// Numerics identical to the former hgemm -> global -> LG-mgemm path (same bf16
// intermediate, same MFMA order).
struct FsJob {
  const unsigned short* A;            // agg bf16 [M,256]
  const unsigned short* W0h;          // [256][64] l0 Ws transposed hi
  const unsigned short* W0l;          //             lo
  const float* den;                   // [M,4]
  const float* b0;                    // [256] l0 bias
  const unsigned short* Wch;          // [48][256] Wc transposed hi
  const unsigned short* Wcl;          //             lo
  unsigned short* hs1;                // bf16 [M,32]
  float* outA; float* outB;           // layer-1 logits [M]
};
__global__ __launch_bounds__(256) void l0l1_kernel(FsJob j0, FsJob j1, int M){
  const FsJob jb = blockIdx.z ? j1 : j0;
  __shared__ __align__(16) unsigned short H1[64*264];   // hi1 rows (pad 8)
  __shared__ __align__(16) unsigned short Sa[64*72];
  __shared__ __align__(16) unsigned short Sbh[64*72];
  __shared__ __align__(16) unsigned short Sbl[64*72];
  const int t = threadIdx.x;
  const int m0 = blockIdx.x*64;
  const int wv = t>>6, l = t&63;
  const int lr = l&15, lq = l>>4;

  // ---- phase 1: 4 head GEMMs -> H1 ----
  for (int h=0; h<4; ++h){
    #pragma unroll
    for (int i=0;i<2;i++){
      int li = t + i*256;
      int r = li >> 3, c8 = (li & 7)*8;
      short8 v = {0,0,0,0,0,0,0,0};
      if (m0 + r < M) v = *(const short8*)(jb.A + (size_t)(m0+r)*256 + h*64 + c8);
      *(short8*)&Sa[r*72 + c8] = v;
    }
    #pragma unroll
    for (int i=0;i<2;i++){
      int c  = t + i*256;
      int n  = c >> 3;
      int k8 = (c & 7) * 8;
      *(short8*)&Sbh[n*72 + k8] =
          *(const short8*)(jb.W0h + (size_t)(h*64 + n)*64 + k8);
      *(short8*)&Sbl[n*72 + k8] =
          *(const short8*)(jb.W0l + (size_t)(h*64 + n)*64 + k8);
    }
    __syncthreads();
    floatx4 acc[4];
    #pragma unroll
    for (int i=0;i<4;i++) acc[i] = (floatx4){0.f,0.f,0.f,0.f};
    #pragma unroll
    for (int ks=0; ks<2; ks++){
      const int koff = ks*32 + lq*8;
      short8 a_h = *(const short8*)&Sa[(wv*16+lr)*72 + koff];
      #pragma unroll
      for (int nt=0; nt<4; nt++){
        short8 b_h = *(const short8*)&Sbh[(nt*16+lr)*72 + koff];
        short8 b_l = *(const short8*)&Sbl[(nt*16+lr)*72 + koff];
        acc[nt] = __builtin_amdgcn_mfma_f32_16x16x32_bf16(a_h, b_h, acc[nt], 0,0,0);
        acc[nt] = __builtin_amdgcn_mfma_f32_16x16x32_bf16(a_h, b_l, acc[nt], 0,0,0);
      }
    }
    float inv[4];
    #pragma unroll
    for (int r=0;r<4;r++){
      int m = m0 + wv*16 + lq*4 + r;
      inv[r] = (m < M) ? 1.f/(jb.den[(size_t)m*4 + h] + 1e-16f) : 0.f;
    }
    #pragma unroll
    for (int nt=0; nt<4; nt++){
      int col = h*64 + nt*16 + lr;
      float bv = jb.b0[col];
      #pragma unroll
      for (int r=0;r<4;r++){
        int mrow = wv*16 + lq*4 + r;
        H1[mrow*264 + col] = f2bf(elu_f(acc[nt][r]*inv[r] + bv));
      }
    }
    __syncthreads();   // H1 head-slice written; Sa/Sb free for next head
  }

  // ---- phase 2: K=256 GEMM (A from H1) -> hs1 + logits ----
  floatx4 acc2[3];
  #pragma unroll
  for (int i=0;i<3;i++) acc2[i] = (floatx4){0.f,0.f,0.f,0.f};
  for (int kt=0; kt<4; ++kt){
    for (int c = t; c < 48*8; c += 256){
      int n  = c >> 3;
      int k8 = (c & 7) * 8;
      *(short8*)&Sbh[n*72 + k8] =
          *(const short8*)(jb.Wch + (size_t)n*256 + kt*64 + k8);
      *(short8*)&Sbl[n*72 + k8] =
          *(const short8*)(jb.Wcl + (size_t)n*256 + kt*64 + k8);
    }
    __syncthreads();
    #pragma unroll
    for (int ks=0; ks<2; ks++){
      const int koff = ks*32 + lq*8;
      short8 a_h = *(const short8*)&H1[(wv*16+lr)*264 + kt*64 + koff];
      #pragma unroll
      for (int nt=0; nt<3; nt++){
        short8 b_h = *(const short8*)&Sbh[(nt*16+lr)*72 + koff];
        short8 b_l = *(const short8*)&Sbl[(nt*16+lr)*72 + koff];
        acc2[nt] = __builtin_amdgcn_mfma_f32_16x16x32_bf16(a_h, b_h, acc2[nt], 0,0,0);
        acc2[nt] = __builtin_amdgcn_mfma_f32_16x16x32_bf16(a_h, b_l, acc2[nt], 0,0,0);
      }
    }
    __syncthreads();
  }
  // epilogue: cols 0..31 -> hs1 bf16, col 32 -> outA, col 33 -> outB
  #pragma unroll
  for (int nt=0; nt<3; nt++){
    int n = nt*16 + lr;
    #pragma unroll
    for (int r=0;r<4;r++){
      int m = m0 + wv*16 + lq*4 + r;
      if (m < M){
        float o = acc2[nt][r];
        if (n < 32)       jb.hs1[(size_t)m*32 + n] = f2bf(o);
        else if (n == 32) jb.outA[m] = o;
        else if (n == 33) jb.outB[m] = o;
      }
    }
  }
}

// ---------------- collapse attention vectors ----------------
struct CollapseJob { const float* W; const float* a; float* out; int K,H,C; };
struct CollapseArgs { CollapseJob j[8]; };
__global__ void collapse_kernel(CollapseArgs args){
  CollapseJob jb = args.j[blockIdx.x];
  int t = threadIdx.x;
  if (t < jb.K * jb.H){
    int k = t / jb.H, h = t % jb.H;
    const float* wr = jb.W + (size_t)k * (jb.H*jb.C) + h*jb.C;
    const float* ar = jb.a + h*jb.C;
    float s = 0.f;
    for (int c=0;c<jb.C;c++) s += wr[c]*ar[c];
    jb.out[h*jb.K + k] = s;   // layout [H,K]
  }
}

// ---------------- layer-0 pre-aggregation over hu/hi rows ----------------
// 8 dsts per wave, 8 lanes per dst, 8 channels per lane: edge-sum is fully
// within-lane => no cross-lane reduction epilogue. Unroll-4 edge loop: 4
// x-row gathers in flight per iteration (gather-latency hiding).
struct AggPJob {
  const int* offs; const int* ssrc;
  const unsigned short* x;     // bf16 [NN,64]
  const unsigned short* coef;  // bf16 [E,4]
  unsigned short* agg;         // bf16 [NN,256]
  float* den;                  // fp32 [NN,4]
};
__global__ __launch_bounds__(256) void aggpre_kernel(AggPJob ja, AggPJob jbb){
  const AggPJob jb = blockIdx.y ? jbb : ja;
  const int tid = threadIdx.x;
  const int lane = tid & 63, wid = tid >> 6;
  const int grp = lane >> 3;       // dst group within wave (0..7)
  const int cl  = lane & 7;        // channel lane within group
  const int c8  = cl * 8;          // channel base (8 bf16 = 16B per lane)
  const int dst = blockIdx.x*32 + wid*8 + grp;
  if (dst >= NN) return;
  const int b0 = jb.offs[dst], b1 = jb.offs[dst+1];
  float acc[4][8];
  float den[4] = {0.f,0.f,0.f,0.f};
  #pragma unroll
  for (int h=0;h<4;h++)
    #pragma unroll
    for (int c=0;c<8;c++) acc[h][c]=0.f;
  int e = b0;
  // unroll-4: batch 4 independent x gathers + coef loads per iteration
  for (; e+3 < b1; e += 4){
    int s0 = jb.ssrc[e];
    int s1 = jb.ssrc[e+1];
    int s2 = jb.ssrc[e+2];
    int s3 = jb.ssrc[e+3];
    uint4 q0 = *(const uint4*)(jb.x + ((size_t)s0<<6) + c8);
    uint4 q1 = *(const uint4*)(jb.x + ((size_t)s1<<6) + c8);
    uint4 q2 = *(const uint4*)(jb.x + ((size_t)s2<<6) + c8);
    uint4 q3 = *(const uint4*)(jb.x + ((size_t)s3<<6) + c8);
    uint2 w0 = *(const uint2*)(jb.coef + (size_t)e*4);
    uint2 w1 = *(const uint2*)(jb.coef + (size_t)(e+1)*4);
    uint2 w2 = *(const uint2*)(jb.coef + (size_t)(e+2)*4);
    uint2 w3 = *(const uint2*)(jb.coef + (size_t)(e+3)*4);
    agg_pair(acc, den, q0, q1, w0, w1);
    agg_pair(acc, den, q2, q3, w2, w3);
  }
  if (e+1 < b1){
    int s0 = jb.ssrc[e];
    int s1 = jb.ssrc[e+1];
    uint4 q0 = *(const uint4*)(jb.x + ((size_t)s0<<6) + c8);
    uint4 q1 = *(const uint4*)(jb.x + ((size_t)s1<<6) + c8);
    uint2 w0 = *(const uint2*)(jb.coef + (size_t)e*4);
    uint2 w1 = *(const uint2*)(jb.coef + (size_t)(e+1)*4);
    agg_pair(acc, den, q0, q1, w0, w1);
    e += 2;
  }
  if (e < b1){  // odd-degree tail: single edge, scalar path
    int s = jb.ssrc[e];
    uint4 q = *(const uint4*)(jb.x + ((size_t)s<<6) + c8);
    uint2 w = *(const uint2*)(jb.coef + (size_t)e*4);
    float wf[4] = { bf2f(w.x & 0xffffu), bf2f(w.x >> 16),
                    bf2f(w.y & 0xffffu), bf2f(w.y >> 16) };
    float xf[8] = { bf2f(q.x & 0xffffu), bf2f(q.x >> 16),
                    bf2f(q.y & 0xffffu), bf2f(q.y >> 16),
                    bf2f(q.z & 0xffffu), bf2f(q.z >> 16),
                    bf2f(q.w & 0xffffu), bf2f(q.w >> 16) };
    #pragma unroll
    for (int h=0;h<4;h++){
      den[h] += wf[h];
      #pragma unroll
      for (int c=0;c<8;c++) acc[h][c] += wf[h]*xf[c];
    }
  }
  // epilogue: pack + store only (no shuffles)
  #pragma unroll
  for (int h=0;h<4;h++){
    uint2 plo = bf4_pack(make_float4(acc[h][0],acc[h][1],acc[h][2],acc[h][3]));
    uint2 phi = bf4_pack(make_float4(acc[h][4],acc[h][5],acc[h][6],acc[h][7]));
    uint4 pk = { plo.x, plo.y, phi.x, phi.y };
    *(uint4*)(jb.agg + (size_t)dst*256 + h*64 + c8) = pk;
  }
  if (cl == 0)
    *(float4*)(jb.den + (size_t)dst*4) = make_float4(den[0],den[1],den[2],den[3]);
}

// ---------------- layer-1 aggregation (aggpre-style: 8 dst/wave, shuffle-free) ----
struct Agg1Job {
  const int* offs; const int* ssrc;
  const unsigned short* hs;   // bf16 [NN,32]
  const float* als; const float* ald;  // layer-1 logits
  const float* bias; float* out;
};
__global__ __launch_bounds__(256) void agg1_kernel(Agg1Job ja, Agg1Job jbb){
  const Agg1Job jb = blockIdx.y ? jbb : ja;
  const int tid = threadIdx.x;
  const int lane = tid & 63, wid = tid >> 6;
  const int grp = lane >> 3;       // dst group within wave (0..7)
  const int cl  = lane & 7;        // col lane within group
  const int c4  = cl * 4;          // col base (4 f32 outputs per lane)
  const int dst = blockIdx.x*32 + wid*8 + grp;
  if (dst >= NN) return;
  const int b0 = jb.offs[dst], b1 = jb.offs[dst+1];
  const float ad = jb.ald[dst];
  float acc[4] = {0.f,0.f,0.f,0.f};
  float den = 0.f;
  int e = b0;
  for (; e+3 < b1; e += 4){
    int s0 = jb.ssrc[e];
    int s1 = jb.ssrc[e+1];
    int s2 = jb.ssrc[e+2];
    int s3 = jb.ssrc[e+3];
    float a0 = jb.als[s0];
    float a1 = jb.als[s1];
    float a2 = jb.als[s2];
    float a3 = jb.als[s3];
    float4 v0 = bf4_load(jb.hs + ((size_t)s0<<5) + c4);
    float4 v1 = bf4_load(jb.hs + ((size_t)s1<<5) + c4);
    float4 v2 = bf4_load(jb.hs + ((size_t)s2<<5) + c4);
    float4 v3 = bf4_load(jb.hs + ((size_t)s3<<5) + c4);
    float w0 = __expf(lrelu_f(a0 + ad));
    float w1 = __expf(lrelu_f(a1 + ad));
    float w2 = __expf(lrelu_f(a2 + ad));
    float w3 = __expf(lrelu_f(a3 + ad));
    acc[0] += w0*v0.x + w1*v1.x + w2*v2.x + w3*v3.x;
    acc[1] += w0*v0.y + w1*v1.y + w2*v2.y + w3*v3.y;
    acc[2] += w0*v0.z + w1*v1.z + w2*v2.z + w3*v3.z;
    acc[3] += w0*v0.w + w1*v1.w + w2*v2.w + w3*v3.w;
    den += (w0 + w1) + (w2 + w3);
  }
  for (; e < b1; ++e){
    int s = jb.ssrc[e];
    float w = __expf(lrelu_f(jb.als[s] + ad));
    float4 v = bf4_load(jb.hs + ((size_t)s<<5) + c4);
    acc[0] += w*v.x; acc[1] += w*v.y; acc[2] += w*v.z; acc[3] += w*v.w;
    den += w;
  }
  const float inv = 1.f/(den + 1e-16f);
  float4 b = *(const float4*)(jb.bias + c4);
  float4 o = make_float4(acc[0]*inv+b.x, acc[1]*inv+b.y,
                         acc[2]*inv+b.z, acc[3]*inv+b.w);
  *(float4*)(jb.out + (size_t)dst*32 + c4) = o;
}

// ---------------- host glue ----------------
extern "C" void kernel_launch(void* const* d_in, const int* in_sizes, int n_in,
                              void* d_out, int out_size, void* d_ws, size_t ws_size,
                              hipStream_t stream)
{
  (void)in_sizes; (void)n_in; (void)out_size; (void)ws_size;
  const float* x_user   = (const float*)d_in[0];
  const float* x_item   = (const float*)d_in[1];
  const int*   e_u2i    = (const int*)  d_in[2];
  const int*   e_i2u    = (const int*)  d_in[3];
  const float* p_user_w = (const float*)d_in[4];
  const float* p_user_b = (const float*)d_in[5];
  const float* p_item_w = (const float*)d_in[6];
  const float* p_item_b = (const float*)d_in[7];
  const float* l0_u2i_ws=(const float*)d_in[8];
  const float* l0_u2i_wd=(const float*)d_in[9];
  const float* l0_u2i_as=(const float*)d_in[10];
  const float* l0_u2i_ad=(const float*)d_in[11];
  const float* l0_u2i_b =(const float*)d_in[12];
  const float* l0_i2u_ws=(const float*)d_in[13];
  const float* l0_i2u_wd=(const float*)d_in[14];
  const float* l0_i2u_as=(const float*)d_in[15];
  const float* l0_i2u_ad=(const float*)d_in[16];
  const float* l0_i2u_b =(const float*)d_in[17];
  const float* l1_u2i_ws=(const float*)d_in[18];
  const float* l1_u2i_wd=(const float*)d_in[19];
  const float* l1_u2i_as=(const float*)d_in[20];
  const float* l1_u2i_ad=(const float*)d_in[21];
  const float* l1_u2i_b =(const float*)d_in[22];
  const float* l1_i2u_ws=(const float*)d_in[23];
  const float* l1_i2u_wd=(const float*)d_in[24];
  const float* l1_i2u_as=(const float*)d_in[25];
  const float* l1_i2u_ad=(const float*)d_in[26];
  const float* l1_i2u_b =(const float*)d_in[27];

  char* base = (char*)d_ws;
  size_t off = 0;
  auto alloc = [&](size_t bytes)->void*{
    void* p = base + off;
    off += (bytes + 255) & ~(size_t)255;
    return p;
  };
  int* offs_u2i = (int*)alloc((size_t)(NN+1)*sizeof(int));
  int* offs_i2u = (int*)alloc((size_t)(NN+1)*sizeof(int));
  int* ssrc_u2i = (int*)alloc((size_t)NE*sizeof(int));
  int* ssrc_i2u = (int*)alloc((size_t)NE*sizeof(int));
  int* ghist    = (int*)alloc((size_t)2*200*sizeof(int));
  int* gbase    = (int*)alloc((size_t)2*200*sizeof(int));
  int* gcur     = (int*)alloc((size_t)2*200*sizeof(int));
  unsigned short* coef0_u2i = (unsigned short*)alloc((size_t)NE*4*sizeof(unsigned short));
  unsigned short* coef0_i2u = (unsigned short*)alloc((size_t)NE*4*sizeof(unsigned short));
  unsigned short* hu = (unsigned short*)alloc((size_t)NN*64*sizeof(unsigned short));
  unsigned short* hi = (unsigned short*)alloc((size_t)NN*64*sizeof(unsigned short));
  unsigned short* agg_u2i = (unsigned short*)alloc((size_t)NN*256*sizeof(unsigned short));
  unsigned short* agg_i2u = (unsigned short*)alloc((size_t)NN*256*sizeof(unsigned short));
  float* den_u2i = (float*)alloc((size_t)NN*4*sizeof(float));
  float* den_i2u = (float*)alloc((size_t)NN*4*sizeof(float));
  unsigned short* hu1 = (unsigned short*)alloc((size_t)NN*256*sizeof(unsigned short));
  unsigned short* hi1 = (unsigned short*)alloc((size_t)NN*256*sizeof(unsigned short));
  unsigned short* hs1_u2i = (unsigned short*)alloc((size_t)NN*32*sizeof(unsigned short));
  unsigned short* hs1_i2u = (unsigned short*)alloc((size_t)NN*32*sizeof(unsigned short));
  float* als0_u2i = (float*)alloc((size_t)NN*4*sizeof(float));
  float* ald0_u2i = (float*)alloc((size_t)NN*4*sizeof(float));
  float* als0_i2u = (float*)alloc((size_t)NN*4*sizeof(float));
  float* ald0_i2u = (float*)alloc((size_t)NN*4*sizeof(float));
  float* als1_u2i = (float*)alloc((size_t)NN*sizeof(float));
  float* ald1_u2i = (float*)alloc((size_t)NN*sizeof(float));
  float* als1_i2u = (float*)alloc((size_t)NN*sizeof(float));
  float* ald1_i2u = (float*)alloc((size_t)NN*sizeof(float));
  float* cw0s_u2i = (float*)alloc(256*sizeof(float));
  float* cw0d_u2i = (float*)alloc(256*sizeof(float));
  float* cw0s_i2u = (float*)alloc(256*sizeof(float));
  float* cw0d_i2u = (float*)alloc(256*sizeof(float));
  float* cw1s_u2i = (float*)alloc(256*sizeof(float));
  float* cw1d_u2i = (float*)alloc(256*sizeof(float));
  float* cw1s_i2u = (float*)alloc(256*sizeof(float));
  float* cw1d_i2u = (float*)alloc(256*sizeof(float));
  // transposed bf16 hi/lo weight images
  unsigned short* wt_pu_h  = (unsigned short*)alloc((size_t)64*128*sizeof(unsigned short));
  unsigned short* wt_pu_l  = (unsigned short*)alloc((size_t)64*128*sizeof(unsigned short));
  unsigned short* wt_pi_h  = (unsigned short*)alloc((size_t)64*128*sizeof(unsigned short));
  unsigned short* wt_pi_l  = (unsigned short*)alloc((size_t)64*128*sizeof(unsigned short));
  unsigned short* wt_l0u_h = (unsigned short*)alloc((size_t)256*64*sizeof(unsigned short));
  unsigned short* wt_l0u_l = (unsigned short*)alloc((size_t)256*64*sizeof(unsigned short));
  unsigned short* wt_l0i_h = (unsigned short*)alloc((size_t)256*64*sizeof(unsigned short));
  unsigned short* wt_l0i_l = (unsigned short*)alloc((size_t)256*64*sizeof(unsigned short));
  unsigned short* wt_wcu_h = (unsigned short*)alloc((size_t)48*256*sizeof(unsigned short));
  unsigned short* wt_wcu_l = (unsigned short*)alloc((size_t)48*256*sizeof(unsigned short));
  unsigned short* wt_wci_h = (unsigned short*)alloc((size_t)48*256*sizeof(unsigned short));
  unsigned short* wt_wci_l = (unsigned short*)alloc((size_t)48*256*sizeof(unsigned short));
  // pairs scratch aliases hu1/hi1: consumed by part2 (hu1/hi1 now LDS-only)
  int2* pairs_u2i = (int2*)hu1;
  int2* pairs_i2u = pairs_u2i + NE;

  const int GM = (NN + 63)/64;

  // ---- bucket sort stage A ----
  hipMemsetAsync(ghist, 0, (size_t)2*200*sizeof(int), stream);
  ghist_kernel<<<dim3(256,2), 256, 0, stream>>>(e_u2i, e_i2u, ghist);
  gscan_kernel<<<1, 256, 0, stream>>>(ghist, gbase, gcur);
  part1_kernel<<<dim3((NE+TILE1-1)/TILE1,2), 256, 0, stream>>>(
      e_u2i, e_i2u, gcur, pairs_u2i, pairs_i2u);

  // ---- collapse attention vectors ----
  CollapseArgs ca;
  ca.j[0] = {l0_u2i_ws, l0_u2i_as, cw0s_u2i, 64, 4, 64};
  ca.j[1] = {l0_u2i_wd, l0_u2i_ad, cw0d_u2i, 64, 4, 64};
  ca.j[2] = {l0_i2u_ws, l0_i2u_as, cw0s_i2u, 64, 4, 64};
  ca.j[3] = {l0_i2u_wd, l0_i2u_ad, cw0d_i2u, 64, 4, 64};
  ca.j[4] = {l1_u2i_ws, l1_u2i_as, cw1s_u2i, 256, 1, 32};
  ca.j[5] = {l1_u2i_wd, l1_u2i_ad, cw1d_u2i, 256, 1, 32};
  ca.j[6] = {l1_i2u_ws, l1_i2u_as, cw1s_i2u, 256, 1, 32};
  ca.j[7] = {l1_i2u_wd, l1_i2u_ad, cw1d_i2u, 256, 1, 32};
  collapse_kernel<<<8, 256, 0, stream>>>(ca);

  // ---- weight pre-conversion (transposed bf16 hi/lo; Wc built with cw cols) ----
  WcvArgs wa;
  wa.j[0] = {p_user_w,  nullptr,   nullptr,   wt_pu_h,  wt_pu_l,  128, 64, 0};
  wa.j[1] = {p_item_w,  nullptr,   nullptr,   wt_pi_h,  wt_pi_l,  128, 64, 0};
  wa.j[2] = {l0_u2i_ws, nullptr,   nullptr,   wt_l0u_h, wt_l0u_l, 64, 256, 0};
  wa.j[3] = {l0_i2u_ws, nullptr,   nullptr,   wt_l0i_h, wt_l0i_l, 64, 256, 0};
  wa.j[4] = {l1_u2i_ws, cw1s_u2i,  cw1d_i2u,  wt_wcu_h, wt_wcu_l, 256, 48, 1};
  wa.j[5] = {l1_i2u_ws, cw1s_i2u,  cw1d_u2i,  wt_wci_h, wt_wci_l, 256, 48, 1};
  wconv_kernel<<<dim3(64,6), 256, 0, stream>>>(wa);

  // ---- input projections (+bias +ELU) -> bf16, with fused layer-0 logits ----
  mgemm_kernel<4,128,true,true,false,false,true><<<dim3(GM,1,2), 256, 0, stream>>>(
      MgJob{x_user, wt_pu_h, wt_pu_l, p_user_b, hu, als0_u2i, ald0_i2u, cw0s_u2i, cw0d_i2u},
      MgJob{x_item, wt_pi_h, wt_pi_l, p_item_b, hi, als0_i2u, ald0_u2i, cw0s_i2u, cw0d_u2i},
      NN, 64);

  // ---- bucket sort stage B ----
  part2_kernel<<<dim3(GB,2), 256, 0, stream>>>(
      Part2Job{pairs_u2i, gbase,       als0_u2i, ald0_u2i, ssrc_u2i, offs_u2i, coef0_u2i},
      Part2Job{pairs_i2u, gbase + 200, als0_i2u, ald0_i2u, ssrc_i2u, offs_i2u, coef0_i2u});

  // ---- layer 0: pre-aggregate hu/hi rows (8 dst/wave, unroll-4 gathers) ----
  aggpre_kernel<<<dim3((NN+31)/32,2), 256, 0, stream>>>(
      AggPJob{offs_u2i, ssrc_u2i, hu, coef0_u2i, agg_u2i, den_u2i},
      AggPJob{offs_i2u, ssrc_i2u, hi, coef0_i2u, agg_i2u, den_i2u});

  // ---- fused layer-0 head GEMMs + layer-1 feature GEMM (hi1/hu1 stay in LDS) ----
  // chain A: agg_i2u -> hu1(LDS) -> hs1_u2i + als1_u2i + ald1_i2u
  // chain B: agg_u2i -> hi1(LDS) -> hs1_i2u + als1_i2u + ald1_u2i
  l0l1_kernel<<<dim3(GM,1,2), 256, 0, stream>>>(
      FsJob{agg_i2u, wt_l0i_h, wt_l0i_l, den_i2u, l0_i2u_b,
            wt_wcu_h, wt_wcu_l, hs1_u2i, als1_u2i, ald1_i2u},
      FsJob{agg_u2i, wt_l0u_h, wt_l0u_l, den_u2i, l0_u2i_b,
            wt_wci_h, wt_wci_l, hs1_i2u, als1_i2u, ald1_u2i},
      NN);

  // ---- layer 1: aggregate (+bias), shuffle-free 8 dst/wave ----
  float* hu2 = (float*)d_out;                  // first tuple element (users, i2u dst)
  float* hi2 = (float*)d_out + (size_t)NN*32;  // second tuple element (items, u2i dst)
  agg1_kernel<<<dim3((NN+31)/32,2), 256, 0, stream>>>(
      Agg1Job{offs_u2i, ssrc_u2i, hs1_u2i, als1_u2i, ald1_u2i, l1_u2i_b, hi2},
      Agg1Job{offs_i2u, ssrc_i2u, hs1_i2u, als1_i2u, ald1_i2u, l1_i2u_b, hu2});
}

// Round 13
// 338.417 us; speedup vs baseline: 1.1062x; 1.0307x over previous
//
#include <hip/hip_runtime.h>
#include <cstdint>
#include <cstddef>

#define NN 50000
#define NE 800000
#define GB 196        // coarse buckets = ceil(NN/256)
#define TILE1 4096    // edges per part1 block
#define CAP 8192      // max edges per bucket in part2 LDS (mean 4082)

typedef __attribute__((ext_vector_type(8))) short short8;
typedef __attribute__((ext_vector_type(4))) float floatx4;

__device__ __forceinline__ float lrelu_f(float x){ return x >= 0.f ? x : 0.2f*x; }
__device__ __forceinline__ float elu_f(float x){ return x > 0.f ? x : __expf(x) - 1.f; }

__device__ __forceinline__ unsigned short f2bf(float f){
  unsigned int u = __float_as_uint(f);
  u += 0x7FFFu + ((u >> 16) & 1u);
  return (unsigned short)(u >> 16);
}
__device__ __forceinline__ float bf2f(unsigned int us){
  return __uint_as_float(us << 16);
}
__device__ __forceinline__ float4 bf4_load(const unsigned short* p){
  uint2 q = *(const uint2*)p;
  return make_float4(bf2f(q.x & 0xffffu), bf2f(q.x >> 16),
                     bf2f(q.y & 0xffffu), bf2f(q.y >> 16));
}
__device__ __forceinline__ uint2 bf4_pack(float4 o){
  uint2 p;
  p.x = (unsigned)f2bf(o.x) | ((unsigned)f2bf(o.y) << 16);
  p.y = (unsigned)f2bf(o.z) | ((unsigned)f2bf(o.w) << 16);
  return p;
}
__device__ __forceinline__ void split_bf(float a, unsigned short& h, unsigned short& l){
  h = f2bf(a);
  l = f2bf(a - bf2f(h));
}

// v_dot2_f32_bf16: acc += a.bf16[0]*b.bf16[0] + a.bf16[1]*b.bf16[1]
__device__ __forceinline__ float dot2bf(float acc, unsigned a, unsigned b){
  asm("v_dot2_f32_bf16 %0, %1, %2, %0" : "+v"(acc) : "v"(a), "v"(b));
  return acc;
}

// process one edge PAIR (bf16 operands stay packed; sums stay within-lane)
__device__ __forceinline__ void agg_pair(float (&acc)[4][8], float (&den)[4],
                                         uint4 q0, uint4 q1, uint2 w0, uint2 w1){
  const unsigned ONE2 = 0x3F803F80u;  // packed bf16 (1.0, 1.0)
  unsigned wp[4];
  wp[0] = __builtin_amdgcn_perm(w1.x, w0.x, 0x05040100u);
  wp[1] = __builtin_amdgcn_perm(w1.x, w0.x, 0x07060302u);
  wp[2] = __builtin_amdgcn_perm(w1.y, w0.y, 0x05040100u);
  wp[3] = __builtin_amdgcn_perm(w1.y, w0.y, 0x07060302u);
  unsigned xp[8];
  xp[0] = __builtin_amdgcn_perm(q1.x, q0.x, 0x05040100u);
  xp[1] = __builtin_amdgcn_perm(q1.x, q0.x, 0x07060302u);
  xp[2] = __builtin_amdgcn_perm(q1.y, q0.y, 0x05040100u);
  xp[3] = __builtin_amdgcn_perm(q1.y, q0.y, 0x07060302u);
  xp[4] = __builtin_amdgcn_perm(q1.z, q0.z, 0x05040100u);
  xp[5] = __builtin_amdgcn_perm(q1.z, q0.z, 0x07060302u);
  xp[6] = __builtin_amdgcn_perm(q1.w, q0.w, 0x05040100u);
  xp[7] = __builtin_amdgcn_perm(q1.w, q0.w, 0x07060302u);
  #pragma unroll
  for (int h=0;h<4;h++){
    den[h] = dot2bf(den[h], wp[h], ONE2);
    #pragma unroll
    for (int c=0;c<8;c++) acc[h][c] = dot2bf(acc[h][c], wp[h], xp[c]);
  }
}

// ---------------- two-level bucket sort of edges by dst ----------------
__global__ __launch_bounds__(256) void ghist_kernel(const int* __restrict__ e0,
                                                    const int* __restrict__ e1,
                                                    int* __restrict__ ghist){
  const int ty = blockIdx.y;
  const int* e = ty ? e1 : e0;
  __shared__ int h[GB];
  for (int j=threadIdx.x; j<GB; j+=256) h[j]=0;
  __syncthreads();
  for (int i = blockIdx.x*256 + threadIdx.x; i < NE; i += 256*256)
    atomicAdd(&h[e[NE+i]>>8], 1);
  __syncthreads();
  for (int j=threadIdx.x; j<GB; j+=256) if (h[j]) atomicAdd(&ghist[ty*200+j], h[j]);
}

__global__ __launch_bounds__(256) void gscan_kernel(const int* __restrict__ ghist,
                                                    int* __restrict__ gbase,
                                                    int* __restrict__ gcur){
  __shared__ int wb[4];
  const int t = threadIdx.x, wv = t>>6, l = t&63;
  for (int ty=0; ty<2; ++ty){
    int v = (t < GB) ? ghist[ty*200+t] : 0;
    int sum = v;
    #pragma unroll
    for (int off=1; off<64; off<<=1){
      int x = __shfl_up(sum, off, 64);
      if (l >= off) sum += x;
    }
    if (l == 63) wb[wv] = sum;
    __syncthreads();
    int wbase = 0;
    #pragma unroll
    for (int w=0; w<4; ++w) if (w < wv) wbase += wb[w];
    int excl = wbase + sum - v;
    if (t <= GB) gbase[ty*200+t] = excl;
    if (t <  GB) gcur [ty*200+t] = excl;
    __syncthreads();
  }
}

// partition with LDS staging: global writes are contiguous per-bucket runs
__global__ __launch_bounds__(256) void part1_kernel(const int* __restrict__ e0,
                                                    const int* __restrict__ e1,
                                                    int* __restrict__ gcur,
                                                    int2* __restrict__ p0,
                                                    int2* __restrict__ p1){
  const int ty = blockIdx.y;
  const int* e = ty ? e1 : e0;
  int2* pairs = ty ? p1 : p0;
  __shared__ int cnt[256];
  __shared__ int lstart[256];
  __shared__ int lcur[256];
  __shared__ int curg[GB];
  __shared__ int lsrc[TILE1];
  __shared__ int ldst[TILE1];
  __shared__ int wb[4];
  const int t = threadIdx.x;
  cnt[t] = 0;
  __syncthreads();
  int dreg[16], sreg[16];
  const int base = blockIdx.x*TILE1;
  const int ntile = min(TILE1, NE - base);
  #pragma unroll
  for (int it=0; it<16; ++it){
    int i = base + it*256 + t;
    int d = -1, s = 0;
    if (i < NE){ d = e[NE+i]; s = e[i]; atomicAdd(&cnt[d>>8], 1); }
    dreg[it] = d; sreg[it] = s;
  }
  __syncthreads();
  int c = cnt[t], sum = c;
  #pragma unroll
  for (int off=1; off<64; off<<=1){
    int x = __shfl_up(sum, off, 64);
    if ((t&63) >= off) sum += x;
  }
  if ((t&63) == 63) wb[t>>6] = sum;
  __syncthreads();
  int wbase = 0;
  #pragma unroll
  for (int w=0; w<4; ++w) if (w < (t>>6)) wbase += wb[w];
  int excl = wbase + sum - c;
  lstart[t] = excl;
  lcur[t] = excl;
  if (t < GB && c > 0) curg[t] = atomicAdd(&gcur[ty*200+t], c);
  __syncthreads();
  #pragma unroll
  for (int it=0; it<16; ++it){
    int d = dreg[it];
    if (d >= 0){
      int pos = atomicAdd(&lcur[d>>8], 1);
      lsrc[pos] = sreg[it];
      ldst[pos] = d;
    }
  }
  __syncthreads();
  for (int i=t; i<ntile; i+=256){
    int d = ldst[i];
    int j = d>>8;
    pairs[curg[j] + (i - lstart[j])] = make_int2(lsrc[i], d);
  }
}

// per-bucket LDS bin by dst + CSR offsets + fused layer-0 softmax weights (bf16).
struct Part2Job {
  const int2* pairs; const int* gbase;
  const float* als; const float* ald;   // [NN,4]
  int* ssrc; int* offs; unsigned short* coef;  // coef: [E,4] bf16
};
__global__ __launch_bounds__(256) void part2_kernel(Part2Job j0, Part2Job j1){
  const Part2Job jb = blockIdx.y ? j1 : j0;
  const int b = blockIdx.x;
  const int t = threadIdx.x;
  __shared__ int lcnt[256];
  __shared__ int lcur[256];
  __shared__ int wb[4];
  __shared__ int sorted_src[CAP];
  __shared__ unsigned char sorted_dl[CAP];
  const int gb0 = jb.gbase[b], gb1 = jb.gbase[b+1];
  const int n = gb1 - gb0;
  lcnt[t] = 0;
  __syncthreads();
  for (int i=t; i<n; i+=256)
    atomicAdd(&lcnt[jb.pairs[gb0+i].y - (b<<8)], 1);
  __syncthreads();
  int c = lcnt[t], sum = c;
  #pragma unroll
  for (int off=1; off<64; off<<=1){
    int x = __shfl_up(sum, off, 64);
    if ((t&63) >= off) sum += x;
  }
  if ((t&63) == 63) wb[t>>6] = sum;
  __syncthreads();
  int wbase = 0;
  #pragma unroll
  for (int w=0; w<4; ++w) if (w < (t>>6)) wbase += wb[w];
  int excl = wbase + sum - c;
  lcur[t] = excl;
  int g = (b<<8) + t;
  if (g <= NN) jb.offs[g] = gb0 + excl;
  __syncthreads();
  for (int i=t; i<n; i+=256){
    int2 pr = jb.pairs[gb0+i];
    int dl = pr.y - (b<<8);
    int pos = atomicAdd(&lcur[dl], 1);
    sorted_src[pos] = pr.x;
    sorted_dl[pos] = (unsigned char)dl;
  }
  __syncthreads();
  const float4* als4 = (const float4*)jb.als;
  const float4* ald4 = (const float4*)jb.ald;
  for (int i=t; i<n; i+=256){
    int s  = sorted_src[i];
    int dl = sorted_dl[i];
    float4 a  = als4[s];
    float4 ad = ald4[(b<<8)+dl];
    // no max-shift: |alpha| small at this model scale; softmax shift-invariant.
    float4 w;
    w.x = __expf(lrelu_f(a.x+ad.x));
    w.y = __expf(lrelu_f(a.y+ad.y));
    w.z = __expf(lrelu_f(a.z+ad.z));
    w.w = __expf(lrelu_f(a.w+ad.w));
    ((uint2*)jb.coef)[gb0+i] = bf4_pack(w);
    jb.ssrc[gb0+i] = s;
  }
}

// ---------------- weight pre-conversion: W[K][N] f32 -> transposed bf16 hi/lo ----
// mode 0: plain. mode 1: Wc build (n<32: Ws[k*32+n], n==32: cwS[k], n==33: cwD[k], else 0)
struct WcvJob {
  const float* W; const float* cwS; const float* cwD;
  unsigned short* Wth; unsigned short* Wtl;
  int K; int N; int mode;
};
struct WcvArgs { WcvJob j[6]; };
__global__ __launch_bounds__(256) void wconv_kernel(WcvArgs args){
  WcvJob jb = args.j[blockIdx.y];
  int idx = blockIdx.x*256 + threadIdx.x;
  if (idx >= jb.K * jb.N) return;
  int k = idx / jb.N, n = idx % jb.N;
  float val;
  if (jb.mode == 0) val = jb.W[(size_t)k*jb.N + n];
  else {
    if (n < 32)       val = jb.W[(size_t)k*32 + n];
    else if (n == 32) val = jb.cwS[k];
    else if (n == 33) val = jb.cwD[k];
    else              val = 0.f;
  }
  unsigned short h, g;
  split_bf(val, h, g);
  jb.Wth[(size_t)n*jb.K + k] = h;
  jb.Wtl[(size_t)n*jb.K + k] = g;
}

// ---------------- MFMA GEMM (proj): C = act(A[M,K] @ W[K,N] (+bias)) ----------------
// Two-phase LDS-staged structure (round-9 proven).
struct MgJob {
  const void* A;                     // f32 [M,KK] if !BF16A else bf16 [M,KK]
  const unsigned short* Wth;         // [N][KK] bf16 hi (transposed)
  const unsigned short* Wtl;         // [N][KK] bf16 lo
  const float* bias;
  void* C; float* outA; float* outB;
  const float* cwS; const float* cwD;
};
template<int NT, int KK, bool ELU, bool BF16OUT, bool BF16A, bool LG, bool LOGIT>
__global__ __launch_bounds__(256) void mgemm_kernel(MgJob j0, MgJob j1,
                                                    int M, int N)
{
  const MgJob jb = blockIdx.z ? j1 : j0;
  constexpr int TN = NT*16;
  __shared__ __align__(16) unsigned short Ah[64*72];
  __shared__ __align__(16) unsigned short Al[BF16A ? 8 : 64*72];
  __shared__ __align__(16) unsigned short Bh[TN*72];
  __shared__ __align__(16) unsigned short Bl[TN*72];
  __shared__ float CwS[LOGIT ? 256 : 1];
  __shared__ float CwD[LOGIT ? 256 : 1];
  const int t = threadIdx.x;
  const int m0 = blockIdx.x*64;
  const int n0 = blockIdx.y*TN;
  const int wv = t>>6, l = t&63;
  const int lr = l&15, lq = l>>4;
  if constexpr (LOGIT){ CwS[t] = jb.cwS[t]; CwD[t] = jb.cwD[t]; }
  floatx4 acc[NT];
  #pragma unroll
  for (int i=0;i<NT;i++) acc[i] = (floatx4){0.f,0.f,0.f,0.f};

  #pragma unroll
  for (int kt=0; kt<KK; kt+=64){
    if constexpr (BF16A){
      const unsigned short* A = (const unsigned short*)jb.A;
      #pragma unroll
      for (int i=0;i<2;i++){
        int li = t + i*256;
        int r = li >> 3, c8 = (li & 7)*8;
        short8 v = {0,0,0,0,0,0,0,0};
        if (m0 + r < M) v = *(const short8*)(A + (size_t)(m0+r)*KK + kt + c8);
        *(short8*)&Ah[r*72 + c8] = v;
      }
    } else {
      const float* A = (const float*)jb.A;
      #pragma unroll
      for (int i=0;i<4;i++){
        int li = t + i*256;
        int r = li >> 4, c4 = (li & 15)*4;
        float4 v = make_float4(0.f,0.f,0.f,0.f);
        if (m0 + r < M) v = *(const float4*)(A + (size_t)(m0+r)*KK + kt + c4);
        unsigned short h0,h1,h2,h3,g0,g1,g2,g3;
        split_bf(v.x,h0,g0); split_bf(v.y,h1,g1);
        split_bf(v.z,h2,g2); split_bf(v.w,h3,g3);
        uint2 ph = { (unsigned)h0 | ((unsigned)h1<<16), (unsigned)h2 | ((unsigned)h3<<16) };
        uint2 pl = { (unsigned)g0 | ((unsigned)g1<<16), (unsigned)g2 | ((unsigned)g3<<16) };
        *(uint2*)&Ah[r*72 + c4] = ph;
        *(uint2*)&Al[r*72 + c4] = pl;
      }
    }
    // B-stage: pure copy of preconverted bf16 hi/lo (16B chunks).
    for (int c = t; c < TN*8; c += 256){
      int n  = c >> 3;
      int k8 = (c & 7) * 8;
      *(short8*)&Bh[n*72 + k8] =
          *(const short8*)(jb.Wth + (size_t)(n0 + n)*KK + kt + k8);
      *(short8*)&Bl[n*72 + k8] =
          *(const short8*)(jb.Wtl + (size_t)(n0 + n)*KK + kt + k8);
    }
    __syncthreads();
    #pragma unroll
    for (int ks=0; ks<2; ks++){
      const int koff = ks*32 + lq*8;
      short8 a_h = *(const short8*)&Ah[(wv*16+lr)*72 + koff];
      short8 a_l;
      if constexpr (!BF16A) a_l = *(const short8*)&Al[(wv*16+lr)*72 + koff];
      #pragma unroll
      for (int nt=0; nt<NT; nt++){
        short8 b_h = *(const short8*)&Bh[(nt*16+lr)*72 + koff];
        short8 b_l = *(const short8*)&Bl[(nt*16+lr)*72 + koff];
        acc[nt] = __builtin_amdgcn_mfma_f32_16x16x32_bf16(a_h, b_h, acc[nt], 0,0,0);
        acc[nt] = __builtin_amdgcn_mfma_f32_16x16x32_bf16(a_h, b_l, acc[nt], 0,0,0);
        if constexpr (!BF16A)
          acc[nt] = __builtin_amdgcn_mfma_f32_16x16x32_bf16(a_l, b_h, acc[nt], 0,0,0);
      }
    }
    __syncthreads();
  }
  float ls[LOGIT ? 4 : 1][LOGIT ? 4 : 1];   // [r][h]
  float ld_[LOGIT ? 4 : 1][LOGIT ? 4 : 1];
  if constexpr (LOGIT){
    #pragma unroll
    for (int r=0;r<4;r++)
      #pragma unroll
      for (int h=0;h<4;h++){ ls[r][h]=0.f; ld_[r][h]=0.f; }
  }
  #pragma unroll
  for (int nt=0; nt<NT; nt++){
    int n = n0 + nt*16 + lr;
    float bv = jb.bias ? jb.bias[n] : 0.f;
    #pragma unroll
    for (int r=0;r<4;r++){
      int m = m0 + wv*16 + lq*4 + r;
      if (m < M){
        float o = acc[nt][r] + bv;
        if (ELU) o = elu_f(o);
        if constexpr (LG){
          if (n < 32)       ((unsigned short*)jb.C)[(size_t)m*32 + n] = f2bf(o);
          else if (n == 32) jb.outA[m] = o;
          else if (n == 33) jb.outB[m] = o;
        } else {
          if (BF16OUT) ((unsigned short*)jb.C)[(size_t)m*N + n] = f2bf(o);
          else         ((float*)jb.C)[(size_t)m*N + n] = o;
        }
        if constexpr (LOGIT){
          #pragma unroll
          for (int h=0;h<4;h++){
            ls[r][h]  = fmaf(o, CwS[h*64 + n], ls[r][h]);
            ld_[r][h] = fmaf(o, CwD[h*64 + n], ld_[r][h]);
          }
        }
      }
    }
  }
  if constexpr (LOGIT){
    // reduce over the 16 lr-lanes (channels), then lane lr==0 writes 4 rows x 4 heads
    #pragma unroll
    for (int r=0;r<4;r++)
      #pragma unroll
      for (int h=0;h<4;h++){
        float a = ls[r][h], d = ld_[r][h];
        #pragma unroll
        for (int off=1; off<16; off<<=1){
          a += __shfl_xor(a, off, 64);
          d += __shfl_xor(d, off, 64);
        }
        ls[r][h]=a; ld_[r][h]=d;
      }
    if (lr == 0){
      #pragma unroll
      for (int r=0;r<4;r++){
        int m = m0 + wv*16 + lq*4 + r;
        if (m < M){
          #pragma unroll
          for (int h=0;h<4;h++){
            jb.outA[(size_t)m*4 + h] = ls[r][h];
            jb.outB[(size_t)m*4 + h] = ld_[r][h];
          }
        }
      }
    }
  }
}

// ---------------- fused layer-0 head GEMMs + layer-1 feature GEMM ----------------
// Interleaved per-head schedule: head-h GEMM -> H1 slice [64][72] (8.6KB,
// reused) -> Wc K-slice kt=h accumulated into acc2. LDS 36.9KB -> 4 blocks/CU
// (vs 61.4KB/2 blocks for the phase-split version). Same accumulation order
// (kt ascending) => bit-identical to the former hgemm -> LG-mgemm path.
struct FsJob {
  const unsigned short* A;            // agg bf16 [M,256]
  const unsigned short* W0h;          // [256][64] l0 Ws transposed hi
  const unsigned short* W0l;          //             lo
  const float* den;                   // [M,4]
  const float* b0;                    // [256] l0 bias
  const unsigned short* Wch;          // [48][256] Wc transposed hi
  const unsigned short* Wcl;          //             lo
  unsigned short* hs1;                // bf16 [M,32]
  float* outA; float* outB;           // layer-1 logits [M]
};
__global__ __launch_bounds__(256) void l0l1_kernel(FsJob j0, FsJob j1, int M){
  const FsJob jb = blockIdx.z ? j1 : j0;
  __shared__ __align__(16) unsigned short H1[64*72];    // current head's hi1 slice
  __shared__ __align__(16) unsigned short Sa[64*72];
  __shared__ __align__(16) unsigned short Sbh[64*72];
  __shared__ __align__(16) unsigned short Sbl[64*72];
  const int t = threadIdx.x;
  const int m0 = blockIdx.x*64;
  const int wv = t>>6, l = t&63;
  const int lr = l&15, lq = l>>4;
  floatx4 acc2[3];
  #pragma unroll
  for (int i=0;i<3;i++) acc2[i] = (floatx4){0.f,0.f,0.f,0.f};

  for (int h=0; h<4; ++h){
    // stage A head slice + W0 head slice
    #pragma unroll
    for (int i=0;i<2;i++){
      int li = t + i*256;
      int r = li >> 3, c8 = (li & 7)*8;
      short8 v = {0,0,0,0,0,0,0,0};
      if (m0 + r < M) v = *(const short8*)(jb.A + (size_t)(m0+r)*256 + h*64 + c8);
      *(short8*)&Sa[r*72 + c8] = v;
    }
    #pragma unroll
    for (int i=0;i<2;i++){
      int c  = t + i*256;
      int n  = c >> 3;
      int k8 = (c & 7) * 8;
      *(short8*)&Sbh[n*72 + k8] =
          *(const short8*)(jb.W0h + (size_t)(h*64 + n)*64 + k8);
      *(short8*)&Sbl[n*72 + k8] =
          *(const short8*)(jb.W0l + (size_t)(h*64 + n)*64 + k8);
    }
    __syncthreads();
    // head GEMM
    floatx4 acc[4];
    #pragma unroll
    for (int i=0;i<4;i++) acc[i] = (floatx4){0.f,0.f,0.f,0.f};
    #pragma unroll
    for (int ks=0; ks<2; ks++){
      const int koff = ks*32 + lq*8;
      short8 a_h = *(const short8*)&Sa[(wv*16+lr)*72 + koff];
      #pragma unroll
      for (int nt=0; nt<4; nt++){
        short8 b_h = *(const short8*)&Sbh[(nt*16+lr)*72 + koff];
        short8 b_l = *(const short8*)&Sbl[(nt*16+lr)*72 + koff];
        acc[nt] = __builtin_amdgcn_mfma_f32_16x16x32_bf16(a_h, b_h, acc[nt], 0,0,0);
        acc[nt] = __builtin_amdgcn_mfma_f32_16x16x32_bf16(a_h, b_l, acc[nt], 0,0,0);
      }
    }
    float inv[4];
    #pragma unroll
    for (int r=0;r<4;r++){
      int m = m0 + wv*16 + lq*4 + r;
      inv[r] = (m < M) ? 1.f/(jb.den[(size_t)m*4 + h] + 1e-16f) : 0.f;
    }
    #pragma unroll
    for (int nt=0; nt<4; nt++){
      int col = nt*16 + lr;
      float bv = jb.b0[h*64 + col];
      #pragma unroll
      for (int r=0;r<4;r++){
        int mrow = wv*16 + lq*4 + r;
        H1[mrow*72 + col] = f2bf(elu_f(acc[nt][r]*inv[r] + bv));
      }
    }
    __syncthreads();   // H1 written; W0 reads complete -> Sb reusable
    // stage Wc K-slice kt=h
    for (int c = t; c < 48*8; c += 256){
      int n  = c >> 3;
      int k8 = (c & 7) * 8;
      *(short8*)&Sbh[n*72 + k8] =
          *(const short8*)(jb.Wch + (size_t)n*256 + h*64 + k8);
      *(short8*)&Sbl[n*72 + k8] =
          *(const short8*)(jb.Wcl + (size_t)n*256 + h*64 + k8);
    }
    __syncthreads();
    // accumulate layer-1 K-slice
    #pragma unroll
    for (int ks=0; ks<2; ks++){
      const int koff = ks*32 + lq*8;
      short8 a_h = *(const short8*)&H1[(wv*16+lr)*72 + koff];
      #pragma unroll
      for (int nt=0; nt<3; nt++){
        short8 b_h = *(const short8*)&Sbh[(nt*16+lr)*72 + koff];
        short8 b_l = *(const short8*)&Sbl[(nt*16+lr)*72 + koff];
        acc2[nt] = __builtin_amdgcn_mfma_f32_16x16x32_bf16(a_h, b_h, acc2[nt], 0,0,0);
        acc2[nt] = __builtin_amdgcn_mfma_f32_16x16x32_bf16(a_h, b_l, acc2[nt], 0,0,0);
      }
    }
    __syncthreads();   // H1/Sb reads complete -> reusable next head
  }
  // epilogue: cols 0..31 -> hs1 bf16, col 32 -> outA, col 33 -> outB
  #pragma unroll
  for (int nt=0; nt<3; nt++){
    int n = nt*16 + lr;
    #pragma unroll
    for (int r=0;r<4;r++){
      int m = m0 + wv*16 + lq*4 + r;
      if (m < M){
        float o = acc2[nt][r];
        if (n < 32)       jb.hs1[(size_t)m*32 + n] = f2bf(o);
        else if (n == 32) jb.outA[m] = o;
        else if (n == 33) jb.outB[m] = o;
      }
    }
  }
}

// ---------------- collapse attention vectors ----------------
struct CollapseJob { const float* W; const float* a; float* out; int K,H,C; };
struct CollapseArgs { CollapseJob j[8]; };
__global__ void collapse_kernel(CollapseArgs args){
  CollapseJob jb = args.j[blockIdx.x];
  int t = threadIdx.x;
  if (t < jb.K * jb.H){
    int k = t / jb.H, h = t % jb.H;
    const float* wr = jb.W + (size_t)k * (jb.H*jb.C) + h*jb.C;
    const float* ar = jb.a + h*jb.C;
    float s = 0.f;
    for (int c=0;c<jb.C;c++) s += wr[c]*ar[c];
    jb.out[h*jb.K + k] = s;   // layout [H,K]
  }
}

// ---------------- layer-0 pre-aggregation over hu/hi rows ----------------
// 8 dsts per wave, 8 lanes per dst, 8 channels per lane: edge-sum is fully
// within-lane => no cross-lane reduction epilogue. Unroll-4 edge loop: 4
// x-row gathers in flight per iteration (gather-latency hiding).
struct AggPJob {
  const int* offs; const int* ssrc;
  const unsigned short* x;     // bf16 [NN,64]
  const unsigned short* coef;  // bf16 [E,4]
  unsigned short* agg;         // bf16 [NN,256]
  float* den;                  // fp32 [NN,4]
};
__global__ __launch_bounds__(256) void aggpre_kernel(AggPJob ja, AggPJob jbb){
  const AggPJob jb = blockIdx.y ? jbb : ja;
  const int tid = threadIdx.x;
  const int lane = tid & 63, wid = tid >> 6;
  const int grp = lane >> 3;       // dst group within wave (0..7)
  const int cl  = lane & 7;        // channel lane within group
  const int c8  = cl * 8;          // channel base (8 bf16 = 16B per lane)
  const int dst = blockIdx.x*32 + wid*8 + grp;
  if (dst >= NN) return;
  const int b0 = jb.offs[dst], b1 = jb.offs[dst+1];
  float acc[4][8];
  float den[4] = {0.f,0.f,0.f,0.f};
  #pragma unroll
  for (int h=0;h<4;h++)
    #pragma unroll
    for (int c=0;c<8;c++) acc[h][c]=0.f;
  int e = b0;
  // unroll-4: batch 4 independent x gathers + coef loads per iteration
  for (; e+3 < b1; e += 4){
    int s0 = jb.ssrc[e];
    int s1 = jb.ssrc[e+1];
    int s2 = jb.ssrc[e+2];
    int s3 = jb.ssrc[e+3];
    uint4 q0 = *(const uint4*)(jb.x + ((size_t)s0<<6) + c8);
    uint4 q1 = *(const uint4*)(jb.x + ((size_t)s1<<6) + c8);
    uint4 q2 = *(const uint4*)(jb.x + ((size_t)s2<<6) + c8);
    uint4 q3 = *(const uint4*)(jb.x + ((size_t)s3<<6) + c8);
    uint2 w0 = *(const uint2*)(jb.coef + (size_t)e*4);
    uint2 w1 = *(const uint2*)(jb.coef + (size_t)(e+1)*4);
    uint2 w2 = *(const uint2*)(jb.coef + (size_t)(e+2)*4);
    uint2 w3 = *(const uint2*)(jb.coef + (size_t)(e+3)*4);
    agg_pair(acc, den, q0, q1, w0, w1);
    agg_pair(acc, den, q2, q3, w2, w3);
  }
  if (e+1 < b1){
    int s0 = jb.ssrc[e];
    int s1 = jb.ssrc[e+1];
    uint4 q0 = *(const uint4*)(jb.x + ((size_t)s0<<6) + c8);
    uint4 q1 = *(const uint4*)(jb.x + ((size_t)s1<<6) + c8);
    uint2 w0 = *(const uint2*)(jb.coef + (size_t)e*4);
    uint2 w1 = *(const uint2*)(jb.coef + (size_t)(e+1)*4);
    agg_pair(acc, den, q0, q1, w0, w1);
    e += 2;
  }
  if (e < b1){  // odd-degree tail: single edge, scalar path
    int s = jb.ssrc[e];
    uint4 q = *(const uint4*)(jb.x + ((size_t)s<<6) + c8);
    uint2 w = *(const uint2*)(jb.coef + (size_t)e*4);
    float wf[4] = { bf2f(w.x & 0xffffu), bf2f(w.x >> 16),
                    bf2f(w.y & 0xffffu), bf2f(w.y >> 16) };
    float xf[8] = { bf2f(q.x & 0xffffu), bf2f(q.x >> 16),
                    bf2f(q.y & 0xffffu), bf2f(q.y >> 16),
                    bf2f(q.z & 0xffffu), bf2f(q.z >> 16),
                    bf2f(q.w & 0xffffu), bf2f(q.w >> 16) };
    #pragma unroll
    for (int h=0;h<4;h++){
      den[h] += wf[h];
      #pragma unroll
      for (int c=0;c<8;c++) acc[h][c] += wf[h]*xf[c];
    }
  }
  // epilogue: pack + store only (no shuffles)
  #pragma unroll
  for (int h=0;h<4;h++){
    uint2 plo = bf4_pack(make_float4(acc[h][0],acc[h][1],acc[h][2],acc[h][3]));
    uint2 phi = bf4_pack(make_float4(acc[h][4],acc[h][5],acc[h][6],acc[h][7]));
    uint4 pk = { plo.x, plo.y, phi.x, phi.y };
    *(uint4*)(jb.agg + (size_t)dst*256 + h*64 + c8) = pk;
  }
  if (cl == 0)
    *(float4*)(jb.den + (size_t)dst*4) = make_float4(den[0],den[1],den[2],den[3]);
}

// ---------------- layer-1 aggregation (aggpre-style: 8 dst/wave, shuffle-free) ----
struct Agg1Job {
  const int* offs; const int* ssrc;
  const unsigned short* hs;   // bf16 [NN,32]
  const float* als; const float* ald;  // layer-1 logits
  const float* bias; float* out;
};
__global__ __launch_bounds__(256) void agg1_kernel(Agg1Job ja, Agg1Job jbb){
  const Agg1Job jb = blockIdx.y ? jbb : ja;
  const int tid = threadIdx.x;
  const int lane = tid & 63, wid = tid >> 6;
  const int grp = lane >> 3;       // dst group within wave (0..7)
  const int cl  = lane & 7;        // col lane within group
  const int c4  = cl * 4;          // col base (4 f32 outputs per lane)
  const int dst = blockIdx.x*32 + wid*8 + grp;
  if (dst >= NN) return;
  const int b0 = jb.offs[dst], b1 = jb.offs[dst+1];
  const float ad = jb.ald[dst];
  float acc[4] = {0.f,0.f,0.f,0.f};
  float den = 0.f;
  int e = b0;
  for (; e+3 < b1; e += 4){
    int s0 = jb.ssrc[e];
    int s1 = jb.ssrc[e+1];
    int s2 = jb.ssrc[e+2];
    int s3 = jb.ssrc[e+3];
    float a0 = jb.als[s0];
    float a1 = jb.als[s1];
    float a2 = jb.als[s2];
    float a3 = jb.als[s3];
    float4 v0 = bf4_load(jb.hs + ((size_t)s0<<5) + c4);
    float4 v1 = bf4_load(jb.hs + ((size_t)s1<<5) + c4);
    float4 v2 = bf4_load(jb.hs + ((size_t)s2<<5) + c4);
    float4 v3 = bf4_load(jb.hs + ((size_t)s3<<5) + c4);
    float w0 = __expf(lrelu_f(a0 + ad));
    float w1 = __expf(lrelu_f(a1 + ad));
    float w2 = __expf(lrelu_f(a2 + ad));
    float w3 = __expf(lrelu_f(a3 + ad));
    acc[0] += w0*v0.x + w1*v1.x + w2*v2.x + w3*v3.x;
    acc[1] += w0*v0.y + w1*v1.y + w2*v2.y + w3*v3.y;
    acc[2] += w0*v0.z + w1*v1.z + w2*v2.z + w3*v3.z;
    acc[3] += w0*v0.w + w1*v1.w + w2*v2.w + w3*v3.w;
    den += (w0 + w1) + (w2 + w3);
  }
  for (; e < b1; ++e){
    int s = jb.ssrc[e];
    float w = __expf(lrelu_f(jb.als[s] + ad));
    float4 v = bf4_load(jb.hs + ((size_t)s<<5) + c4);
    acc[0] += w*v.x; acc[1] += w*v.y; acc[2] += w*v.z; acc[3] += w*v.w;
    den += w;
  }
  const float inv = 1.f/(den + 1e-16f);
  float4 b = *(const float4*)(jb.bias + c4);
  float4 o = make_float4(acc[0]*inv+b.x, acc[1]*inv+b.y,
                         acc[2]*inv+b.z, acc[3]*inv+b.w);
  *(float4*)(jb.out + (size_t)dst*32 + c4) = o;
}

// ---------------- host glue ----------------
extern "C" void kernel_launch(void* const* d_in, const int* in_sizes, int n_in,
                              void* d_out, int out_size, void* d_ws, size_t ws_size,
                              hipStream_t stream)
{
  (void)in_sizes; (void)n_in; (void)out_size; (void)ws_size;
  const float* x_user   = (const float*)d_in[0];
  const float* x_item   = (const float*)d_in[1];
  const int*   e_u2i    = (const int*)  d_in[2];
  const int*   e_i2u    = (const int*)  d_in[3];
  const float* p_user_w = (const float*)d_in[4];
  const float* p_user_b = (const float*)d_in[5];
  const float* p_item_w = (const float*)d_in[6];
  const float* p_item_b = (const float*)d_in[7];
  const float* l0_u2i_ws=(const float*)d_in[8];
  const float* l0_u2i_wd=(const float*)d_in[9];
  const float* l0_u2i_as=(const float*)d_in[10];
  const float* l0_u2i_ad=(const float*)d_in[11];
  const float* l0_u2i_b =(const float*)d_in[12];
  const float* l0_i2u_ws=(const float*)d_in[13];
  const float* l0_i2u_wd=(const float*)d_in[14];
  const float* l0_i2u_as=(const float*)d_in[15];
  const float* l0_i2u_ad=(const float*)d_in[16];
  const float* l0_i2u_b =(const float*)d_in[17];
  const float* l1_u2i_ws=(const float*)d_in[18];
  const float* l1_u2i_wd=(const float*)d_in[19];
  const float* l1_u2i_as=(const float*)d_in[20];
  const float* l1_u2i_ad=(const float*)d_in[21];
  const float* l1_u2i_b =(const float*)d_in[22];
  const float* l1_i2u_ws=(const float*)d_in[23];
  const float* l1_i2u_wd=(const float*)d_in[24];
  const float* l1_i2u_as=(const float*)d_in[25];
  const float* l1_i2u_ad=(const float*)d_in[26];
  const float* l1_i2u_b =(const float*)d_in[27];

  char* base = (char*)d_ws;
  size_t off = 0;
  auto alloc = [&](size_t bytes)->void*{
    void* p = base + off;
    off += (bytes + 255) & ~(size_t)255;
    return p;
  };
  int* offs_u2i = (int*)alloc((size_t)(NN+1)*sizeof(int));
  int* offs_i2u = (int*)alloc((size_t)(NN+1)*sizeof(int));
  int* ssrc_u2i = (int*)alloc((size_t)NE*sizeof(int));
  int* ssrc_i2u = (int*)alloc((size_t)NE*sizeof(int));
  int* ghist    = (int*)alloc((size_t)2*200*sizeof(int));
  int* gbase    = (int*)alloc((size_t)2*200*sizeof(int));
  int* gcur     = (int*)alloc((size_t)2*200*sizeof(int));
  unsigned short* coef0_u2i = (unsigned short*)alloc((size_t)NE*4*sizeof(unsigned short));
  unsigned short* coef0_i2u = (unsigned short*)alloc((size_t)NE*4*sizeof(unsigned short));
  unsigned short* hu = (unsigned short*)alloc((size_t)NN*64*sizeof(unsigned short));
  unsigned short* hi = (unsigned short*)alloc((size_t)NN*64*sizeof(unsigned short));
  unsigned short* agg_u2i = (unsigned short*)alloc((size_t)NN*256*sizeof(unsigned short));
  unsigned short* agg_i2u = (unsigned short*)alloc((size_t)NN*256*sizeof(unsigned short));
  float* den_u2i = (float*)alloc((size_t)NN*4*sizeof(float));
  float* den_i2u = (float*)alloc((size_t)NN*4*sizeof(float));
  unsigned short* hu1 = (unsigned short*)alloc((size_t)NN*256*sizeof(unsigned short));
  unsigned short* hi1 = (unsigned short*)alloc((size_t)NN*256*sizeof(unsigned short));
  unsigned short* hs1_u2i = (unsigned short*)alloc((size_t)NN*32*sizeof(unsigned short));
  unsigned short* hs1_i2u = (unsigned short*)alloc((size_t)NN*32*sizeof(unsigned short));
  float* als0_u2i = (float*)alloc((size_t)NN*4*sizeof(float));
  float* ald0_u2i = (float*)alloc((size_t)NN*4*sizeof(float));
  float* als0_i2u = (float*)alloc((size_t)NN*4*sizeof(float));
  float* ald0_i2u = (float*)alloc((size_t)NN*4*sizeof(float));
  float* als1_u2i = (float*)alloc((size_t)NN*sizeof(float));
  float* ald1_u2i = (float*)alloc((size_t)NN*sizeof(float));
  float* als1_i2u = (float*)alloc((size_t)NN*sizeof(float));
  float* ald1_i2u = (float*)alloc((size_t)NN*sizeof(float));
  float* cw0s_u2i = (float*)alloc(256*sizeof(float));
  float* cw0d_u2i = (float*)alloc(256*sizeof(float));
  float* cw0s_i2u = (float*)alloc(256*sizeof(float));
  float* cw0d_i2u = (float*)alloc(256*sizeof(float));
  float* cw1s_u2i = (float*)alloc(256*sizeof(float));
  float* cw1d_u2i = (float*)alloc(256*sizeof(float));
  float* cw1s_i2u = (float*)alloc(256*sizeof(float));
  float* cw1d_i2u = (float*)alloc(256*sizeof(float));
  // transposed bf16 hi/lo weight images
  unsigned short* wt_pu_h  = (unsigned short*)alloc((size_t)64*128*sizeof(unsigned short));
  unsigned short* wt_pu_l  = (unsigned short*)alloc((size_t)64*128*sizeof(unsigned short));
  unsigned short* wt_pi_h  = (unsigned short*)alloc((size_t)64*128*sizeof(unsigned short));
  unsigned short* wt_pi_l  = (unsigned short*)alloc((size_t)64*128*sizeof(unsigned short));
  unsigned short* wt_l0u_h = (unsigned short*)alloc((size_t)256*64*sizeof(unsigned short));
  unsigned short* wt_l0u_l = (unsigned short*)alloc((size_t)256*64*sizeof(unsigned short));
  unsigned short* wt_l0i_h = (unsigned short*)alloc((size_t)256*64*sizeof(unsigned short));
  unsigned short* wt_l0i_l = (unsigned short*)alloc((size_t)256*64*sizeof(unsigned short));
  unsigned short* wt_wcu_h = (unsigned short*)alloc((size_t)48*256*sizeof(unsigned short));
  unsigned short* wt_wcu_l = (unsigned short*)alloc((size_t)48*256*sizeof(unsigned short));
  unsigned short* wt_wci_h = (unsigned short*)alloc((size_t)48*256*sizeof(unsigned short));
  unsigned short* wt_wci_l = (unsigned short*)alloc((size_t)48*256*sizeof(unsigned short));
  // pairs scratch aliases hu1/hi1: consumed by part2 (hu1/hi1 now LDS-only)
  int2* pairs_u2i = (int2*)hu1;
  int2* pairs_i2u = pairs_u2i + NE;

  const int GM = (NN + 63)/64;

  // ---- bucket sort stage A ----
  hipMemsetAsync(ghist, 0, (size_t)2*200*sizeof(int), stream);
  ghist_kernel<<<dim3(256,2), 256, 0, stream>>>(e_u2i, e_i2u, ghist);
  gscan_kernel<<<1, 256, 0, stream>>>(ghist, gbase, gcur);
  part1_kernel<<<dim3((NE+TILE1-1)/TILE1,2), 256, 0, stream>>>(
      e_u2i, e_i2u, gcur, pairs_u2i, pairs_i2u);

  // ---- collapse attention vectors ----
  CollapseArgs ca;
  ca.j[0] = {l0_u2i_ws, l0_u2i_as, cw0s_u2i, 64, 4, 64};
  ca.j[1] = {l0_u2i_wd, l0_u2i_ad, cw0d_u2i, 64, 4, 64};
  ca.j[2] = {l0_i2u_ws, l0_i2u_as, cw0s_i2u, 64, 4, 64};
  ca.j[3] = {l0_i2u_wd, l0_i2u_ad, cw0d_i2u, 64, 4, 64};
  ca.j[4] = {l1_u2i_ws, l1_u2i_as, cw1s_u2i, 256, 1, 32};
  ca.j[5] = {l1_u2i_wd, l1_u2i_ad, cw1d_u2i, 256, 1, 32};
  ca.j[6] = {l1_i2u_ws, l1_i2u_as, cw1s_i2u, 256, 1, 32};
  ca.j[7] = {l1_i2u_wd, l1_i2u_ad, cw1d_i2u, 256, 1, 32};
  collapse_kernel<<<8, 256, 0, stream>>>(ca);

  // ---- weight pre-conversion (transposed bf16 hi/lo; Wc built with cw cols) ----
  WcvArgs wa;
  wa.j[0] = {p_user_w,  nullptr,   nullptr,   wt_pu_h,  wt_pu_l,  128, 64, 0};
  wa.j[1] = {p_item_w,  nullptr,   nullptr,   wt_pi_h,  wt_pi_l,  128, 64, 0};
  wa.j[2] = {l0_u2i_ws, nullptr,   nullptr,   wt_l0u_h, wt_l0u_l, 64, 256, 0};
  wa.j[3] = {l0_i2u_ws, nullptr,   nullptr,   wt_l0i_h, wt_l0i_l, 64, 256, 0};
  wa.j[4] = {l1_u2i_ws, cw1s_u2i,  cw1d_i2u,  wt_wcu_h, wt_wcu_l, 256, 48, 1};
  wa.j[5] = {l1_i2u_ws, cw1s_i2u,  cw1d_u2i,  wt_wci_h, wt_wci_l, 256, 48, 1};
  wconv_kernel<<<dim3(64,6), 256, 0, stream>>>(wa);

  // ---- input projections (+bias +ELU) -> bf16, with fused layer-0 logits ----
  mgemm_kernel<4,128,true,true,false,false,true><<<dim3(GM,1,2), 256, 0, stream>>>(
      MgJob{x_user, wt_pu_h, wt_pu_l, p_user_b, hu, als0_u2i, ald0_i2u, cw0s_u2i, cw0d_i2u},
      MgJob{x_item, wt_pi_h, wt_pi_l, p_item_b, hi, als0_i2u, ald0_u2i, cw0s_i2u, cw0d_u2i},
      NN, 64);

  // ---- bucket sort stage B ----
  part2_kernel<<<dim3(GB,2), 256, 0, stream>>>(
      Part2Job{pairs_u2i, gbase,       als0_u2i, ald0_u2i, ssrc_u2i, offs_u2i, coef0_u2i},
      Part2Job{pairs_i2u, gbase + 200, als0_i2u, ald0_i2u, ssrc_i2u, offs_i2u, coef0_i2u});

  // ---- layer 0: pre-aggregate hu/hi rows (8 dst/wave, unroll-4 gathers) ----
  aggpre_kernel<<<dim3((NN+31)/32,2), 256, 0, stream>>>(
      AggPJob{offs_u2i, ssrc_u2i, hu, coef0_u2i, agg_u2i, den_u2i},
      AggPJob{offs_i2u, ssrc_i2u, hi, coef0_i2u, agg_i2u, den_i2u});

  // ---- fused layer-0 head GEMMs + layer-1 feature GEMM (interleaved per head) ----
  // chain A: agg_i2u -> hu1(LDS slice) -> hs1_u2i + als1_u2i + ald1_i2u
  // chain B: agg_u2i -> hi1(LDS slice) -> hs1_i2u + als1_i2u + ald1_u2i
  l0l1_kernel<<<dim3(GM,1,2), 256, 0, stream>>>(
      FsJob{agg_i2u, wt_l0i_h, wt_l0i_l, den_i2u, l0_i2u_b,
            wt_wcu_h, wt_wcu_l, hs1_u2i, als1_u2i, ald1_i2u},
      FsJob{agg_u2i, wt_l0u_h, wt_l0u_l, den_u2i, l0_u2i_b,
            wt_wci_h, wt_wci_l, hs1_i2u, als1_i2u, ald1_u2i},
      NN);

  // ---- layer 1: aggregate (+bias), shuffle-free 8 dst/wave ----
  float* hu2 = (float*)d_out;                  // first tuple element (users, i2u dst)
  float* hi2 = (float*)d_out + (size_t)NN*32;  // second tuple element (items, u2i dst)
  agg1_kernel<<<dim3((NN+31)/32,2), 256, 0, stream>>>(
      Agg1Job{offs_u2i, ssrc_u2i, hs1_u2i, als1_u2i, ald1_u2i, l1_u2i_b, hi2},
      Agg1Job{offs_i2u, ssrc_i2u, hs1_i2u, als1_i2u, ald1_i2u, l1_i2u_b, hu2});
}

// Round 14
// 337.550 us; speedup vs baseline: 1.1090x; 1.0026x over previous
//
#include <hip/hip_runtime.h>
#include <cstdint>
#include <cstddef>

#define NN 50000
#define NE 800000
#define GB 196        // coarse buckets = ceil(NN/256)
#define TILE1 4096    // edges per part1 block
#define CAP 8192      // max edges per bucket in part2 LDS (mean 4082)

typedef __attribute__((ext_vector_type(8))) short short8;
typedef __attribute__((ext_vector_type(4))) float floatx4;

__device__ __forceinline__ float lrelu_f(float x){ return x >= 0.f ? x : 0.2f*x; }
__device__ __forceinline__ float elu_f(float x){ return x > 0.f ? x : __expf(x) - 1.f; }

__device__ __forceinline__ unsigned short f2bf(float f){
  unsigned int u = __float_as_uint(f);
  u += 0x7FFFu + ((u >> 16) & 1u);
  return (unsigned short)(u >> 16);
}
__device__ __forceinline__ float bf2f(unsigned int us){
  return __uint_as_float(us << 16);
}
__device__ __forceinline__ float4 bf4_load(const unsigned short* p){
  uint2 q = *(const uint2*)p;
  return make_float4(bf2f(q.x & 0xffffu), bf2f(q.x >> 16),
                     bf2f(q.y & 0xffffu), bf2f(q.y >> 16));
}
__device__ __forceinline__ uint2 bf4_pack(float4 o){
  uint2 p;
  p.x = (unsigned)f2bf(o.x) | ((unsigned)f2bf(o.y) << 16);
  p.y = (unsigned)f2bf(o.z) | ((unsigned)f2bf(o.w) << 16);
  return p;
}
__device__ __forceinline__ void split_bf(float a, unsigned short& h, unsigned short& l){
  h = f2bf(a);
  l = f2bf(a - bf2f(h));
}

// v_dot2_f32_bf16: acc += a.bf16[0]*b.bf16[0] + a.bf16[1]*b.bf16[1]
__device__ __forceinline__ float dot2bf(float acc, unsigned a, unsigned b){
  asm("v_dot2_f32_bf16 %0, %1, %2, %0" : "+v"(acc) : "v"(a), "v"(b));
  return acc;
}

// process one edge PAIR (bf16 operands stay packed; sums stay within-lane)
__device__ __forceinline__ void agg_pair(float (&acc)[4][8], float (&den)[4],
                                         uint4 q0, uint4 q1, uint2 w0, uint2 w1){
  const unsigned ONE2 = 0x3F803F80u;  // packed bf16 (1.0, 1.0)
  unsigned wp[4];
  wp[0] = __builtin_amdgcn_perm(w1.x, w0.x, 0x05040100u);
  wp[1] = __builtin_amdgcn_perm(w1.x, w0.x, 0x07060302u);
  wp[2] = __builtin_amdgcn_perm(w1.y, w0.y, 0x05040100u);
  wp[3] = __builtin_amdgcn_perm(w1.y, w0.y, 0x07060302u);
  unsigned xp[8];
  xp[0] = __builtin_amdgcn_perm(q1.x, q0.x, 0x05040100u);
  xp[1] = __builtin_amdgcn_perm(q1.x, q0.x, 0x07060302u);
  xp[2] = __builtin_amdgcn_perm(q1.y, q0.y, 0x05040100u);
  xp[3] = __builtin_amdgcn_perm(q1.y, q0.y, 0x07060302u);
  xp[4] = __builtin_amdgcn_perm(q1.z, q0.z, 0x05040100u);
  xp[5] = __builtin_amdgcn_perm(q1.z, q0.z, 0x07060302u);
  xp[6] = __builtin_amdgcn_perm(q1.w, q0.w, 0x05040100u);
  xp[7] = __builtin_amdgcn_perm(q1.w, q0.w, 0x07060302u);
  #pragma unroll
  for (int h=0;h<4;h++){
    den[h] = dot2bf(den[h], wp[h], ONE2);
    #pragma unroll
    for (int c=0;c<8;c++) acc[h][c] = dot2bf(acc[h][c], wp[h], xp[c]);
  }
}

// ---------------- two-level bucket sort of edges by dst ----------------
__global__ __launch_bounds__(256) void ghist_kernel(const int* __restrict__ e0,
                                                    const int* __restrict__ e1,
                                                    int* __restrict__ ghist){
  const int ty = blockIdx.y;
  const int* e = ty ? e1 : e0;
  __shared__ int h[GB];
  for (int j=threadIdx.x; j<GB; j+=256) h[j]=0;
  __syncthreads();
  for (int i = blockIdx.x*256 + threadIdx.x; i < NE; i += 256*256)
    atomicAdd(&h[e[NE+i]>>8], 1);
  __syncthreads();
  for (int j=threadIdx.x; j<GB; j+=256) if (h[j]) atomicAdd(&ghist[ty*200+j], h[j]);
}

__global__ __launch_bounds__(256) void gscan_kernel(const int* __restrict__ ghist,
                                                    int* __restrict__ gbase,
                                                    int* __restrict__ gcur){
  __shared__ int wb[4];
  const int t = threadIdx.x, wv = t>>6, l = t&63;
  for (int ty=0; ty<2; ++ty){
    int v = (t < GB) ? ghist[ty*200+t] : 0;
    int sum = v;
    #pragma unroll
    for (int off=1; off<64; off<<=1){
      int x = __shfl_up(sum, off, 64);
      if (l >= off) sum += x;
    }
    if (l == 63) wb[wv] = sum;
    __syncthreads();
    int wbase = 0;
    #pragma unroll
    for (int w=0; w<4; ++w) if (w < wv) wbase += wb[w];
    int excl = wbase + sum - v;
    if (t <= GB) gbase[ty*200+t] = excl;
    if (t <  GB) gcur [ty*200+t] = excl;
    __syncthreads();
  }
}

// partition with LDS staging: global writes are contiguous per-bucket runs
__global__ __launch_bounds__(256) void part1_kernel(const int* __restrict__ e0,
                                                    const int* __restrict__ e1,
                                                    int* __restrict__ gcur,
                                                    int2* __restrict__ p0,
                                                    int2* __restrict__ p1){
  const int ty = blockIdx.y;
  const int* e = ty ? e1 : e0;
  int2* pairs = ty ? p1 : p0;
  __shared__ int cnt[256];
  __shared__ int lstart[256];
  __shared__ int lcur[256];
  __shared__ int curg[GB];
  __shared__ int lsrc[TILE1];
  __shared__ int ldst[TILE1];
  __shared__ int wb[4];
  const int t = threadIdx.x;
  cnt[t] = 0;
  __syncthreads();
  int dreg[16], sreg[16];
  const int base = blockIdx.x*TILE1;
  const int ntile = min(TILE1, NE - base);
  #pragma unroll
  for (int it=0; it<16; ++it){
    int i = base + it*256 + t;
    int d = -1, s = 0;
    if (i < NE){ d = e[NE+i]; s = e[i]; atomicAdd(&cnt[d>>8], 1); }
    dreg[it] = d; sreg[it] = s;
  }
  __syncthreads();
  int c = cnt[t], sum = c;
  #pragma unroll
  for (int off=1; off<64; off<<=1){
    int x = __shfl_up(sum, off, 64);
    if ((t&63) >= off) sum += x;
  }
  if ((t&63) == 63) wb[t>>6] = sum;
  __syncthreads();
  int wbase = 0;
  #pragma unroll
  for (int w=0; w<4; ++w) if (w < (t>>6)) wbase += wb[w];
  int excl = wbase + sum - c;
  lstart[t] = excl;
  lcur[t] = excl;
  if (t < GB && c > 0) curg[t] = atomicAdd(&gcur[ty*200+t], c);
  __syncthreads();
  #pragma unroll
  for (int it=0; it<16; ++it){
    int d = dreg[it];
    if (d >= 0){
      int pos = atomicAdd(&lcur[d>>8], 1);
      lsrc[pos] = sreg[it];
      ldst[pos] = d;
    }
  }
  __syncthreads();
  for (int i=t; i<ntile; i+=256){
    int d = ldst[i];
    int j = d>>8;
    pairs[curg[j] + (i - lstart[j])] = make_int2(lsrc[i], d);
  }
}

// per-bucket LDS bin by dst + CSR offsets + fused layer-0 softmax weights (bf16).
struct Part2Job {
  const int2* pairs; const int* gbase;
  const float* als; const float* ald;   // [NN,4]
  int* ssrc; int* offs; unsigned short* coef;  // coef: [E,4] bf16
};
__global__ __launch_bounds__(256) void part2_kernel(Part2Job j0, Part2Job j1){
  const Part2Job jb = blockIdx.y ? j1 : j0;
  const int b = blockIdx.x;
  const int t = threadIdx.x;
  __shared__ int lcnt[256];
  __shared__ int lcur[256];
  __shared__ int wb[4];
  __shared__ int sorted_src[CAP];
  __shared__ unsigned char sorted_dl[CAP];
  const int gb0 = jb.gbase[b], gb1 = jb.gbase[b+1];
  const int n = gb1 - gb0;
  lcnt[t] = 0;
  __syncthreads();
  for (int i=t; i<n; i+=256)
    atomicAdd(&lcnt[jb.pairs[gb0+i].y - (b<<8)], 1);
  __syncthreads();
  int c = lcnt[t], sum = c;
  #pragma unroll
  for (int off=1; off<64; off<<=1){
    int x = __shfl_up(sum, off, 64);
    if ((t&63) >= off) sum += x;
  }
  if ((t&63) == 63) wb[t>>6] = sum;
  __syncthreads();
  int wbase = 0;
  #pragma unroll
  for (int w=0; w<4; ++w) if (w < (t>>6)) wbase += wb[w];
  int excl = wbase + sum - c;
  lcur[t] = excl;
  int g = (b<<8) + t;
  if (g <= NN) jb.offs[g] = gb0 + excl;
  __syncthreads();
  for (int i=t; i<n; i+=256){
    int2 pr = jb.pairs[gb0+i];
    int dl = pr.y - (b<<8);
    int pos = atomicAdd(&lcur[dl], 1);
    sorted_src[pos] = pr.x;
    sorted_dl[pos] = (unsigned char)dl;
  }
  __syncthreads();
  const float4* als4 = (const float4*)jb.als;
  const float4* ald4 = (const float4*)jb.ald;
  for (int i=t; i<n; i+=256){
    int s  = sorted_src[i];
    int dl = sorted_dl[i];
    float4 a  = als4[s];
    float4 ad = ald4[(b<<8)+dl];
    // no max-shift: |alpha| small at this model scale; softmax shift-invariant.
    float4 w;
    w.x = __expf(lrelu_f(a.x+ad.x));
    w.y = __expf(lrelu_f(a.y+ad.y));
    w.z = __expf(lrelu_f(a.z+ad.z));
    w.w = __expf(lrelu_f(a.w+ad.w));
    ((uint2*)jb.coef)[gb0+i] = bf4_pack(w);
    jb.ssrc[gb0+i] = s;
  }
}

// ---------------- weight prep (collapse folded in) ----------------
// mode 0: plain transpose W[K][N] f32 -> bf16 hi/lo [N][K].
// mode 1: Wc build [256 x 48] -> transposed: n<32: W(=l1 Ws)[k*32+n];
//         n==32: dot32(W[k*32+.], a1(=l1 as));  n==33: dot32(a2(=other wd)[k*32+.], a3(=other ad)); else 0.
// mode 2: cw0 collapse -> FLOAT out: k=idx/N, h=idx%N (N=H=4, C=64):
//         fout[h*K+k] = dot64(W[k*256 + h*64 + .], a1[h*64 + .])   (sequential sum, matches old collapse)
struct WcvJob {
  const float* W; const float* a1; const float* a2; const float* a3;
  unsigned short* Wth; unsigned short* Wtl; float* fout;
  int K; int N; int mode;
};
struct WcvArgs { WcvJob j[10]; };
__global__ __launch_bounds__(256) void wconv_kernel(WcvArgs args){
  WcvJob jb = args.j[blockIdx.y];
  int idx = blockIdx.x*256 + threadIdx.x;
  if (idx >= jb.K * jb.N) return;
  if (jb.mode == 2){
    int k = idx / jb.N, h = idx % jb.N;
    const float* wr = jb.W + (size_t)k*256 + h*64;
    const float* ar = jb.a1 + h*64;
    float s = 0.f;
    for (int c=0;c<64;c++) s += wr[c]*ar[c];
    jb.fout[h*jb.K + k] = s;
    return;
  }
  int k = idx / jb.N, n = idx % jb.N;
  float val;
  if (jb.mode == 0) val = jb.W[(size_t)k*jb.N + n];
  else {
    if (n < 32)       val = jb.W[(size_t)k*32 + n];
    else if (n == 32){
      float s = 0.f;
      for (int c=0;c<32;c++) s += jb.W[(size_t)k*32 + c]*jb.a1[c];
      val = s;
    }
    else if (n == 33){
      float s = 0.f;
      for (int c=0;c<32;c++) s += jb.a2[(size_t)k*32 + c]*jb.a3[c];
      val = s;
    }
    else              val = 0.f;
  }
  unsigned short h, g;
  split_bf(val, h, g);
  jb.Wth[(size_t)n*jb.K + k] = h;
  jb.Wtl[(size_t)n*jb.K + k] = g;
}

// ---------------- MFMA GEMM (proj): C = act(A[M,K] @ W[K,N] (+bias)) ----------------
// Two-phase LDS-staged structure (round-9 proven).
struct MgJob {
  const void* A;                     // f32 [M,KK] if !BF16A else bf16 [M,KK]
  const unsigned short* Wth;         // [N][KK] bf16 hi (transposed)
  const unsigned short* Wtl;         // [N][KK] bf16 lo
  const float* bias;
  void* C; float* outA; float* outB;
  const float* cwS; const float* cwD;
};
template<int NT, int KK, bool ELU, bool BF16OUT, bool BF16A, bool LG, bool LOGIT>
__global__ __launch_bounds__(256) void mgemm_kernel(MgJob j0, MgJob j1,
                                                    int M, int N)
{
  const MgJob jb = blockIdx.z ? j1 : j0;
  constexpr int TN = NT*16;
  __shared__ __align__(16) unsigned short Ah[64*72];
  __shared__ __align__(16) unsigned short Al[BF16A ? 8 : 64*72];
  __shared__ __align__(16) unsigned short Bh[TN*72];
  __shared__ __align__(16) unsigned short Bl[TN*72];
  __shared__ float CwS[LOGIT ? 256 : 1];
  __shared__ float CwD[LOGIT ? 256 : 1];
  const int t = threadIdx.x;
  const int m0 = blockIdx.x*64;
  const int n0 = blockIdx.y*TN;
  const int wv = t>>6, l = t&63;
  const int lr = l&15, lq = l>>4;
  if constexpr (LOGIT){ CwS[t] = jb.cwS[t]; CwD[t] = jb.cwD[t]; }
  floatx4 acc[NT];
  #pragma unroll
  for (int i=0;i<NT;i++) acc[i] = (floatx4){0.f,0.f,0.f,0.f};

  #pragma unroll
  for (int kt=0; kt<KK; kt+=64){
    if constexpr (BF16A){
      const unsigned short* A = (const unsigned short*)jb.A;
      #pragma unroll
      for (int i=0;i<2;i++){
        int li = t + i*256;
        int r = li >> 3, c8 = (li & 7)*8;
        short8 v = {0,0,0,0,0,0,0,0};
        if (m0 + r < M) v = *(const short8*)(A + (size_t)(m0+r)*KK + kt + c8);
        *(short8*)&Ah[r*72 + c8] = v;
      }
    } else {
      const float* A = (const float*)jb.A;
      #pragma unroll
      for (int i=0;i<4;i++){
        int li = t + i*256;
        int r = li >> 4, c4 = (li & 15)*4;
        float4 v = make_float4(0.f,0.f,0.f,0.f);
        if (m0 + r < M) v = *(const float4*)(A + (size_t)(m0+r)*KK + kt + c4);
        unsigned short h0,h1,h2,h3,g0,g1,g2,g3;
        split_bf(v.x,h0,g0); split_bf(v.y,h1,g1);
        split_bf(v.z,h2,g2); split_bf(v.w,h3,g3);
        uint2 ph = { (unsigned)h0 | ((unsigned)h1<<16), (unsigned)h2 | ((unsigned)h3<<16) };
        uint2 pl = { (unsigned)g0 | ((unsigned)g1<<16), (unsigned)g2 | ((unsigned)g3<<16) };
        *(uint2*)&Ah[r*72 + c4] = ph;
        *(uint2*)&Al[r*72 + c4] = pl;
      }
    }
    // B-stage: pure copy of preconverted bf16 hi/lo (16B chunks).
    for (int c = t; c < TN*8; c += 256){
      int n  = c >> 3;
      int k8 = (c & 7) * 8;
      *(short8*)&Bh[n*72 + k8] =
          *(const short8*)(jb.Wth + (size_t)(n0 + n)*KK + kt + k8);
      *(short8*)&Bl[n*72 + k8] =
          *(const short8*)(jb.Wtl + (size_t)(n0 + n)*KK + kt + k8);
    }
    __syncthreads();
    #pragma unroll
    for (int ks=0; ks<2; ks++){
      const int koff = ks*32 + lq*8;
      short8 a_h = *(const short8*)&Ah[(wv*16+lr)*72 + koff];
      short8 a_l;
      if constexpr (!BF16A) a_l = *(const short8*)&Al[(wv*16+lr)*72 + koff];
      #pragma unroll
      for (int nt=0; nt<NT; nt++){
        short8 b_h = *(const short8*)&Bh[(nt*16+lr)*72 + koff];
        short8 b_l = *(const short8*)&Bl[(nt*16+lr)*72 + koff];
        acc[nt] = __builtin_amdgcn_mfma_f32_16x16x32_bf16(a_h, b_h, acc[nt], 0,0,0);
        acc[nt] = __builtin_amdgcn_mfma_f32_16x16x32_bf16(a_h, b_l, acc[nt], 0,0,0);
        if constexpr (!BF16A)
          acc[nt] = __builtin_amdgcn_mfma_f32_16x16x32_bf16(a_l, b_h, acc[nt], 0,0,0);
      }
    }
    __syncthreads();
  }
  float ls[LOGIT ? 4 : 1][LOGIT ? 4 : 1];   // [r][h]
  float ld_[LOGIT ? 4 : 1][LOGIT ? 4 : 1];
  if constexpr (LOGIT){
    #pragma unroll
    for (int r=0;r<4;r++)
      #pragma unroll
      for (int h=0;h<4;h++){ ls[r][h]=0.f; ld_[r][h]=0.f; }
  }
  #pragma unroll
  for (int nt=0; nt<NT; nt++){
    int n = n0 + nt*16 + lr;
    float bv = jb.bias ? jb.bias[n] : 0.f;
    #pragma unroll
    for (int r=0;r<4;r++){
      int m = m0 + wv*16 + lq*4 + r;
      if (m < M){
        float o = acc[nt][r] + bv;
        if (ELU) o = elu_f(o);
        if constexpr (LG){
          if (n < 32)       ((unsigned short*)jb.C)[(size_t)m*32 + n] = f2bf(o);
          else if (n == 32) jb.outA[m] = o;
          else if (n == 33) jb.outB[m] = o;
        } else {
          if (BF16OUT) ((unsigned short*)jb.C)[(size_t)m*N + n] = f2bf(o);
          else         ((float*)jb.C)[(size_t)m*N + n] = o;
        }
        if constexpr (LOGIT){
          #pragma unroll
          for (int h=0;h<4;h++){
            ls[r][h]  = fmaf(o, CwS[h*64 + n], ls[r][h]);
            ld_[r][h] = fmaf(o, CwD[h*64 + n], ld_[r][h]);
          }
        }
      }
    }
  }
  if constexpr (LOGIT){
    // reduce over the 16 lr-lanes (channels), then lane lr==0 writes 4 rows x 4 heads
    #pragma unroll
    for (int r=0;r<4;r++)
      #pragma unroll
      for (int h=0;h<4;h++){
        float a = ls[r][h], d = ld_[r][h];
        #pragma unroll
        for (int off=1; off<16; off<<=1){
          a += __shfl_xor(a, off, 64);
          d += __shfl_xor(d, off, 64);
        }
        ls[r][h]=a; ld_[r][h]=d;
      }
    if (lr == 0){
      #pragma unroll
      for (int r=0;r<4;r++){
        int m = m0 + wv*16 + lq*4 + r;
        if (m < M){
          #pragma unroll
          for (int h=0;h<4;h++){
            jb.outA[(size_t)m*4 + h] = ls[r][h];
            jb.outB[(size_t)m*4 + h] = ld_[r][h];
          }
        }
      }
    }
  }
}

// ---------------- fused layer-0 head GEMMs + layer-1 feature GEMM ----------------
// Interleaved per-head schedule (round-13 proven, 36.9KB LDS). H1 epilogue
// stores are dword-PACKED via shfl_xor(.,1): halves store count and conflict
// depth (was 16 scalar ushort stores/lane at 4-way -> 3.2M conflict cycles).
struct FsJob {
  const unsigned short* A;            // agg bf16 [M,256]
  const unsigned short* W0h;          // [256][64] l0 Ws transposed hi
  const unsigned short* W0l;          //             lo
  const float* den;                   // [M,4]
  const float* b0;                    // [256] l0 bias
  const unsigned short* Wch;          // [48][256] Wc transposed hi
  const unsigned short* Wcl;          //             lo
  unsigned short* hs1;                // bf16 [M,32]
  float* outA; float* outB;           // layer-1 logits [M]
};
__global__ __launch_bounds__(256) void l0l1_kernel(FsJob j0, FsJob j1, int M){
  const FsJob jb = blockIdx.z ? j1 : j0;
  __shared__ __align__(16) unsigned short H1[64*72];    // current head's hi1 slice
  __shared__ __align__(16) unsigned short Sa[64*72];
  __shared__ __align__(16) unsigned short Sbh[64*72];
  __shared__ __align__(16) unsigned short Sbl[64*72];
  const int t = threadIdx.x;
  const int m0 = blockIdx.x*64;
  const int wv = t>>6, l = t&63;
  const int lr = l&15, lq = l>>4;
  floatx4 acc2[3];
  #pragma unroll
  for (int i=0;i<3;i++) acc2[i] = (floatx4){0.f,0.f,0.f,0.f};

  for (int h=0; h<4; ++h){
    // stage A head slice + W0 head slice
    #pragma unroll
    for (int i=0;i<2;i++){
      int li = t + i*256;
      int r = li >> 3, c8 = (li & 7)*8;
      short8 v = {0,0,0,0,0,0,0,0};
      if (m0 + r < M) v = *(const short8*)(jb.A + (size_t)(m0+r)*256 + h*64 + c8);
      *(short8*)&Sa[r*72 + c8] = v;
    }
    #pragma unroll
    for (int i=0;i<2;i++){
      int c  = t + i*256;
      int n  = c >> 3;
      int k8 = (c & 7) * 8;
      *(short8*)&Sbh[n*72 + k8] =
          *(const short8*)(jb.W0h + (size_t)(h*64 + n)*64 + k8);
      *(short8*)&Sbl[n*72 + k8] =
          *(const short8*)(jb.W0l + (size_t)(h*64 + n)*64 + k8);
    }
    __syncthreads();
    // head GEMM
    floatx4 acc[4];
    #pragma unroll
    for (int i=0;i<4;i++) acc[i] = (floatx4){0.f,0.f,0.f,0.f};
    #pragma unroll
    for (int ks=0; ks<2; ks++){
      const int koff = ks*32 + lq*8;
      short8 a_h = *(const short8*)&Sa[(wv*16+lr)*72 + koff];
      #pragma unroll
      for (int nt=0; nt<4; nt++){
        short8 b_h = *(const short8*)&Sbh[(nt*16+lr)*72 + koff];
        short8 b_l = *(const short8*)&Sbl[(nt*16+lr)*72 + koff];
        acc[nt] = __builtin_amdgcn_mfma_f32_16x16x32_bf16(a_h, b_h, acc[nt], 0,0,0);
        acc[nt] = __builtin_amdgcn_mfma_f32_16x16x32_bf16(a_h, b_l, acc[nt], 0,0,0);
      }
    }
    float inv[4];
    #pragma unroll
    for (int r=0;r<4;r++){
      int m = m0 + wv*16 + lq*4 + r;
      inv[r] = (m < M) ? 1.f/(jb.den[(size_t)m*4 + h] + 1e-16f) : 0.f;
    }
    // H1 write: pack lr-even/odd pairs into dword stores (conflict fix)
    #pragma unroll
    for (int nt=0; nt<4; nt++){
      int col = nt*16 + lr;
      float bv = jb.b0[h*64 + col];
      #pragma unroll
      for (int r=0;r<4;r++){
        int mrow = wv*16 + lq*4 + r;
        unsigned me = (unsigned)f2bf(elu_f(acc[nt][r]*inv[r] + bv));
        unsigned other = __shfl_xor((int)me, 1, 64);
        if ((lr & 1) == 0)
          *(unsigned*)&H1[mrow*72 + col] = me | (other << 16);
      }
    }
    __syncthreads();   // H1 written; W0 reads complete -> Sb reusable
    // stage Wc K-slice kt=h
    for (int c = t; c < 48*8; c += 256){
      int n  = c >> 3;
      int k8 = (c & 7) * 8;
      *(short8*)&Sbh[n*72 + k8] =
          *(const short8*)(jb.Wch + (size_t)n*256 + h*64 + k8);
      *(short8*)&Sbl[n*72 + k8] =
          *(const short8*)(jb.Wcl + (size_t)n*256 + h*64 + k8);
    }
    __syncthreads();
    // accumulate layer-1 K-slice
    #pragma unroll
    for (int ks=0; ks<2; ks++){
      const int koff = ks*32 + lq*8;
      short8 a_h = *(const short8*)&H1[(wv*16+lr)*72 + koff];
      #pragma unroll
      for (int nt=0; nt<3; nt++){
        short8 b_h = *(const short8*)&Sbh[(nt*16+lr)*72 + koff];
        short8 b_l = *(const short8*)&Sbl[(nt*16+lr)*72 + koff];
        acc2[nt] = __builtin_amdgcn_mfma_f32_16x16x32_bf16(a_h, b_h, acc2[nt], 0,0,0);
        acc2[nt] = __builtin_amdgcn_mfma_f32_16x16x32_bf16(a_h, b_l, acc2[nt], 0,0,0);
      }
    }
    __syncthreads();   // H1/Sb reads complete -> reusable next head
  }
  // epilogue: cols 0..31 -> hs1 bf16, col 32 -> outA, col 33 -> outB
  #pragma unroll
  for (int nt=0; nt<3; nt++){
    int n = nt*16 + lr;
    #pragma unroll
    for (int r=0;r<4;r++){
      int m = m0 + wv*16 + lq*4 + r;
      if (m < M){
        float o = acc2[nt][r];
        if (n < 32)       jb.hs1[(size_t)m*32 + n] = f2bf(o);
        else if (n == 32) jb.outA[m] = o;
        else if (n == 33) jb.outB[m] = o;
      }
    }
  }
}

// ---------------- layer-0 pre-aggregation over hu/hi rows ----------------
// 8 dsts per wave, 8 lanes per dst, 8 channels per lane: edge-sum is fully
// within-lane => no cross-lane reduction epilogue. Unroll-4 edge loop: 4
// x-row gathers in flight per iteration (gather-latency hiding).
struct AggPJob {
  const int* offs; const int* ssrc;
  const unsigned short* x;     // bf16 [NN,64]
  const unsigned short* coef;  // bf16 [E,4]
  unsigned short* agg;         // bf16 [NN,256]
  float* den;                  // fp32 [NN,4]
};
__global__ __launch_bounds__(256) void aggpre_kernel(AggPJob ja, AggPJob jbb){
  const AggPJob jb = blockIdx.y ? jbb : ja;
  const int tid = threadIdx.x;
  const int lane = tid & 63, wid = tid >> 6;
  const int grp = lane >> 3;       // dst group within wave (0..7)
  const int cl  = lane & 7;        // channel lane within group
  const int c8  = cl * 8;          // channel base (8 bf16 = 16B per lane)
  const int dst = blockIdx.x*32 + wid*8 + grp;
  if (dst >= NN) return;
  const int b0 = jb.offs[dst], b1 = jb.offs[dst+1];
  float acc[4][8];
  float den[4] = {0.f,0.f,0.f,0.f};
  #pragma unroll
  for (int h=0;h<4;h++)
    #pragma unroll
    for (int c=0;c<8;c++) acc[h][c]=0.f;
  int e = b0;
  // unroll-4: batch 4 independent x gathers + coef loads per iteration
  for (; e+3 < b1; e += 4){
    int s0 = jb.ssrc[e];
    int s1 = jb.ssrc[e+1];
    int s2 = jb.ssrc[e+2];
    int s3 = jb.ssrc[e+3];
    uint4 q0 = *(const uint4*)(jb.x + ((size_t)s0<<6) + c8);
    uint4 q1 = *(const uint4*)(jb.x + ((size_t)s1<<6) + c8);
    uint4 q2 = *(const uint4*)(jb.x + ((size_t)s2<<6) + c8);
    uint4 q3 = *(const uint4*)(jb.x + ((size_t)s3<<6) + c8);
    uint2 w0 = *(const uint2*)(jb.coef + (size_t)e*4);
    uint2 w1 = *(const uint2*)(jb.coef + (size_t)(e+1)*4);
    uint2 w2 = *(const uint2*)(jb.coef + (size_t)(e+2)*4);
    uint2 w3 = *(const uint2*)(jb.coef + (size_t)(e+3)*4);
    agg_pair(acc, den, q0, q1, w0, w1);
    agg_pair(acc, den, q2, q3, w2, w3);
  }
  if (e+1 < b1){
    int s0 = jb.ssrc[e];
    int s1 = jb.ssrc[e+1];
    uint4 q0 = *(const uint4*)(jb.x + ((size_t)s0<<6) + c8);
    uint4 q1 = *(const uint4*)(jb.x + ((size_t)s1<<6) + c8);
    uint2 w0 = *(const uint2*)(jb.coef + (size_t)e*4);
    uint2 w1 = *(const uint2*)(jb.coef + (size_t)(e+1)*4);
    agg_pair(acc, den, q0, q1, w0, w1);
    e += 2;
  }
  if (e < b1){  // odd-degree tail: single edge, scalar path
    int s = jb.ssrc[e];
    uint4 q = *(const uint4*)(jb.x + ((size_t)s<<6) + c8);
    uint2 w = *(const uint2*)(jb.coef + (size_t)e*4);
    float wf[4] = { bf2f(w.x & 0xffffu), bf2f(w.x >> 16),
                    bf2f(w.y & 0xffffu), bf2f(w.y >> 16) };
    float xf[8] = { bf2f(q.x & 0xffffu), bf2f(q.x >> 16),
                    bf2f(q.y & 0xffffu), bf2f(q.y >> 16),
                    bf2f(q.z & 0xffffu), bf2f(q.z >> 16),
                    bf2f(q.w & 0xffffu), bf2f(q.w >> 16) };
    #pragma unroll
    for (int h=0;h<4;h++){
      den[h] += wf[h];
      #pragma unroll
      for (int c=0;c<8;c++) acc[h][c] += wf[h]*xf[c];
    }
  }
  // epilogue: pack + store only (no shuffles)
  #pragma unroll
  for (int h=0;h<4;h++){
    uint2 plo = bf4_pack(make_float4(acc[h][0],acc[h][1],acc[h][2],acc[h][3]));
    uint2 phi = bf4_pack(make_float4(acc[h][4],acc[h][5],acc[h][6],acc[h][7]));
    uint4 pk = { plo.x, plo.y, phi.x, phi.y };
    *(uint4*)(jb.agg + (size_t)dst*256 + h*64 + c8) = pk;
  }
  if (cl == 0)
    *(float4*)(jb.den + (size_t)dst*4) = make_float4(den[0],den[1],den[2],den[3]);
}

// ---------------- layer-1 aggregation (aggpre-style: 8 dst/wave, shuffle-free) ----
struct Agg1Job {
  const int* offs; const int* ssrc;
  const unsigned short* hs;   // bf16 [NN,32]
  const float* als; const float* ald;  // layer-1 logits
  const float* bias; float* out;
};
__global__ __launch_bounds__(256) void agg1_kernel(Agg1Job ja, Agg1Job jbb){
  const Agg1Job jb = blockIdx.y ? jbb : ja;
  const int tid = threadIdx.x;
  const int lane = tid & 63, wid = tid >> 6;
  const int grp = lane >> 3;       // dst group within wave (0..7)
  const int cl  = lane & 7;        // col lane within group
  const int c4  = cl * 4;          // col base (4 f32 outputs per lane)
  const int dst = blockIdx.x*32 + wid*8 + grp;
  if (dst >= NN) return;
  const int b0 = jb.offs[dst], b1 = jb.offs[dst+1];
  const float ad = jb.ald[dst];
  float acc[4] = {0.f,0.f,0.f,0.f};
  float den = 0.f;
  int e = b0;
  for (; e+3 < b1; e += 4){
    int s0 = jb.ssrc[e];
    int s1 = jb.ssrc[e+1];
    int s2 = jb.ssrc[e+2];
    int s3 = jb.ssrc[e+3];
    float a0 = jb.als[s0];
    float a1 = jb.als[s1];
    float a2 = jb.als[s2];
    float a3 = jb.als[s3];
    float4 v0 = bf4_load(jb.hs + ((size_t)s0<<5) + c4);
    float4 v1 = bf4_load(jb.hs + ((size_t)s1<<5) + c4);
    float4 v2 = bf4_load(jb.hs + ((size_t)s2<<5) + c4);
    float4 v3 = bf4_load(jb.hs + ((size_t)s3<<5) + c4);
    float w0 = __expf(lrelu_f(a0 + ad));
    float w1 = __expf(lrelu_f(a1 + ad));
    float w2 = __expf(lrelu_f(a2 + ad));
    float w3 = __expf(lrelu_f(a3 + ad));
    acc[0] += w0*v0.x + w1*v1.x + w2*v2.x + w3*v3.x;
    acc[1] += w0*v0.y + w1*v1.y + w2*v2.y + w3*v3.y;
    acc[2] += w0*v0.z + w1*v1.z + w2*v2.z + w3*v3.z;
    acc[3] += w0*v0.w + w1*v1.w + w2*v2.w + w3*v3.w;
    den += (w0 + w1) + (w2 + w3);
  }
  for (; e < b1; ++e){
    int s = jb.ssrc[e];
    float w = __expf(lrelu_f(jb.als[s] + ad));
    float4 v = bf4_load(jb.hs + ((size_t)s<<5) + c4);
    acc[0] += w*v.x; acc[1] += w*v.y; acc[2] += w*v.z; acc[3] += w*v.w;
    den += w;
  }
  const float inv = 1.f/(den + 1e-16f);
  float4 b = *(const float4*)(jb.bias + c4);
  float4 o = make_float4(acc[0]*inv+b.x, acc[1]*inv+b.y,
                         acc[2]*inv+b.z, acc[3]*inv+b.w);
  *(float4*)(jb.out + (size_t)dst*32 + c4) = o;
}

// ---------------- host glue ----------------
extern "C" void kernel_launch(void* const* d_in, const int* in_sizes, int n_in,
                              void* d_out, int out_size, void* d_ws, size_t ws_size,
                              hipStream_t stream)
{
  (void)in_sizes; (void)n_in; (void)out_size; (void)ws_size;
  const float* x_user   = (const float*)d_in[0];
  const float* x_item   = (const float*)d_in[1];
  const int*   e_u2i    = (const int*)  d_in[2];
  const int*   e_i2u    = (const int*)  d_in[3];
  const float* p_user_w = (const float*)d_in[4];
  const float* p_user_b = (const float*)d_in[5];
  const float* p_item_w = (const float*)d_in[6];
  const float* p_item_b = (const float*)d_in[7];
  const float* l0_u2i_ws=(const float*)d_in[8];
  const float* l0_u2i_wd=(const float*)d_in[9];
  const float* l0_u2i_as=(const float*)d_in[10];
  const float* l0_u2i_ad=(const float*)d_in[11];
  const float* l0_u2i_b =(const float*)d_in[12];
  const float* l0_i2u_ws=(const float*)d_in[13];
  const float* l0_i2u_wd=(const float*)d_in[14];
  const float* l0_i2u_as=(const float*)d_in[15];
  const float* l0_i2u_ad=(const float*)d_in[16];
  const float* l0_i2u_b =(const float*)d_in[17];
  const float* l1_u2i_ws=(const float*)d_in[18];
  const float* l1_u2i_wd=(const float*)d_in[19];
  const float* l1_u2i_as=(const float*)d_in[20];
  const float* l1_u2i_ad=(const float*)d_in[21];
  const float* l1_u2i_b =(const float*)d_in[22];
  const float* l1_i2u_ws=(const float*)d_in[23];
  const float* l1_i2u_wd=(const float*)d_in[24];
  const float* l1_i2u_as=(const float*)d_in[25];
  const float* l1_i2u_ad=(const float*)d_in[26];
  const float* l1_i2u_b =(const float*)d_in[27];

  char* base = (char*)d_ws;
  size_t off = 0;
  auto alloc = [&](size_t bytes)->void*{
    void* p = base + off;
    off += (bytes + 255) & ~(size_t)255;
    return p;
  };
  int* offs_u2i = (int*)alloc((size_t)(NN+1)*sizeof(int));
  int* offs_i2u = (int*)alloc((size_t)(NN+1)*sizeof(int));
  int* ssrc_u2i = (int*)alloc((size_t)NE*sizeof(int));
  int* ssrc_i2u = (int*)alloc((size_t)NE*sizeof(int));
  int* ghist    = (int*)alloc((size_t)2*200*sizeof(int));
  int* gbase    = (int*)alloc((size_t)2*200*sizeof(int));
  int* gcur     = (int*)alloc((size_t)2*200*sizeof(int));
  unsigned short* coef0_u2i = (unsigned short*)alloc((size_t)NE*4*sizeof(unsigned short));
  unsigned short* coef0_i2u = (unsigned short*)alloc((size_t)NE*4*sizeof(unsigned short));
  unsigned short* hu = (unsigned short*)alloc((size_t)NN*64*sizeof(unsigned short));
  unsigned short* hi = (unsigned short*)alloc((size_t)NN*64*sizeof(unsigned short));
  unsigned short* agg_u2i = (unsigned short*)alloc((size_t)NN*256*sizeof(unsigned short));
  unsigned short* agg_i2u = (unsigned short*)alloc((size_t)NN*256*sizeof(unsigned short));
  float* den_u2i = (float*)alloc((size_t)NN*4*sizeof(float));
  float* den_i2u = (float*)alloc((size_t)NN*4*sizeof(float));
  unsigned short* hu1 = (unsigned short*)alloc((size_t)NN*256*sizeof(unsigned short));
  unsigned short* hi1 = (unsigned short*)alloc((size_t)NN*256*sizeof(unsigned short));
  unsigned short* hs1_u2i = (unsigned short*)alloc((size_t)NN*32*sizeof(unsigned short));
  unsigned short* hs1_i2u = (unsigned short*)alloc((size_t)NN*32*sizeof(unsigned short));
  float* als0_u2i = (float*)alloc((size_t)NN*4*sizeof(float));
  float* ald0_u2i = (float*)alloc((size_t)NN*4*sizeof(float));
  float* als0_i2u = (float*)alloc((size_t)NN*4*sizeof(float));
  float* ald0_i2u = (float*)alloc((size_t)NN*4*sizeof(float));
  float* als1_u2i = (float*)alloc((size_t)NN*sizeof(float));
  float* ald1_u2i = (float*)alloc((size_t)NN*sizeof(float));
  float* als1_i2u = (float*)alloc((size_t)NN*sizeof(float));
  float* ald1_i2u = (float*)alloc((size_t)NN*sizeof(float));
  float* cw0s_u2i = (float*)alloc(256*sizeof(float));
  float* cw0d_u2i = (float*)alloc(256*sizeof(float));
  float* cw0s_i2u = (float*)alloc(256*sizeof(float));
  float* cw0d_i2u = (float*)alloc(256*sizeof(float));
  // transposed bf16 hi/lo weight images
  unsigned short* wt_pu_h  = (unsigned short*)alloc((size_t)64*128*sizeof(unsigned short));
  unsigned short* wt_pu_l  = (unsigned short*)alloc((size_t)64*128*sizeof(unsigned short));
  unsigned short* wt_pi_h  = (unsigned short*)alloc((size_t)64*128*sizeof(unsigned short));
  unsigned short* wt_pi_l  = (unsigned short*)alloc((size_t)64*128*sizeof(unsigned short));
  unsigned short* wt_l0u_h = (unsigned short*)alloc((size_t)256*64*sizeof(unsigned short));
  unsigned short* wt_l0u_l = (unsigned short*)alloc((size_t)256*64*sizeof(unsigned short));
  unsigned short* wt_l0i_h = (unsigned short*)alloc((size_t)256*64*sizeof(unsigned short));
  unsigned short* wt_l0i_l = (unsigned short*)alloc((size_t)256*64*sizeof(unsigned short));
  unsigned short* wt_wcu_h = (unsigned short*)alloc((size_t)48*256*sizeof(unsigned short));
  unsigned short* wt_wcu_l = (unsigned short*)alloc((size_t)48*256*sizeof(unsigned short));
  unsigned short* wt_wci_h = (unsigned short*)alloc((size_t)48*256*sizeof(unsigned short));
  unsigned short* wt_wci_l = (unsigned short*)alloc((size_t)48*256*sizeof(unsigned short));
  // pairs scratch aliases hu1/hi1: consumed by part2 (hu1/hi1 now LDS-only)
  int2* pairs_u2i = (int2*)hu1;
  int2* pairs_i2u = pairs_u2i + NE;

  const int GM = (NN + 63)/64;

  // ---- bucket sort stage A ----
  hipMemsetAsync(ghist, 0, (size_t)2*200*sizeof(int), stream);
  ghist_kernel<<<dim3(256,2), 256, 0, stream>>>(e_u2i, e_i2u, ghist);
  gscan_kernel<<<1, 256, 0, stream>>>(ghist, gbase, gcur);
  part1_kernel<<<dim3((NE+TILE1-1)/TILE1,2), 256, 0, stream>>>(
      e_u2i, e_i2u, gcur, pairs_u2i, pairs_i2u);

  // ---- weight prep (transposes + Wc builds with inline dots + cw0 collapses) ----
  WcvArgs wa;
  wa.j[0] = {p_user_w,  nullptr, nullptr, nullptr, wt_pu_h,  wt_pu_l,  nullptr, 128, 64, 0};
  wa.j[1] = {p_item_w,  nullptr, nullptr, nullptr, wt_pi_h,  wt_pi_l,  nullptr, 128, 64, 0};
  wa.j[2] = {l0_u2i_ws, nullptr, nullptr, nullptr, wt_l0u_h, wt_l0u_l, nullptr, 64, 256, 0};
  wa.j[3] = {l0_i2u_ws, nullptr, nullptr, nullptr, wt_l0i_h, wt_l0i_l, nullptr, 64, 256, 0};
  // Wc_u2i: cols 0..31 = l1_u2i_ws; col32 = dot(l1_u2i_ws[k], l1_u2i_as);
  //         col33 = dot(l1_i2u_wd[k], l1_i2u_ad)
  wa.j[4] = {l1_u2i_ws, l1_u2i_as, l1_i2u_wd, l1_i2u_ad, wt_wcu_h, wt_wcu_l, nullptr, 256, 48, 1};
  wa.j[5] = {l1_i2u_ws, l1_i2u_as, l1_u2i_wd, l1_u2i_ad, wt_wci_h, wt_wci_l, nullptr, 256, 48, 1};
  // cw0 collapses (f32 out, [H=4][K=64], sequential-c sum = old collapse)
  wa.j[6] = {l0_u2i_ws, l0_u2i_as, nullptr, nullptr, nullptr, nullptr, cw0s_u2i, 64, 4, 2};
  wa.j[7] = {l0_u2i_wd, l0_u2i_ad, nullptr, nullptr, nullptr, nullptr, cw0d_u2i, 64, 4, 2};
  wa.j[8] = {l0_i2u_ws, l0_i2u_as, nullptr, nullptr, nullptr, nullptr, cw0s_i2u, 64, 4, 2};
  wa.j[9] = {l0_i2u_wd, l0_i2u_ad, nullptr, nullptr, nullptr, nullptr, cw0d_i2u, 64, 4, 2};
  wconv_kernel<<<dim3(64,10), 256, 0, stream>>>(wa);

  // ---- input projections (+bias +ELU) -> bf16, with fused layer-0 logits ----
  mgemm_kernel<4,128,true,true,false,false,true><<<dim3(GM,1,2), 256, 0, stream>>>(
      MgJob{x_user, wt_pu_h, wt_pu_l, p_user_b, hu, als0_u2i, ald0_i2u, cw0s_u2i, cw0d_i2u},
      MgJob{x_item, wt_pi_h, wt_pi_l, p_item_b, hi, als0_i2u, ald0_u2i, cw0s_i2u, cw0d_u2i},
      NN, 64);

  // ---- bucket sort stage B ----
  part2_kernel<<<dim3(GB,2), 256, 0, stream>>>(
      Part2Job{pairs_u2i, gbase,       als0_u2i, ald0_u2i, ssrc_u2i, offs_u2i, coef0_u2i},
      Part2Job{pairs_i2u, gbase + 200, als0_i2u, ald0_i2u, ssrc_i2u, offs_i2u, coef0_i2u});

  // ---- layer 0: pre-aggregate hu/hi rows (8 dst/wave, unroll-4 gathers) ----
  aggpre_kernel<<<dim3((NN+31)/32,2), 256, 0, stream>>>(
      AggPJob{offs_u2i, ssrc_u2i, hu, coef0_u2i, agg_u2i, den_u2i},
      AggPJob{offs_i2u, ssrc_i2u, hi, coef0_i2u, agg_i2u, den_i2u});

  // ---- fused layer-0 head GEMMs + layer-1 feature GEMM (interleaved per head) ----
  l0l1_kernel<<<dim3(GM,1,2), 256, 0, stream>>>(
      FsJob{agg_i2u, wt_l0i_h, wt_l0i_l, den_i2u, l0_i2u_b,
            wt_wcu_h, wt_wcu_l, hs1_u2i, als1_u2i, ald1_i2u},
      FsJob{agg_u2i, wt_l0u_h, wt_l0u_l, den_u2i, l0_u2i_b,
            wt_wci_h, wt_wci_l, hs1_i2u, als1_i2u, ald1_u2i},
      NN);

  // ---- layer 1: aggregate (+bias), shuffle-free 8 dst/wave ----
  float* hu2 = (float*)d_out;                  // first tuple element (users, i2u dst)
  float* hi2 = (float*)d_out + (size_t)NN*32;  // second tuple element (items, u2i dst)
  agg1_kernel<<<dim3((NN+31)/32,2), 256, 0, stream>>>(
      Agg1Job{offs_u2i, ssrc_u2i, hs1_u2i, als1_u2i, ald1_u2i, l1_u2i_b, hi2},
      Agg1Job{offs_i2u, ssrc_i2u, hs1_i2u, als1_i2u, ald1_i2u, l1_i2u_b, hu2});
}

// Round 15
// 332.106 us; speedup vs baseline: 1.1272x; 1.0164x over previous
//
#include <hip/hip_runtime.h>
#include <cstdint>
#include <cstddef>

#define NN 50000
#define NE 800000
#define GB 196        // coarse buckets = ceil(NN/256)
#define TILE1 4096    // edges per part1 block
#define CAP 8192      // max edges per bucket in part2 LDS (mean 4082)

typedef __attribute__((ext_vector_type(8))) short short8;
typedef __attribute__((ext_vector_type(4))) float floatx4;

__device__ __forceinline__ float lrelu_f(float x){ return x >= 0.f ? x : 0.2f*x; }
__device__ __forceinline__ float elu_f(float x){ return x > 0.f ? x : __expf(x) - 1.f; }

__device__ __forceinline__ unsigned short f2bf(float f){
  unsigned int u = __float_as_uint(f);
  u += 0x7FFFu + ((u >> 16) & 1u);
  return (unsigned short)(u >> 16);
}
__device__ __forceinline__ float bf2f(unsigned int us){
  return __uint_as_float(us << 16);
}
__device__ __forceinline__ float4 bf4_load(const unsigned short* p){
  uint2 q = *(const uint2*)p;
  return make_float4(bf2f(q.x & 0xffffu), bf2f(q.x >> 16),
                     bf2f(q.y & 0xffffu), bf2f(q.y >> 16));
}
__device__ __forceinline__ uint2 bf4_pack(float4 o){
  uint2 p;
  p.x = (unsigned)f2bf(o.x) | ((unsigned)f2bf(o.y) << 16);
  p.y = (unsigned)f2bf(o.z) | ((unsigned)f2bf(o.w) << 16);
  return p;
}
__device__ __forceinline__ void split_bf(float a, unsigned short& h, unsigned short& l){
  h = f2bf(a);
  l = f2bf(a - bf2f(h));
}

// v_dot2_f32_bf16: acc += a.bf16[0]*b.bf16[0] + a.bf16[1]*b.bf16[1]
__device__ __forceinline__ float dot2bf(float acc, unsigned a, unsigned b){
  asm("v_dot2_f32_bf16 %0, %1, %2, %0" : "+v"(acc) : "v"(a), "v"(b));
  return acc;
}

// process one edge PAIR (bf16 operands stay packed; sums stay within-lane)
__device__ __forceinline__ void agg_pair(float (&acc)[4][8], float (&den)[4],
                                         uint4 q0, uint4 q1, uint2 w0, uint2 w1){
  const unsigned ONE2 = 0x3F803F80u;  // packed bf16 (1.0, 1.0)
  unsigned wp[4];
  wp[0] = __builtin_amdgcn_perm(w1.x, w0.x, 0x05040100u);
  wp[1] = __builtin_amdgcn_perm(w1.x, w0.x, 0x07060302u);
  wp[2] = __builtin_amdgcn_perm(w1.y, w0.y, 0x05040100u);
  wp[3] = __builtin_amdgcn_perm(w1.y, w0.y, 0x07060302u);
  unsigned xp[8];
  xp[0] = __builtin_amdgcn_perm(q1.x, q0.x, 0x05040100u);
  xp[1] = __builtin_amdgcn_perm(q1.x, q0.x, 0x07060302u);
  xp[2] = __builtin_amdgcn_perm(q1.y, q0.y, 0x05040100u);
  xp[3] = __builtin_amdgcn_perm(q1.y, q0.y, 0x07060302u);
  xp[4] = __builtin_amdgcn_perm(q1.z, q0.z, 0x05040100u);
  xp[5] = __builtin_amdgcn_perm(q1.z, q0.z, 0x07060302u);
  xp[6] = __builtin_amdgcn_perm(q1.w, q0.w, 0x05040100u);
  xp[7] = __builtin_amdgcn_perm(q1.w, q0.w, 0x07060302u);
  #pragma unroll
  for (int h=0;h<4;h++){
    den[h] = dot2bf(den[h], wp[h], ONE2);
    #pragma unroll
    for (int c=0;c<8;c++) acc[h][c] = dot2bf(acc[h][c], wp[h], xp[c]);
  }
}

// ---------------- two-level bucket sort of edges by dst ----------------
__global__ __launch_bounds__(256) void ghist_kernel(const int* __restrict__ e0,
                                                    const int* __restrict__ e1,
                                                    int* __restrict__ ghist){
  const int ty = blockIdx.y;
  const int* e = ty ? e1 : e0;
  __shared__ int h[GB];
  for (int j=threadIdx.x; j<GB; j+=256) h[j]=0;
  __syncthreads();
  for (int i = blockIdx.x*256 + threadIdx.x; i < NE; i += 256*256)
    atomicAdd(&h[e[NE+i]>>8], 1);
  __syncthreads();
  for (int j=threadIdx.x; j<GB; j+=256) if (h[j]) atomicAdd(&ghist[ty*200+j], h[j]);
}

__global__ __launch_bounds__(256) void gscan_kernel(const int* __restrict__ ghist,
                                                    int* __restrict__ gbase,
                                                    int* __restrict__ gcur){
  __shared__ int wb[4];
  const int t = threadIdx.x, wv = t>>6, l = t&63;
  for (int ty=0; ty<2; ++ty){
    int v = (t < GB) ? ghist[ty*200+t] : 0;
    int sum = v;
    #pragma unroll
    for (int off=1; off<64; off<<=1){
      int x = __shfl_up(sum, off, 64);
      if (l >= off) sum += x;
    }
    if (l == 63) wb[wv] = sum;
    __syncthreads();
    int wbase = 0;
    #pragma unroll
    for (int w=0; w<4; ++w) if (w < wv) wbase += wb[w];
    int excl = wbase + sum - v;
    if (t <= GB) gbase[ty*200+t] = excl;
    if (t <  GB) gcur [ty*200+t] = excl;
    __syncthreads();
  }
}

// partition with LDS staging: global writes are contiguous per-bucket runs
__global__ __launch_bounds__(256) void part1_kernel(const int* __restrict__ e0,
                                                    const int* __restrict__ e1,
                                                    int* __restrict__ gcur,
                                                    int2* __restrict__ p0,
                                                    int2* __restrict__ p1){
  const int ty = blockIdx.y;
  const int* e = ty ? e1 : e0;
  int2* pairs = ty ? p1 : p0;
  __shared__ int cnt[256];
  __shared__ int lstart[256];
  __shared__ int lcur[256];
  __shared__ int curg[GB];
  __shared__ int lsrc[TILE1];
  __shared__ int ldst[TILE1];
  __shared__ int wb[4];
  const int t = threadIdx.x;
  cnt[t] = 0;
  __syncthreads();
  int dreg[16], sreg[16];
  const int base = blockIdx.x*TILE1;
  const int ntile = min(TILE1, NE - base);
  #pragma unroll
  for (int it=0; it<16; ++it){
    int i = base + it*256 + t;
    int d = -1, s = 0;
    if (i < NE){ d = e[NE+i]; s = e[i]; atomicAdd(&cnt[d>>8], 1); }
    dreg[it] = d; sreg[it] = s;
  }
  __syncthreads();
  int c = cnt[t], sum = c;
  #pragma unroll
  for (int off=1; off<64; off<<=1){
    int x = __shfl_up(sum, off, 64);
    if ((t&63) >= off) sum += x;
  }
  if ((t&63) == 63) wb[t>>6] = sum;
  __syncthreads();
  int wbase = 0;
  #pragma unroll
  for (int w=0; w<4; ++w) if (w < (t>>6)) wbase += wb[w];
  int excl = wbase + sum - c;
  lstart[t] = excl;
  lcur[t] = excl;
  if (t < GB && c > 0) curg[t] = atomicAdd(&gcur[ty*200+t], c);
  __syncthreads();
  #pragma unroll
  for (int it=0; it<16; ++it){
    int d = dreg[it];
    if (d >= 0){
      int pos = atomicAdd(&lcur[d>>8], 1);
      lsrc[pos] = sreg[it];
      ldst[pos] = d;
    }
  }
  __syncthreads();
  for (int i=t; i<ntile; i+=256){
    int d = ldst[i];
    int j = d>>8;
    pairs[curg[j] + (i - lstart[j])] = make_int2(lsrc[i], d);
  }
}

// per-bucket LDS bin by dst + CSR offsets + fused layer-0 softmax weights (bf16).
struct Part2Job {
  const int2* pairs; const int* gbase;
  const float* als; const float* ald;   // [NN,4]
  int* ssrc; int* offs; unsigned short* coef;  // coef: [E,4] bf16
};
__global__ __launch_bounds__(256) void part2_kernel(Part2Job j0, Part2Job j1){
  const Part2Job jb = blockIdx.y ? j1 : j0;
  const int b = blockIdx.x;
  const int t = threadIdx.x;
  __shared__ int lcnt[256];
  __shared__ int lcur[256];
  __shared__ int wb[4];
  __shared__ int sorted_src[CAP];
  __shared__ unsigned char sorted_dl[CAP];
  const int gb0 = jb.gbase[b], gb1 = jb.gbase[b+1];
  const int n = gb1 - gb0;
  lcnt[t] = 0;
  __syncthreads();
  for (int i=t; i<n; i+=256)
    atomicAdd(&lcnt[jb.pairs[gb0+i].y - (b<<8)], 1);
  __syncthreads();
  int c = lcnt[t], sum = c;
  #pragma unroll
  for (int off=1; off<64; off<<=1){
    int x = __shfl_up(sum, off, 64);
    if ((t&63) >= off) sum += x;
  }
  if ((t&63) == 63) wb[t>>6] = sum;
  __syncthreads();
  int wbase = 0;
  #pragma unroll
  for (int w=0; w<4; ++w) if (w < (t>>6)) wbase += wb[w];
  int excl = wbase + sum - c;
  lcur[t] = excl;
  int g = (b<<8) + t;
  if (g <= NN) jb.offs[g] = gb0 + excl;
  __syncthreads();
  for (int i=t; i<n; i+=256){
    int2 pr = jb.pairs[gb0+i];
    int dl = pr.y - (b<<8);
    int pos = atomicAdd(&lcur[dl], 1);
    sorted_src[pos] = pr.x;
    sorted_dl[pos] = (unsigned char)dl;
  }
  __syncthreads();
  const float4* als4 = (const float4*)jb.als;
  const float4* ald4 = (const float4*)jb.ald;
  for (int i=t; i<n; i+=256){
    int s  = sorted_src[i];
    int dl = sorted_dl[i];
    float4 a  = als4[s];
    float4 ad = ald4[(b<<8)+dl];
    // no max-shift: |alpha| small at this model scale; softmax shift-invariant.
    float4 w;
    w.x = __expf(lrelu_f(a.x+ad.x));
    w.y = __expf(lrelu_f(a.y+ad.y));
    w.z = __expf(lrelu_f(a.z+ad.z));
    w.w = __expf(lrelu_f(a.w+ad.w));
    ((uint2*)jb.coef)[gb0+i] = bf4_pack(w);
    jb.ssrc[gb0+i] = s;
  }
}

// ---------------- weight prep (collapse folded in) ----------------
// mode 0: plain transpose W[K][N] f32 -> bf16 hi/lo [N][K].
// mode 1: Wc build [256 x 48] -> transposed: n<32: W(=l1 Ws)[k*32+n];
//         n==32: dot32(W[k*32+.], a1(=l1 as));  n==33: dot32(a2(=other wd)[k*32+.], a3(=other ad)); else 0.
// mode 2: cw0 collapse -> FLOAT out: k=idx/N, h=idx%N (N=H=4, C=64):
//         fout[h*K+k] = dot64(W[k*256 + h*64 + .], a1[h*64 + .])   (sequential sum, matches old collapse)
struct WcvJob {
  const float* W; const float* a1; const float* a2; const float* a3;
  unsigned short* Wth; unsigned short* Wtl; float* fout;
  int K; int N; int mode;
};
struct WcvArgs { WcvJob j[10]; };
__global__ __launch_bounds__(256) void wconv_kernel(WcvArgs args){
  WcvJob jb = args.j[blockIdx.y];
  int idx = blockIdx.x*256 + threadIdx.x;
  if (idx >= jb.K * jb.N) return;
  if (jb.mode == 2){
    int k = idx / jb.N, h = idx % jb.N;
    const float* wr = jb.W + (size_t)k*256 + h*64;
    const float* ar = jb.a1 + h*64;
    float s = 0.f;
    for (int c=0;c<64;c++) s += wr[c]*ar[c];
    jb.fout[h*jb.K + k] = s;
    return;
  }
  int k = idx / jb.N, n = idx % jb.N;
  float val;
  if (jb.mode == 0) val = jb.W[(size_t)k*jb.N + n];
  else {
    if (n < 32)       val = jb.W[(size_t)k*32 + n];
    else if (n == 32){
      float s = 0.f;
      for (int c=0;c<32;c++) s += jb.W[(size_t)k*32 + c]*jb.a1[c];
      val = s;
    }
    else if (n == 33){
      float s = 0.f;
      for (int c=0;c<32;c++) s += jb.a2[(size_t)k*32 + c]*jb.a3[c];
      val = s;
    }
    else              val = 0.f;
  }
  unsigned short h, g;
  split_bf(val, h, g);
  jb.Wth[(size_t)n*jb.K + k] = h;
  jb.Wtl[(size_t)n*jb.K + k] = g;
}

// ---------------- MFMA GEMM (proj): C = act(A[M,K] @ W[K,N] (+bias)) ----------------
// Two-phase LDS-staged structure (round-9 proven).
struct MgJob {
  const void* A;                     // f32 [M,KK] if !BF16A else bf16 [M,KK]
  const unsigned short* Wth;         // [N][KK] bf16 hi (transposed)
  const unsigned short* Wtl;         // [N][KK] bf16 lo
  const float* bias;
  void* C; float* outA; float* outB;
  const float* cwS; const float* cwD;
};
template<int NT, int KK, bool ELU, bool BF16OUT, bool BF16A, bool LG, bool LOGIT>
__global__ __launch_bounds__(256) void mgemm_kernel(MgJob j0, MgJob j1,
                                                    int M, int N)
{
  const MgJob jb = blockIdx.z ? j1 : j0;
  constexpr int TN = NT*16;
  __shared__ __align__(16) unsigned short Ah[64*72];
  __shared__ __align__(16) unsigned short Al[BF16A ? 8 : 64*72];
  __shared__ __align__(16) unsigned short Bh[TN*72];
  __shared__ __align__(16) unsigned short Bl[TN*72];
  __shared__ float CwS[LOGIT ? 256 : 1];
  __shared__ float CwD[LOGIT ? 256 : 1];
  const int t = threadIdx.x;
  const int m0 = blockIdx.x*64;
  const int n0 = blockIdx.y*TN;
  const int wv = t>>6, l = t&63;
  const int lr = l&15, lq = l>>4;
  if constexpr (LOGIT){ CwS[t] = jb.cwS[t]; CwD[t] = jb.cwD[t]; }
  floatx4 acc[NT];
  #pragma unroll
  for (int i=0;i<NT;i++) acc[i] = (floatx4){0.f,0.f,0.f,0.f};

  #pragma unroll
  for (int kt=0; kt<KK; kt+=64){
    if constexpr (BF16A){
      const unsigned short* A = (const unsigned short*)jb.A;
      #pragma unroll
      for (int i=0;i<2;i++){
        int li = t + i*256;
        int r = li >> 3, c8 = (li & 7)*8;
        short8 v = {0,0,0,0,0,0,0,0};
        if (m0 + r < M) v = *(const short8*)(A + (size_t)(m0+r)*KK + kt + c8);
        *(short8*)&Ah[r*72 + c8] = v;
      }
    } else {
      const float* A = (const float*)jb.A;
      #pragma unroll
      for (int i=0;i<4;i++){
        int li = t + i*256;
        int r = li >> 4, c4 = (li & 15)*4;
        float4 v = make_float4(0.f,0.f,0.f,0.f);
        if (m0 + r < M) v = *(const float4*)(A + (size_t)(m0+r)*KK + kt + c4);
        unsigned short h0,h1,h2,h3,g0,g1,g2,g3;
        split_bf(v.x,h0,g0); split_bf(v.y,h1,g1);
        split_bf(v.z,h2,g2); split_bf(v.w,h3,g3);
        uint2 ph = { (unsigned)h0 | ((unsigned)h1<<16), (unsigned)h2 | ((unsigned)h3<<16) };
        uint2 pl = { (unsigned)g0 | ((unsigned)g1<<16), (unsigned)g2 | ((unsigned)g3<<16) };
        *(uint2*)&Ah[r*72 + c4] = ph;
        *(uint2*)&Al[r*72 + c4] = pl;
      }
    }
    // B-stage: pure copy of preconverted bf16 hi/lo (16B chunks).
    for (int c = t; c < TN*8; c += 256){
      int n  = c >> 3;
      int k8 = (c & 7) * 8;
      *(short8*)&Bh[n*72 + k8] =
          *(const short8*)(jb.Wth + (size_t)(n0 + n)*KK + kt + k8);
      *(short8*)&Bl[n*72 + k8] =
          *(const short8*)(jb.Wtl + (size_t)(n0 + n)*KK + kt + k8);
    }
    __syncthreads();
    #pragma unroll
    for (int ks=0; ks<2; ks++){
      const int koff = ks*32 + lq*8;
      short8 a_h = *(const short8*)&Ah[(wv*16+lr)*72 + koff];
      short8 a_l;
      if constexpr (!BF16A) a_l = *(const short8*)&Al[(wv*16+lr)*72 + koff];
      #pragma unroll
      for (int nt=0; nt<NT; nt++){
        short8 b_h = *(const short8*)&Bh[(nt*16+lr)*72 + koff];
        short8 b_l = *(const short8*)&Bl[(nt*16+lr)*72 + koff];
        acc[nt] = __builtin_amdgcn_mfma_f32_16x16x32_bf16(a_h, b_h, acc[nt], 0,0,0);
        acc[nt] = __builtin_amdgcn_mfma_f32_16x16x32_bf16(a_h, b_l, acc[nt], 0,0,0);
        if constexpr (!BF16A)
          acc[nt] = __builtin_amdgcn_mfma_f32_16x16x32_bf16(a_l, b_h, acc[nt], 0,0,0);
      }
    }
    __syncthreads();
  }
  float ls[LOGIT ? 4 : 1][LOGIT ? 4 : 1];   // [r][h]
  float ld_[LOGIT ? 4 : 1][LOGIT ? 4 : 1];
  if constexpr (LOGIT){
    #pragma unroll
    for (int r=0;r<4;r++)
      #pragma unroll
      for (int h=0;h<4;h++){ ls[r][h]=0.f; ld_[r][h]=0.f; }
  }
  #pragma unroll
  for (int nt=0; nt<NT; nt++){
    int n = n0 + nt*16 + lr;
    float bv = jb.bias ? jb.bias[n] : 0.f;
    #pragma unroll
    for (int r=0;r<4;r++){
      int m = m0 + wv*16 + lq*4 + r;
      if (m < M){
        float o = acc[nt][r] + bv;
        if (ELU) o = elu_f(o);
        if constexpr (LG){
          if (n < 32)       ((unsigned short*)jb.C)[(size_t)m*32 + n] = f2bf(o);
          else if (n == 32) jb.outA[m] = o;
          else if (n == 33) jb.outB[m] = o;
        } else {
          if (BF16OUT) ((unsigned short*)jb.C)[(size_t)m*N + n] = f2bf(o);
          else         ((float*)jb.C)[(size_t)m*N + n] = o;
        }
        if constexpr (LOGIT){
          #pragma unroll
          for (int h=0;h<4;h++){
            ls[r][h]  = fmaf(o, CwS[h*64 + n], ls[r][h]);
            ld_[r][h] = fmaf(o, CwD[h*64 + n], ld_[r][h]);
          }
        }
      }
    }
  }
  if constexpr (LOGIT){
    // reduce over the 16 lr-lanes (channels), then lane lr==0 writes 4 rows x 4 heads
    #pragma unroll
    for (int r=0;r<4;r++)
      #pragma unroll
      for (int h=0;h<4;h++){
        float a = ls[r][h], d = ld_[r][h];
        #pragma unroll
        for (int off=1; off<16; off<<=1){
          a += __shfl_xor(a, off, 64);
          d += __shfl_xor(d, off, 64);
        }
        ls[r][h]=a; ld_[r][h]=d;
      }
    if (lr == 0){
      #pragma unroll
      for (int r=0;r<4;r++){
        int m = m0 + wv*16 + lq*4 + r;
        if (m < M){
          #pragma unroll
          for (int h=0;h<4;h++){
            jb.outA[(size_t)m*4 + h] = ls[r][h];
            jb.outB[(size_t)m*4 + h] = ld_[r][h];
          }
        }
      }
    }
  }
}

// ---------------- fused layer-0 head GEMMs + layer-1 feature GEMM ----------------
// Interleaved per-head schedule (round-13 proven, 36.9KB LDS, scalar H1 stores
// — round-14's shfl-packed variant regressed: conflicts were NOT from these
// stores, and the shuffles added pure VALU cost).
struct FsJob {
  const unsigned short* A;            // agg bf16 [M,256]
  const unsigned short* W0h;          // [256][64] l0 Ws transposed hi
  const unsigned short* W0l;          //             lo
  const float* den;                   // [M,4]
  const float* b0;                    // [256] l0 bias
  const unsigned short* Wch;          // [48][256] Wc transposed hi
  const unsigned short* Wcl;          //             lo
  unsigned short* hs1;                // bf16 [M,32]
  float* outA; float* outB;           // layer-1 logits [M]
};
__global__ __launch_bounds__(256) void l0l1_kernel(FsJob j0, FsJob j1, int M){
  const FsJob jb = blockIdx.z ? j1 : j0;
  __shared__ __align__(16) unsigned short H1[64*72];    // current head's hi1 slice
  __shared__ __align__(16) unsigned short Sa[64*72];
  __shared__ __align__(16) unsigned short Sbh[64*72];
  __shared__ __align__(16) unsigned short Sbl[64*72];
  const int t = threadIdx.x;
  const int m0 = blockIdx.x*64;
  const int wv = t>>6, l = t&63;
  const int lr = l&15, lq = l>>4;
  floatx4 acc2[3];
  #pragma unroll
  for (int i=0;i<3;i++) acc2[i] = (floatx4){0.f,0.f,0.f,0.f};

  for (int h=0; h<4; ++h){
    // stage A head slice + W0 head slice
    #pragma unroll
    for (int i=0;i<2;i++){
      int li = t + i*256;
      int r = li >> 3, c8 = (li & 7)*8;
      short8 v = {0,0,0,0,0,0,0,0};
      if (m0 + r < M) v = *(const short8*)(jb.A + (size_t)(m0+r)*256 + h*64 + c8);
      *(short8*)&Sa[r*72 + c8] = v;
    }
    #pragma unroll
    for (int i=0;i<2;i++){
      int c  = t + i*256;
      int n  = c >> 3;
      int k8 = (c & 7) * 8;
      *(short8*)&Sbh[n*72 + k8] =
          *(const short8*)(jb.W0h + (size_t)(h*64 + n)*64 + k8);
      *(short8*)&Sbl[n*72 + k8] =
          *(const short8*)(jb.W0l + (size_t)(h*64 + n)*64 + k8);
    }
    __syncthreads();
    // head GEMM
    floatx4 acc[4];
    #pragma unroll
    for (int i=0;i<4;i++) acc[i] = (floatx4){0.f,0.f,0.f,0.f};
    #pragma unroll
    for (int ks=0; ks<2; ks++){
      const int koff = ks*32 + lq*8;
      short8 a_h = *(const short8*)&Sa[(wv*16+lr)*72 + koff];
      #pragma unroll
      for (int nt=0; nt<4; nt++){
        short8 b_h = *(const short8*)&Sbh[(nt*16+lr)*72 + koff];
        short8 b_l = *(const short8*)&Sbl[(nt*16+lr)*72 + koff];
        acc[nt] = __builtin_amdgcn_mfma_f32_16x16x32_bf16(a_h, b_h, acc[nt], 0,0,0);
        acc[nt] = __builtin_amdgcn_mfma_f32_16x16x32_bf16(a_h, b_l, acc[nt], 0,0,0);
      }
    }
    float inv[4];
    #pragma unroll
    for (int r=0;r<4;r++){
      int m = m0 + wv*16 + lq*4 + r;
      inv[r] = (m < M) ? 1.f/(jb.den[(size_t)m*4 + h] + 1e-16f) : 0.f;
    }
    #pragma unroll
    for (int nt=0; nt<4; nt++){
      int col = nt*16 + lr;
      float bv = jb.b0[h*64 + col];
      #pragma unroll
      for (int r=0;r<4;r++){
        int mrow = wv*16 + lq*4 + r;
        H1[mrow*72 + col] = f2bf(elu_f(acc[nt][r]*inv[r] + bv));
      }
    }
    __syncthreads();   // H1 written; W0 reads complete -> Sb reusable
    // stage Wc K-slice kt=h
    for (int c = t; c < 48*8; c += 256){
      int n  = c >> 3;
      int k8 = (c & 7) * 8;
      *(short8*)&Sbh[n*72 + k8] =
          *(const short8*)(jb.Wch + (size_t)n*256 + h*64 + k8);
      *(short8*)&Sbl[n*72 + k8] =
          *(const short8*)(jb.Wcl + (size_t)n*256 + h*64 + k8);
    }
    __syncthreads();
    // accumulate layer-1 K-slice
    #pragma unroll
    for (int ks=0; ks<2; ks++){
      const int koff = ks*32 + lq*8;
      short8 a_h = *(const short8*)&H1[(wv*16+lr)*72 + koff];
      #pragma unroll
      for (int nt=0; nt<3; nt++){
        short8 b_h = *(const short8*)&Sbh[(nt*16+lr)*72 + koff];
        short8 b_l = *(const short8*)&Sbl[(nt*16+lr)*72 + koff];
        acc2[nt] = __builtin_amdgcn_mfma_f32_16x16x32_bf16(a_h, b_h, acc2[nt], 0,0,0);
        acc2[nt] = __builtin_amdgcn_mfma_f32_16x16x32_bf16(a_h, b_l, acc2[nt], 0,0,0);
      }
    }
    __syncthreads();   // H1/Sb reads complete -> reusable next head
  }
  // epilogue: cols 0..31 -> hs1 bf16, col 32 -> outA, col 33 -> outB
  #pragma unroll
  for (int nt=0; nt<3; nt++){
    int n = nt*16 + lr;
    #pragma unroll
    for (int r=0;r<4;r++){
      int m = m0 + wv*16 + lq*4 + r;
      if (m < M){
        float o = acc2[nt][r];
        if (n < 32)       jb.hs1[(size_t)m*32 + n] = f2bf(o);
        else if (n == 32) jb.outA[m] = o;
        else if (n == 33) jb.outB[m] = o;
      }
    }
  }
}

// ---------------- layer-0 pre-aggregation over hu/hi rows ----------------
// 8 dsts per wave, 8 lanes per dst, 8 channels per lane: edge-sum is fully
// within-lane => no cross-lane reduction epilogue. Unroll-4 edge loop: 4
// x-row gathers in flight per iteration (gather-latency hiding).
struct AggPJob {
  const int* offs; const int* ssrc;
  const unsigned short* x;     // bf16 [NN,64]
  const unsigned short* coef;  // bf16 [E,4]
  unsigned short* agg;         // bf16 [NN,256]
  float* den;                  // fp32 [NN,4]
};
__global__ __launch_bounds__(256) void aggpre_kernel(AggPJob ja, AggPJob jbb){
  const AggPJob jb = blockIdx.y ? jbb : ja;
  const int tid = threadIdx.x;
  const int lane = tid & 63, wid = tid >> 6;
  const int grp = lane >> 3;       // dst group within wave (0..7)
  const int cl  = lane & 7;        // channel lane within group
  const int c8  = cl * 8;          // channel base (8 bf16 = 16B per lane)
  const int dst = blockIdx.x*32 + wid*8 + grp;
  if (dst >= NN) return;
  const int b0 = jb.offs[dst], b1 = jb.offs[dst+1];
  float acc[4][8];
  float den[4] = {0.f,0.f,0.f,0.f};
  #pragma unroll
  for (int h=0;h<4;h++)
    #pragma unroll
    for (int c=0;c<8;c++) acc[h][c]=0.f;
  int e = b0;
  // unroll-4: batch 4 independent x gathers + coef loads per iteration
  for (; e+3 < b1; e += 4){
    int s0 = jb.ssrc[e];
    int s1 = jb.ssrc[e+1];
    int s2 = jb.ssrc[e+2];
    int s3 = jb.ssrc[e+3];
    uint4 q0 = *(const uint4*)(jb.x + ((size_t)s0<<6) + c8);
    uint4 q1 = *(const uint4*)(jb.x + ((size_t)s1<<6) + c8);
    uint4 q2 = *(const uint4*)(jb.x + ((size_t)s2<<6) + c8);
    uint4 q3 = *(const uint4*)(jb.x + ((size_t)s3<<6) + c8);
    uint2 w0 = *(const uint2*)(jb.coef + (size_t)e*4);
    uint2 w1 = *(const uint2*)(jb.coef + (size_t)(e+1)*4);
    uint2 w2 = *(const uint2*)(jb.coef + (size_t)(e+2)*4);
    uint2 w3 = *(const uint2*)(jb.coef + (size_t)(e+3)*4);
    agg_pair(acc, den, q0, q1, w0, w1);
    agg_pair(acc, den, q2, q3, w2, w3);
  }
  if (e+1 < b1){
    int s0 = jb.ssrc[e];
    int s1 = jb.ssrc[e+1];
    uint4 q0 = *(const uint4*)(jb.x + ((size_t)s0<<6) + c8);
    uint4 q1 = *(const uint4*)(jb.x + ((size_t)s1<<6) + c8);
    uint2 w0 = *(const uint2*)(jb.coef + (size_t)e*4);
    uint2 w1 = *(const uint2*)(jb.coef + (size_t)(e+1)*4);
    agg_pair(acc, den, q0, q1, w0, w1);
    e += 2;
  }
  if (e < b1){  // odd-degree tail: single edge, scalar path
    int s = jb.ssrc[e];
    uint4 q = *(const uint4*)(jb.x + ((size_t)s<<6) + c8);
    uint2 w = *(const uint2*)(jb.coef + (size_t)e*4);
    float wf[4] = { bf2f(w.x & 0xffffu), bf2f(w.x >> 16),
                    bf2f(w.y & 0xffffu), bf2f(w.y >> 16) };
    float xf[8] = { bf2f(q.x & 0xffffu), bf2f(q.x >> 16),
                    bf2f(q.y & 0xffffu), bf2f(q.y >> 16),
                    bf2f(q.z & 0xffffu), bf2f(q.z >> 16),
                    bf2f(q.w & 0xffffu), bf2f(q.w >> 16) };
    #pragma unroll
    for (int h=0;h<4;h++){
      den[h] += wf[h];
      #pragma unroll
      for (int c=0;c<8;c++) acc[h][c] += wf[h]*xf[c];
    }
  }
  // epilogue: pack + store only (no shuffles)
  #pragma unroll
  for (int h=0;h<4;h++){
    uint2 plo = bf4_pack(make_float4(acc[h][0],acc[h][1],acc[h][2],acc[h][3]));
    uint2 phi = bf4_pack(make_float4(acc[h][4],acc[h][5],acc[h][6],acc[h][7]));
    uint4 pk = { plo.x, plo.y, phi.x, phi.y };
    *(uint4*)(jb.agg + (size_t)dst*256 + h*64 + c8) = pk;
  }
  if (cl == 0)
    *(float4*)(jb.den + (size_t)dst*4) = make_float4(den[0],den[1],den[2],den[3]);
}

// ---------------- layer-1 aggregation (aggpre-style: 8 dst/wave, shuffle-free) ----
struct Agg1Job {
  const int* offs; const int* ssrc;
  const unsigned short* hs;   // bf16 [NN,32]
  const float* als; const float* ald;  // layer-1 logits
  const float* bias; float* out;
};
__global__ __launch_bounds__(256) void agg1_kernel(Agg1Job ja, Agg1Job jbb){
  const Agg1Job jb = blockIdx.y ? jbb : ja;
  const int tid = threadIdx.x;
  const int lane = tid & 63, wid = tid >> 6;
  const int grp = lane >> 3;       // dst group within wave (0..7)
  const int cl  = lane & 7;        // col lane within group
  const int c4  = cl * 4;          // col base (4 f32 outputs per lane)
  const int dst = blockIdx.x*32 + wid*8 + grp;
  if (dst >= NN) return;
  const int b0 = jb.offs[dst], b1 = jb.offs[dst+1];
  const float ad = jb.ald[dst];
  float acc[4] = {0.f,0.f,0.f,0.f};
  float den = 0.f;
  int e = b0;
  for (; e+3 < b1; e += 4){
    int s0 = jb.ssrc[e];
    int s1 = jb.ssrc[e+1];
    int s2 = jb.ssrc[e+2];
    int s3 = jb.ssrc[e+3];
    float a0 = jb.als[s0];
    float a1 = jb.als[s1];
    float a2 = jb.als[s2];
    float a3 = jb.als[s3];
    float4 v0 = bf4_load(jb.hs + ((size_t)s0<<5) + c4);
    float4 v1 = bf4_load(jb.hs + ((size_t)s1<<5) + c4);
    float4 v2 = bf4_load(jb.hs + ((size_t)s2<<5) + c4);
    float4 v3 = bf4_load(jb.hs + ((size_t)s3<<5) + c4);
    float w0 = __expf(lrelu_f(a0 + ad));
    float w1 = __expf(lrelu_f(a1 + ad));
    float w2 = __expf(lrelu_f(a2 + ad));
    float w3 = __expf(lrelu_f(a3 + ad));
    acc[0] += w0*v0.x + w1*v1.x + w2*v2.x + w3*v3.x;
    acc[1] += w0*v0.y + w1*v1.y + w2*v2.y + w3*v3.y;
    acc[2] += w0*v0.z + w1*v1.z + w2*v2.z + w3*v3.z;
    acc[3] += w0*v0.w + w1*v1.w + w2*v2.w + w3*v3.w;
    den += (w0 + w1) + (w2 + w3);
  }
  for (; e < b1; ++e){
    int s = jb.ssrc[e];
    float w = __expf(lrelu_f(jb.als[s] + ad));
    float4 v = bf4_load(jb.hs + ((size_t)s<<5) + c4);
    acc[0] += w*v.x; acc[1] += w*v.y; acc[2] += w*v.z; acc[3] += w*v.w;
    den += w;
  }
  const float inv = 1.f/(den + 1e-16f);
  float4 b = *(const float4*)(jb.bias + c4);
  float4 o = make_float4(acc[0]*inv+b.x, acc[1]*inv+b.y,
                         acc[2]*inv+b.z, acc[3]*inv+b.w);
  *(float4*)(jb.out + (size_t)dst*32 + c4) = o;
}

// ---------------- host glue ----------------
extern "C" void kernel_launch(void* const* d_in, const int* in_sizes, int n_in,
                              void* d_out, int out_size, void* d_ws, size_t ws_size,
                              hipStream_t stream)
{
  (void)in_sizes; (void)n_in; (void)out_size; (void)ws_size;
  const float* x_user   = (const float*)d_in[0];
  const float* x_item   = (const float*)d_in[1];
  const int*   e_u2i    = (const int*)  d_in[2];
  const int*   e_i2u    = (const int*)  d_in[3];
  const float* p_user_w = (const float*)d_in[4];
  const float* p_user_b = (const float*)d_in[5];
  const float* p_item_w = (const float*)d_in[6];
  const float* p_item_b = (const float*)d_in[7];
  const float* l0_u2i_ws=(const float*)d_in[8];
  const float* l0_u2i_wd=(const float*)d_in[9];
  const float* l0_u2i_as=(const float*)d_in[10];
  const float* l0_u2i_ad=(const float*)d_in[11];
  const float* l0_u2i_b =(const float*)d_in[12];
  const float* l0_i2u_ws=(const float*)d_in[13];
  const float* l0_i2u_wd=(const float*)d_in[14];
  const float* l0_i2u_as=(const float*)d_in[15];
  const float* l0_i2u_ad=(const float*)d_in[16];
  const float* l0_i2u_b =(const float*)d_in[17];
  const float* l1_u2i_ws=(const float*)d_in[18];
  const float* l1_u2i_wd=(const float*)d_in[19];
  const float* l1_u2i_as=(const float*)d_in[20];
  const float* l1_u2i_ad=(const float*)d_in[21];
  const float* l1_u2i_b =(const float*)d_in[22];
  const float* l1_i2u_ws=(const float*)d_in[23];
  const float* l1_i2u_wd=(const float*)d_in[24];
  const float* l1_i2u_as=(const float*)d_in[25];
  const float* l1_i2u_ad=(const float*)d_in[26];
  const float* l1_i2u_b =(const float*)d_in[27];

  char* base = (char*)d_ws;
  size_t off = 0;
  auto alloc = [&](size_t bytes)->void*{
    void* p = base + off;
    off += (bytes + 255) & ~(size_t)255;
    return p;
  };
  int* offs_u2i = (int*)alloc((size_t)(NN+1)*sizeof(int));
  int* offs_i2u = (int*)alloc((size_t)(NN+1)*sizeof(int));
  int* ssrc_u2i = (int*)alloc((size_t)NE*sizeof(int));
  int* ssrc_i2u = (int*)alloc((size_t)NE*sizeof(int));
  int* ghist    = (int*)alloc((size_t)2*200*sizeof(int));
  int* gbase    = (int*)alloc((size_t)2*200*sizeof(int));
  int* gcur     = (int*)alloc((size_t)2*200*sizeof(int));
  unsigned short* coef0_u2i = (unsigned short*)alloc((size_t)NE*4*sizeof(unsigned short));
  unsigned short* coef0_i2u = (unsigned short*)alloc((size_t)NE*4*sizeof(unsigned short));
  unsigned short* hu = (unsigned short*)alloc((size_t)NN*64*sizeof(unsigned short));
  unsigned short* hi = (unsigned short*)alloc((size_t)NN*64*sizeof(unsigned short));
  unsigned short* agg_u2i = (unsigned short*)alloc((size_t)NN*256*sizeof(unsigned short));
  unsigned short* agg_i2u = (unsigned short*)alloc((size_t)NN*256*sizeof(unsigned short));
  float* den_u2i = (float*)alloc((size_t)NN*4*sizeof(float));
  float* den_i2u = (float*)alloc((size_t)NN*4*sizeof(float));
  unsigned short* hu1 = (unsigned short*)alloc((size_t)NN*256*sizeof(unsigned short));
  unsigned short* hi1 = (unsigned short*)alloc((size_t)NN*256*sizeof(unsigned short));
  unsigned short* hs1_u2i = (unsigned short*)alloc((size_t)NN*32*sizeof(unsigned short));
  unsigned short* hs1_i2u = (unsigned short*)alloc((size_t)NN*32*sizeof(unsigned short));
  float* als0_u2i = (float*)alloc((size_t)NN*4*sizeof(float));
  float* ald0_u2i = (float*)alloc((size_t)NN*4*sizeof(float));
  float* als0_i2u = (float*)alloc((size_t)NN*4*sizeof(float));
  float* ald0_i2u = (float*)alloc((size_t)NN*4*sizeof(float));
  float* als1_u2i = (float*)alloc((size_t)NN*sizeof(float));
  float* ald1_u2i = (float*)alloc((size_t)NN*sizeof(float));
  float* als1_i2u = (float*)alloc((size_t)NN*sizeof(float));
  float* ald1_i2u = (float*)alloc((size_t)NN*sizeof(float));
  float* cw0s_u2i = (float*)alloc(256*sizeof(float));
  float* cw0d_u2i = (float*)alloc(256*sizeof(float));
  float* cw0s_i2u = (float*)alloc(256*sizeof(float));
  float* cw0d_i2u = (float*)alloc(256*sizeof(float));
  // transposed bf16 hi/lo weight images
  unsigned short* wt_pu_h  = (unsigned short*)alloc((size_t)64*128*sizeof(unsigned short));
  unsigned short* wt_pu_l  = (unsigned short*)alloc((size_t)64*128*sizeof(unsigned short));
  unsigned short* wt_pi_h  = (unsigned short*)alloc((size_t)64*128*sizeof(unsigned short));
  unsigned short* wt_pi_l  = (unsigned short*)alloc((size_t)64*128*sizeof(unsigned short));
  unsigned short* wt_l0u_h = (unsigned short*)alloc((size_t)256*64*sizeof(unsigned short));
  unsigned short* wt_l0u_l = (unsigned short*)alloc((size_t)256*64*sizeof(unsigned short));
  unsigned short* wt_l0i_h = (unsigned short*)alloc((size_t)256*64*sizeof(unsigned short));
  unsigned short* wt_l0i_l = (unsigned short*)alloc((size_t)256*64*sizeof(unsigned short));
  unsigned short* wt_wcu_h = (unsigned short*)alloc((size_t)48*256*sizeof(unsigned short));
  unsigned short* wt_wcu_l = (unsigned short*)alloc((size_t)48*256*sizeof(unsigned short));
  unsigned short* wt_wci_h = (unsigned short*)alloc((size_t)48*256*sizeof(unsigned short));
  unsigned short* wt_wci_l = (unsigned short*)alloc((size_t)48*256*sizeof(unsigned short));
  // pairs scratch aliases hu1/hi1: consumed by part2 (hu1/hi1 now LDS-only)
  int2* pairs_u2i = (int2*)hu1;
  int2* pairs_i2u = pairs_u2i + NE;

  const int GM = (NN + 63)/64;

  // ---- bucket sort stage A ----
  hipMemsetAsync(ghist, 0, (size_t)2*200*sizeof(int), stream);
  ghist_kernel<<<dim3(256,2), 256, 0, stream>>>(e_u2i, e_i2u, ghist);
  gscan_kernel<<<1, 256, 0, stream>>>(ghist, gbase, gcur);
  part1_kernel<<<dim3((NE+TILE1-1)/TILE1,2), 256, 0, stream>>>(
      e_u2i, e_i2u, gcur, pairs_u2i, pairs_i2u);

  // ---- weight prep (transposes + Wc builds with inline dots + cw0 collapses) ----
  WcvArgs wa;
  wa.j[0] = {p_user_w,  nullptr, nullptr, nullptr, wt_pu_h,  wt_pu_l,  nullptr, 128, 64, 0};
  wa.j[1] = {p_item_w,  nullptr, nullptr, nullptr, wt_pi_h,  wt_pi_l,  nullptr, 128, 64, 0};
  wa.j[2] = {l0_u2i_ws, nullptr, nullptr, nullptr, wt_l0u_h, wt_l0u_l, nullptr, 64, 256, 0};
  wa.j[3] = {l0_i2u_ws, nullptr, nullptr, nullptr, wt_l0i_h, wt_l0i_l, nullptr, 64, 256, 0};
  // Wc_u2i: cols 0..31 = l1_u2i_ws; col32 = dot(l1_u2i_ws[k], l1_u2i_as);
  //         col33 = dot(l1_i2u_wd[k], l1_i2u_ad)
  wa.j[4] = {l1_u2i_ws, l1_u2i_as, l1_i2u_wd, l1_i2u_ad, wt_wcu_h, wt_wcu_l, nullptr, 256, 48, 1};
  wa.j[5] = {l1_i2u_ws, l1_i2u_as, l1_u2i_wd, l1_u2i_ad, wt_wci_h, wt_wci_l, nullptr, 256, 48, 1};
  // cw0 collapses (f32 out, [H=4][K=64], sequential-c sum = old collapse)
  wa.j[6] = {l0_u2i_ws, l0_u2i_as, nullptr, nullptr, nullptr, nullptr, cw0s_u2i, 64, 4, 2};
  wa.j[7] = {l0_u2i_wd, l0_u2i_ad, nullptr, nullptr, nullptr, nullptr, cw0d_u2i, 64, 4, 2};
  wa.j[8] = {l0_i2u_ws, l0_i2u_as, nullptr, nullptr, nullptr, nullptr, cw0s_i2u, 64, 4, 2};
  wa.j[9] = {l0_i2u_wd, l0_i2u_ad, nullptr, nullptr, nullptr, nullptr, cw0d_i2u, 64, 4, 2};
  wconv_kernel<<<dim3(64,10), 256, 0, stream>>>(wa);

  // ---- input projections (+bias +ELU) -> bf16, with fused layer-0 logits ----
  mgemm_kernel<4,128,true,true,false,false,true><<<dim3(GM,1,2), 256, 0, stream>>>(
      MgJob{x_user, wt_pu_h, wt_pu_l, p_user_b, hu, als0_u2i, ald0_i2u, cw0s_u2i, cw0d_i2u},
      MgJob{x_item, wt_pi_h, wt_pi_l, p_item_b, hi, als0_i2u, ald0_u2i, cw0s_i2u, cw0d_u2i},
      NN, 64);

  // ---- bucket sort stage B ----
  part2_kernel<<<dim3(GB,2), 256, 0, stream>>>(
      Part2Job{pairs_u2i, gbase,       als0_u2i, ald0_u2i, ssrc_u2i, offs_u2i, coef0_u2i},
      Part2Job{pairs_i2u, gbase + 200, als0_i2u, ald0_i2u, ssrc_i2u, offs_i2u, coef0_i2u});

  // ---- layer 0: pre-aggregate hu/hi rows (8 dst/wave, unroll-4 gathers) ----
  aggpre_kernel<<<dim3((NN+31)/32,2), 256, 0, stream>>>(
      AggPJob{offs_u2i, ssrc_u2i, hu, coef0_u2i, agg_u2i, den_u2i},
      AggPJob{offs_i2u, ssrc_i2u, hi, coef0_i2u, agg_i2u, den_i2u});

  // ---- fused layer-0 head GEMMs + layer-1 feature GEMM (interleaved per head) ----
  l0l1_kernel<<<dim3(GM,1,2), 256, 0, stream>>>(
      FsJob{agg_i2u, wt_l0i_h, wt_l0i_l, den_i2u, l0_i2u_b,
            wt_wcu_h, wt_wcu_l, hs1_u2i, als1_u2i, ald1_i2u},
      FsJob{agg_u2i, wt_l0u_h, wt_l0u_l, den_u2i, l0_u2i_b,
            wt_wci_h, wt_wci_l, hs1_i2u, als1_i2u, ald1_u2i},
      NN);

  // ---- layer 1: aggregate (+bias), shuffle-free 8 dst/wave ----
  float* hu2 = (float*)d_out;                  // first tuple element (users, i2u dst)
  float* hi2 = (float*)d_out + (size_t)NN*32;  // second tuple element (items, u2i dst)
  agg1_kernel<<<dim3((NN+31)/32,2), 256, 0, stream>>>(
      Agg1Job{offs_u2i, ssrc_u2i, hs1_u2i, als1_u2i, ald1_u2i, l1_u2i_b, hi2},
      Agg1Job{offs_i2u, ssrc_i2u, hs1_i2u, als1_i2u, ald1_i2u, l1_i2u_b, hu2});
}

// Round 16
// 330.574 us; speedup vs baseline: 1.1324x; 1.0046x over previous
//
#include <hip/hip_runtime.h>
#include <cstdint>
#include <cstddef>

#define NN 50000
#define NE 800000
#define GB 196        // coarse buckets = ceil(NN/256)
#define TILE1 4096    // edges per part1 block
#define CAP 8192      // max edges per bucket in part2 LDS (mean 4082)

typedef __attribute__((ext_vector_type(8))) short short8;
typedef __attribute__((ext_vector_type(4))) float floatx4;

__device__ __forceinline__ float lrelu_f(float x){ return x >= 0.f ? x : 0.2f*x; }
__device__ __forceinline__ float elu_f(float x){ return x > 0.f ? x : __expf(x) - 1.f; }

__device__ __forceinline__ unsigned short f2bf(float f){
  unsigned int u = __float_as_uint(f);
  u += 0x7FFFu + ((u >> 16) & 1u);
  return (unsigned short)(u >> 16);
}
__device__ __forceinline__ float bf2f(unsigned int us){
  return __uint_as_float(us << 16);
}
__device__ __forceinline__ float4 bf4_load(const unsigned short* p){
  uint2 q = *(const uint2*)p;
  return make_float4(bf2f(q.x & 0xffffu), bf2f(q.x >> 16),
                     bf2f(q.y & 0xffffu), bf2f(q.y >> 16));
}
__device__ __forceinline__ uint2 bf4_pack(float4 o){
  uint2 p;
  p.x = (unsigned)f2bf(o.x) | ((unsigned)f2bf(o.y) << 16);
  p.y = (unsigned)f2bf(o.z) | ((unsigned)f2bf(o.w) << 16);
  return p;
}
__device__ __forceinline__ void split_bf(float a, unsigned short& h, unsigned short& l){
  h = f2bf(a);
  l = f2bf(a - bf2f(h));
}

// v_dot2_f32_bf16: acc += a.bf16[0]*b.bf16[0] + a.bf16[1]*b.bf16[1]
__device__ __forceinline__ float dot2bf(float acc, unsigned a, unsigned b){
  asm("v_dot2_f32_bf16 %0, %1, %2, %0" : "+v"(acc) : "v"(a), "v"(b));
  return acc;
}

// process one edge PAIR (bf16 operands stay packed; sums stay within-lane)
__device__ __forceinline__ void agg_pair(float (&acc)[4][8], float (&den)[4],
                                         uint4 q0, uint4 q1, uint2 w0, uint2 w1){
  const unsigned ONE2 = 0x3F803F80u;  // packed bf16 (1.0, 1.0)
  unsigned wp[4];
  wp[0] = __builtin_amdgcn_perm(w1.x, w0.x, 0x05040100u);
  wp[1] = __builtin_amdgcn_perm(w1.x, w0.x, 0x07060302u);
  wp[2] = __builtin_amdgcn_perm(w1.y, w0.y, 0x05040100u);
  wp[3] = __builtin_amdgcn_perm(w1.y, w0.y, 0x07060302u);
  unsigned xp[8];
  xp[0] = __builtin_amdgcn_perm(q1.x, q0.x, 0x05040100u);
  xp[1] = __builtin_amdgcn_perm(q1.x, q0.x, 0x07060302u);
  xp[2] = __builtin_amdgcn_perm(q1.y, q0.y, 0x05040100u);
  xp[3] = __builtin_amdgcn_perm(q1.y, q0.y, 0x07060302u);
  xp[4] = __builtin_amdgcn_perm(q1.z, q0.z, 0x05040100u);
  xp[5] = __builtin_amdgcn_perm(q1.z, q0.z, 0x07060302u);
  xp[6] = __builtin_amdgcn_perm(q1.w, q0.w, 0x05040100u);
  xp[7] = __builtin_amdgcn_perm(q1.w, q0.w, 0x07060302u);
  #pragma unroll
  for (int h=0;h<4;h++){
    den[h] = dot2bf(den[h], wp[h], ONE2);
    #pragma unroll
    for (int c=0;c<8;c++) acc[h][c] = dot2bf(acc[h][c], wp[h], xp[c]);
  }
}

// ---------------- two-level bucket sort of edges by dst ----------------
__global__ __launch_bounds__(256) void ghist_kernel(const int* __restrict__ e0,
                                                    const int* __restrict__ e1,
                                                    int* __restrict__ ghist){
  const int ty = blockIdx.y;
  const int* e = ty ? e1 : e0;
  __shared__ int h[GB];
  for (int j=threadIdx.x; j<GB; j+=256) h[j]=0;
  __syncthreads();
  for (int i = blockIdx.x*256 + threadIdx.x; i < NE; i += 256*256)
    atomicAdd(&h[e[NE+i]>>8], 1);
  __syncthreads();
  for (int j=threadIdx.x; j<GB; j+=256) if (h[j]) atomicAdd(&ghist[ty*200+j], h[j]);
}

__global__ __launch_bounds__(256) void gscan_kernel(const int* __restrict__ ghist,
                                                    int* __restrict__ gbase,
                                                    int* __restrict__ gcur){
  __shared__ int wb[4];
  const int t = threadIdx.x, wv = t>>6, l = t&63;
  for (int ty=0; ty<2; ++ty){
    int v = (t < GB) ? ghist[ty*200+t] : 0;
    int sum = v;
    #pragma unroll
    for (int off=1; off<64; off<<=1){
      int x = __shfl_up(sum, off, 64);
      if (l >= off) sum += x;
    }
    if (l == 63) wb[wv] = sum;
    __syncthreads();
    int wbase = 0;
    #pragma unroll
    for (int w=0; w<4; ++w) if (w < wv) wbase += wb[w];
    int excl = wbase + sum - v;
    if (t <= GB) gbase[ty*200+t] = excl;
    if (t <  GB) gcur [ty*200+t] = excl;
    __syncthreads();
  }
}

// partition with LDS staging: global writes are contiguous per-bucket runs
__global__ __launch_bounds__(256) void part1_kernel(const int* __restrict__ e0,
                                                    const int* __restrict__ e1,
                                                    int* __restrict__ gcur,
                                                    int2* __restrict__ p0,
                                                    int2* __restrict__ p1){
  const int ty = blockIdx.y;
  const int* e = ty ? e1 : e0;
  int2* pairs = ty ? p1 : p0;
  __shared__ int cnt[256];
  __shared__ int lstart[256];
  __shared__ int lcur[256];
  __shared__ int curg[GB];
  __shared__ int lsrc[TILE1];
  __shared__ int ldst[TILE1];
  __shared__ int wb[4];
  const int t = threadIdx.x;
  cnt[t] = 0;
  __syncthreads();
  int dreg[16], sreg[16];
  const int base = blockIdx.x*TILE1;
  const int ntile = min(TILE1, NE - base);
  #pragma unroll
  for (int it=0; it<16; ++it){
    int i = base + it*256 + t;
    int d = -1, s = 0;
    if (i < NE){ d = e[NE+i]; s = e[i]; atomicAdd(&cnt[d>>8], 1); }
    dreg[it] = d; sreg[it] = s;
  }
  __syncthreads();
  int c = cnt[t], sum = c;
  #pragma unroll
  for (int off=1; off<64; off<<=1){
    int x = __shfl_up(sum, off, 64);
    if ((t&63) >= off) sum += x;
  }
  if ((t&63) == 63) wb[t>>6] = sum;
  __syncthreads();
  int wbase = 0;
  #pragma unroll
  for (int w=0; w<4; ++w) if (w < (t>>6)) wbase += wb[w];
  int excl = wbase + sum - c;
  lstart[t] = excl;
  lcur[t] = excl;
  if (t < GB && c > 0) curg[t] = atomicAdd(&gcur[ty*200+t], c);
  __syncthreads();
  #pragma unroll
  for (int it=0; it<16; ++it){
    int d = dreg[it];
    if (d >= 0){
      int pos = atomicAdd(&lcur[d>>8], 1);
      lsrc[pos] = sreg[it];
      ldst[pos] = d;
    }
  }
  __syncthreads();
  for (int i=t; i<ntile; i+=256){
    int d = ldst[i];
    int j = d>>8;
    pairs[curg[j] + (i - lstart[j])] = make_int2(lsrc[i], d);
  }
}

// per-bucket LDS bin by dst + CSR offsets + fused layer-0 softmax weights (bf16).
struct Part2Job {
  const int2* pairs; const int* gbase;
  const float* als; const float* ald;   // [NN,4]
  int* ssrc; int* offs; unsigned short* coef;  // coef: [E,4] bf16
};
__global__ __launch_bounds__(256) void part2_kernel(Part2Job j0, Part2Job j1){
  const Part2Job jb = blockIdx.y ? j1 : j0;
  const int b = blockIdx.x;
  const int t = threadIdx.x;
  __shared__ int lcnt[256];
  __shared__ int lcur[256];
  __shared__ int wb[4];
  __shared__ int sorted_src[CAP];
  __shared__ unsigned char sorted_dl[CAP];
  const int gb0 = jb.gbase[b], gb1 = jb.gbase[b+1];
  const int n = gb1 - gb0;
  lcnt[t] = 0;
  __syncthreads();
  for (int i=t; i<n; i+=256)
    atomicAdd(&lcnt[jb.pairs[gb0+i].y - (b<<8)], 1);
  __syncthreads();
  int c = lcnt[t], sum = c;
  #pragma unroll
  for (int off=1; off<64; off<<=1){
    int x = __shfl_up(sum, off, 64);
    if ((t&63) >= off) sum += x;
  }
  if ((t&63) == 63) wb[t>>6] = sum;
  __syncthreads();
  int wbase = 0;
  #pragma unroll
  for (int w=0; w<4; ++w) if (w < (t>>6)) wbase += wb[w];
  int excl = wbase + sum - c;
  lcur[t] = excl;
  int g = (b<<8) + t;
  if (g <= NN) jb.offs[g] = gb0 + excl;
  __syncthreads();
  for (int i=t; i<n; i+=256){
    int2 pr = jb.pairs[gb0+i];
    int dl = pr.y - (b<<8);
    int pos = atomicAdd(&lcur[dl], 1);
    sorted_src[pos] = pr.x;
    sorted_dl[pos] = (unsigned char)dl;
  }
  __syncthreads();
  const float4* als4 = (const float4*)jb.als;
  const float4* ald4 = (const float4*)jb.ald;
  for (int i=t; i<n; i+=256){
    int s  = sorted_src[i];
    int dl = sorted_dl[i];
    float4 a  = als4[s];
    float4 ad = ald4[(b<<8)+dl];
    // no max-shift: |alpha| small at this model scale; softmax shift-invariant.
    float4 w;
    w.x = __expf(lrelu_f(a.x+ad.x));
    w.y = __expf(lrelu_f(a.y+ad.y));
    w.z = __expf(lrelu_f(a.z+ad.z));
    w.w = __expf(lrelu_f(a.w+ad.w));
    ((uint2*)jb.coef)[gb0+i] = bf4_pack(w);
    jb.ssrc[gb0+i] = s;
  }
}

// ---------------- weight prep (collapse folded in) ----------------
// mode 0: plain transpose W[K][N] f32 -> bf16 hi/lo [N][K].
// mode 1: Wc build [256 x 48] -> transposed: n<32: W(=l1 Ws)[k*32+n];
//         n==32: dot32(W[k*32+.], a1(=l1 as));  n==33: dot32(a2(=other wd)[k*32+.], a3(=other ad)); else 0.
// mode 2: cw0 collapse -> FLOAT out: k=idx/N, h=idx%N (N=H=4, C=64):
//         fout[h*K+k] = dot64(W[k*256 + h*64 + .], a1[h*64 + .])   (sequential sum, matches old collapse)
struct WcvJob {
  const float* W; const float* a1; const float* a2; const float* a3;
  unsigned short* Wth; unsigned short* Wtl; float* fout;
  int K; int N; int mode;
};
struct WcvArgs { WcvJob j[10]; };
__global__ __launch_bounds__(256) void wconv_kernel(WcvArgs args){
  WcvJob jb = args.j[blockIdx.y];
  int idx = blockIdx.x*256 + threadIdx.x;
  if (idx >= jb.K * jb.N) return;
  if (jb.mode == 2){
    int k = idx / jb.N, h = idx % jb.N;
    const float* wr = jb.W + (size_t)k*256 + h*64;
    const float* ar = jb.a1 + h*64;
    float s = 0.f;
    for (int c=0;c<64;c++) s += wr[c]*ar[c];
    jb.fout[h*jb.K + k] = s;
    return;
  }
  int k = idx / jb.N, n = idx % jb.N;
  float val;
  if (jb.mode == 0) val = jb.W[(size_t)k*jb.N + n];
  else {
    if (n < 32)       val = jb.W[(size_t)k*32 + n];
    else if (n == 32){
      float s = 0.f;
      for (int c=0;c<32;c++) s += jb.W[(size_t)k*32 + c]*jb.a1[c];
      val = s;
    }
    else if (n == 33){
      float s = 0.f;
      for (int c=0;c<32;c++) s += jb.a2[(size_t)k*32 + c]*jb.a3[c];
      val = s;
    }
    else              val = 0.f;
  }
  unsigned short h, g;
  split_bf(val, h, g);
  jb.Wth[(size_t)n*jb.K + k] = h;
  jb.Wtl[(size_t)n*jb.K + k] = g;
}

// ---------------- MFMA GEMM (proj): C = act(A[M,K] @ W[K,N] (+bias)) ----------------
// Two-phase LDS-staged structure (round-9 proven).
struct MgJob {
  const void* A;                     // f32 [M,KK] if !BF16A else bf16 [M,KK]
  const unsigned short* Wth;         // [N][KK] bf16 hi (transposed)
  const unsigned short* Wtl;         // [N][KK] bf16 lo
  const float* bias;
  void* C; float* outA; float* outB;
  const float* cwS; const float* cwD;
};
template<int NT, int KK, bool ELU, bool BF16OUT, bool BF16A, bool LG, bool LOGIT>
__global__ __launch_bounds__(256) void mgemm_kernel(MgJob j0, MgJob j1,
                                                    int M, int N)
{
  const MgJob jb = blockIdx.z ? j1 : j0;
  constexpr int TN = NT*16;
  __shared__ __align__(16) unsigned short Ah[64*72];
  __shared__ __align__(16) unsigned short Al[BF16A ? 8 : 64*72];
  __shared__ __align__(16) unsigned short Bh[TN*72];
  __shared__ __align__(16) unsigned short Bl[TN*72];
  __shared__ float CwS[LOGIT ? 256 : 1];
  __shared__ float CwD[LOGIT ? 256 : 1];
  const int t = threadIdx.x;
  const int m0 = blockIdx.x*64;
  const int n0 = blockIdx.y*TN;
  const int wv = t>>6, l = t&63;
  const int lr = l&15, lq = l>>4;
  if constexpr (LOGIT){ CwS[t] = jb.cwS[t]; CwD[t] = jb.cwD[t]; }
  floatx4 acc[NT];
  #pragma unroll
  for (int i=0;i<NT;i++) acc[i] = (floatx4){0.f,0.f,0.f,0.f};

  #pragma unroll
  for (int kt=0; kt<KK; kt+=64){
    if constexpr (BF16A){
      const unsigned short* A = (const unsigned short*)jb.A;
      #pragma unroll
      for (int i=0;i<2;i++){
        int li = t + i*256;
        int r = li >> 3, c8 = (li & 7)*8;
        short8 v = {0,0,0,0,0,0,0,0};
        if (m0 + r < M) v = *(const short8*)(A + (size_t)(m0+r)*KK + kt + c8);
        *(short8*)&Ah[r*72 + c8] = v;
      }
    } else {
      const float* A = (const float*)jb.A;
      #pragma unroll
      for (int i=0;i<4;i++){
        int li = t + i*256;
        int r = li >> 4, c4 = (li & 15)*4;
        float4 v = make_float4(0.f,0.f,0.f,0.f);
        if (m0 + r < M) v = *(const float4*)(A + (size_t)(m0+r)*KK + kt + c4);
        unsigned short h0,h1,h2,h3,g0,g1,g2,g3;
        split_bf(v.x,h0,g0); split_bf(v.y,h1,g1);
        split_bf(v.z,h2,g2); split_bf(v.w,h3,g3);
        uint2 ph = { (unsigned)h0 | ((unsigned)h1<<16), (unsigned)h2 | ((unsigned)h3<<16) };
        uint2 pl = { (unsigned)g0 | ((unsigned)g1<<16), (unsigned)g2 | ((unsigned)g3<<16) };
        *(uint2*)&Ah[r*72 + c4] = ph;
        *(uint2*)&Al[r*72 + c4] = pl;
      }
    }
    // B-stage: pure copy of preconverted bf16 hi/lo (16B chunks).
    for (int c = t; c < TN*8; c += 256){
      int n  = c >> 3;
      int k8 = (c & 7) * 8;
      *(short8*)&Bh[n*72 + k8] =
          *(const short8*)(jb.Wth + (size_t)(n0 + n)*KK + kt + k8);
      *(short8*)&Bl[n*72 + k8] =
          *(const short8*)(jb.Wtl + (size_t)(n0 + n)*KK + kt + k8);
    }
    __syncthreads();
    #pragma unroll
    for (int ks=0; ks<2; ks++){
      const int koff = ks*32 + lq*8;
      short8 a_h = *(const short8*)&Ah[(wv*16+lr)*72 + koff];
      short8 a_l;
      if constexpr (!BF16A) a_l = *(const short8*)&Al[(wv*16+lr)*72 + koff];
      #pragma unroll
      for (int nt=0; nt<NT; nt++){
        short8 b_h = *(const short8*)&Bh[(nt*16+lr)*72 + koff];
        short8 b_l = *(const short8*)&Bl[(nt*16+lr)*72 + koff];
        acc[nt] = __builtin_amdgcn_mfma_f32_16x16x32_bf16(a_h, b_h, acc[nt], 0,0,0);
        acc[nt] = __builtin_amdgcn_mfma_f32_16x16x32_bf16(a_h, b_l, acc[nt], 0,0,0);
        if constexpr (!BF16A)
          acc[nt] = __builtin_amdgcn_mfma_f32_16x16x32_bf16(a_l, b_h, acc[nt], 0,0,0);
      }
    }
    __syncthreads();
  }
  float ls[LOGIT ? 4 : 1][LOGIT ? 4 : 1];   // [r][h]
  float ld_[LOGIT ? 4 : 1][LOGIT ? 4 : 1];
  if constexpr (LOGIT){
    #pragma unroll
    for (int r=0;r<4;r++)
      #pragma unroll
      for (int h=0;h<4;h++){ ls[r][h]=0.f; ld_[r][h]=0.f; }
  }
  #pragma unroll
  for (int nt=0; nt<NT; nt++){
    int n = n0 + nt*16 + lr;
    float bv = jb.bias ? jb.bias[n] : 0.f;
    #pragma unroll
    for (int r=0;r<4;r++){
      int m = m0 + wv*16 + lq*4 + r;
      if (m < M){
        float o = acc[nt][r] + bv;
        if (ELU) o = elu_f(o);
        if constexpr (LG){
          if (n < 32)       ((unsigned short*)jb.C)[(size_t)m*32 + n] = f2bf(o);
          else if (n == 32) jb.outA[m] = o;
          else if (n == 33) jb.outB[m] = o;
        } else {
          if (BF16OUT) ((unsigned short*)jb.C)[(size_t)m*N + n] = f2bf(o);
          else         ((float*)jb.C)[(size_t)m*N + n] = o;
        }
        if constexpr (LOGIT){
          #pragma unroll
          for (int h=0;h<4;h++){
            ls[r][h]  = fmaf(o, CwS[h*64 + n], ls[r][h]);
            ld_[r][h] = fmaf(o, CwD[h*64 + n], ld_[r][h]);
          }
        }
      }
    }
  }
  if constexpr (LOGIT){
    // reduce over the 16 lr-lanes (channels), then lane lr==0 writes 4 rows x 4 heads
    #pragma unroll
    for (int r=0;r<4;r++)
      #pragma unroll
      for (int h=0;h<4;h++){
        float a = ls[r][h], d = ld_[r][h];
        #pragma unroll
        for (int off=1; off<16; off<<=1){
          a += __shfl_xor(a, off, 64);
          d += __shfl_xor(d, off, 64);
        }
        ls[r][h]=a; ld_[r][h]=d;
      }
    if (lr == 0){
      #pragma unroll
      for (int r=0;r<4;r++){
        int m = m0 + wv*16 + lq*4 + r;
        if (m < M){
          #pragma unroll
          for (int h=0;h<4;h++){
            jb.outA[(size_t)m*4 + h] = ls[r][h];
            jb.outB[(size_t)m*4 + h] = ld_[r][h];
          }
        }
      }
    }
  }
}

// ---------------- fused layer-0 head GEMMs + layer-1 feature GEMM ----------------
// Interleaved per-head schedule (round-13 proven, 36.9KB LDS, scalar H1 stores).
struct FsJob {
  const unsigned short* A;            // agg bf16 [M,256]
  const unsigned short* W0h;          // [256][64] l0 Ws transposed hi
  const unsigned short* W0l;          //             lo
  const float* den;                   // [M,4]
  const float* b0;                    // [256] l0 bias
  const unsigned short* Wch;          // [48][256] Wc transposed hi
  const unsigned short* Wcl;          //             lo
  unsigned short* hs1;                // bf16 [M,32]
  float* outA; float* outB;           // layer-1 logits [M]
};
__global__ __launch_bounds__(256) void l0l1_kernel(FsJob j0, FsJob j1, int M){
  const FsJob jb = blockIdx.z ? j1 : j0;
  __shared__ __align__(16) unsigned short H1[64*72];    // current head's hi1 slice
  __shared__ __align__(16) unsigned short Sa[64*72];
  __shared__ __align__(16) unsigned short Sbh[64*72];
  __shared__ __align__(16) unsigned short Sbl[64*72];
  const int t = threadIdx.x;
  const int m0 = blockIdx.x*64;
  const int wv = t>>6, l = t&63;
  const int lr = l&15, lq = l>>4;
  floatx4 acc2[3];
  #pragma unroll
  for (int i=0;i<3;i++) acc2[i] = (floatx4){0.f,0.f,0.f,0.f};

  for (int h=0; h<4; ++h){
    // stage A head slice + W0 head slice
    #pragma unroll
    for (int i=0;i<2;i++){
      int li = t + i*256;
      int r = li >> 3, c8 = (li & 7)*8;
      short8 v = {0,0,0,0,0,0,0,0};
      if (m0 + r < M) v = *(const short8*)(jb.A + (size_t)(m0+r)*256 + h*64 + c8);
      *(short8*)&Sa[r*72 + c8] = v;
    }
    #pragma unroll
    for (int i=0;i<2;i++){
      int c  = t + i*256;
      int n  = c >> 3;
      int k8 = (c & 7) * 8;
      *(short8*)&Sbh[n*72 + k8] =
          *(const short8*)(jb.W0h + (size_t)(h*64 + n)*64 + k8);
      *(short8*)&Sbl[n*72 + k8] =
          *(const short8*)(jb.W0l + (size_t)(h*64 + n)*64 + k8);
    }
    __syncthreads();
    // head GEMM
    floatx4 acc[4];
    #pragma unroll
    for (int i=0;i<4;i++) acc[i] = (floatx4){0.f,0.f,0.f,0.f};
    #pragma unroll
    for (int ks=0; ks<2; ks++){
      const int koff = ks*32 + lq*8;
      short8 a_h = *(const short8*)&Sa[(wv*16+lr)*72 + koff];
      #pragma unroll
      for (int nt=0; nt<4; nt++){
        short8 b_h = *(const short8*)&Sbh[(nt*16+lr)*72 + koff];
        short8 b_l = *(const short8*)&Sbl[(nt*16+lr)*72 + koff];
        acc[nt] = __builtin_amdgcn_mfma_f32_16x16x32_bf16(a_h, b_h, acc[nt], 0,0,0);
        acc[nt] = __builtin_amdgcn_mfma_f32_16x16x32_bf16(a_h, b_l, acc[nt], 0,0,0);
      }
    }
    float inv[4];
    #pragma unroll
    for (int r=0;r<4;r++){
      int m = m0 + wv*16 + lq*4 + r;
      inv[r] = (m < M) ? 1.f/(jb.den[(size_t)m*4 + h] + 1e-16f) : 0.f;
    }
    #pragma unroll
    for (int nt=0; nt<4; nt++){
      int col = nt*16 + lr;
      float bv = jb.b0[h*64 + col];
      #pragma unroll
      for (int r=0;r<4;r++){
        int mrow = wv*16 + lq*4 + r;
        H1[mrow*72 + col] = f2bf(elu_f(acc[nt][r]*inv[r] + bv));
      }
    }
    __syncthreads();   // H1 written; W0 reads complete -> Sb reusable
    // stage Wc K-slice kt=h
    for (int c = t; c < 48*8; c += 256){
      int n  = c >> 3;
      int k8 = (c & 7) * 8;
      *(short8*)&Sbh[n*72 + k8] =
          *(const short8*)(jb.Wch + (size_t)n*256 + h*64 + k8);
      *(short8*)&Sbl[n*72 + k8] =
          *(const short8*)(jb.Wcl + (size_t)n*256 + h*64 + k8);
    }
    __syncthreads();
    // accumulate layer-1 K-slice
    #pragma unroll
    for (int ks=0; ks<2; ks++){
      const int koff = ks*32 + lq*8;
      short8 a_h = *(const short8*)&H1[(wv*16+lr)*72 + koff];
      #pragma unroll
      for (int nt=0; nt<3; nt++){
        short8 b_h = *(const short8*)&Sbh[(nt*16+lr)*72 + koff];
        short8 b_l = *(const short8*)&Sbl[(nt*16+lr)*72 + koff];
        acc2[nt] = __builtin_amdgcn_mfma_f32_16x16x32_bf16(a_h, b_h, acc2[nt], 0,0,0);
        acc2[nt] = __builtin_amdgcn_mfma_f32_16x16x32_bf16(a_h, b_l, acc2[nt], 0,0,0);
      }
    }
    __syncthreads();   // H1/Sb reads complete -> reusable next head
  }
  // epilogue: cols 0..31 -> hs1 bf16, col 32 -> outA, col 33 -> outB
  #pragma unroll
  for (int nt=0; nt<3; nt++){
    int n = nt*16 + lr;
    #pragma unroll
    for (int r=0;r<4;r++){
      int m = m0 + wv*16 + lq*4 + r;
      if (m < M){
        float o = acc2[nt][r];
        if (n < 32)       jb.hs1[(size_t)m*32 + n] = f2bf(o);
        else if (n == 32) jb.outA[m] = o;
        else if (n == 33) jb.outB[m] = o;
      }
    }
  }
}

// ---------------- layer-0 pre-aggregation over hu/hi rows ----------------
// 8 dsts per wave, 8 lanes per dst, 8 channels per lane; edge-sum fully
// within-lane. Unroll-8 edge loop: 8 x-row gathers in flight per iteration
// (round-9's unroll-4 deepened; accumulation pair order preserved).
struct AggPJob {
  const int* offs; const int* ssrc;
  const unsigned short* x;     // bf16 [NN,64]
  const unsigned short* coef;  // bf16 [E,4]
  unsigned short* agg;         // bf16 [NN,256]
  float* den;                  // fp32 [NN,4]
};
__global__ __launch_bounds__(256) void aggpre_kernel(AggPJob ja, AggPJob jbb){
  const AggPJob jb = blockIdx.y ? jbb : ja;
  const int tid = threadIdx.x;
  const int lane = tid & 63, wid = tid >> 6;
  const int grp = lane >> 3;       // dst group within wave (0..7)
  const int cl  = lane & 7;        // channel lane within group
  const int c8  = cl * 8;          // channel base (8 bf16 = 16B per lane)
  const int dst = blockIdx.x*32 + wid*8 + grp;
  if (dst >= NN) return;
  const int b0 = jb.offs[dst], b1 = jb.offs[dst+1];
  float acc[4][8];
  float den[4] = {0.f,0.f,0.f,0.f};
  #pragma unroll
  for (int h=0;h<4;h++)
    #pragma unroll
    for (int c=0;c<8;c++) acc[h][c]=0.f;
  int e = b0;
  // unroll-8: batch 8 independent x gathers + coef loads per iteration
  for (; e+7 < b1; e += 8){
    int s0 = jb.ssrc[e];
    int s1 = jb.ssrc[e+1];
    int s2 = jb.ssrc[e+2];
    int s3 = jb.ssrc[e+3];
    int s4 = jb.ssrc[e+4];
    int s5 = jb.ssrc[e+5];
    int s6 = jb.ssrc[e+6];
    int s7 = jb.ssrc[e+7];
    uint4 q0 = *(const uint4*)(jb.x + ((size_t)s0<<6) + c8);
    uint4 q1 = *(const uint4*)(jb.x + ((size_t)s1<<6) + c8);
    uint4 q2 = *(const uint4*)(jb.x + ((size_t)s2<<6) + c8);
    uint4 q3 = *(const uint4*)(jb.x + ((size_t)s3<<6) + c8);
    uint4 q4 = *(const uint4*)(jb.x + ((size_t)s4<<6) + c8);
    uint4 q5 = *(const uint4*)(jb.x + ((size_t)s5<<6) + c8);
    uint4 q6 = *(const uint4*)(jb.x + ((size_t)s6<<6) + c8);
    uint4 q7 = *(const uint4*)(jb.x + ((size_t)s7<<6) + c8);
    uint2 w0 = *(const uint2*)(jb.coef + (size_t)e*4);
    uint2 w1 = *(const uint2*)(jb.coef + (size_t)(e+1)*4);
    uint2 w2 = *(const uint2*)(jb.coef + (size_t)(e+2)*4);
    uint2 w3 = *(const uint2*)(jb.coef + (size_t)(e+3)*4);
    uint2 w4 = *(const uint2*)(jb.coef + (size_t)(e+4)*4);
    uint2 w5 = *(const uint2*)(jb.coef + (size_t)(e+5)*4);
    uint2 w6 = *(const uint2*)(jb.coef + (size_t)(e+6)*4);
    uint2 w7 = *(const uint2*)(jb.coef + (size_t)(e+7)*4);
    agg_pair(acc, den, q0, q1, w0, w1);
    agg_pair(acc, den, q2, q3, w2, w3);
    agg_pair(acc, den, q4, q5, w4, w5);
    agg_pair(acc, den, q6, q7, w6, w7);
  }
  if (e+3 < b1){
    int s0 = jb.ssrc[e];
    int s1 = jb.ssrc[e+1];
    int s2 = jb.ssrc[e+2];
    int s3 = jb.ssrc[e+3];
    uint4 q0 = *(const uint4*)(jb.x + ((size_t)s0<<6) + c8);
    uint4 q1 = *(const uint4*)(jb.x + ((size_t)s1<<6) + c8);
    uint4 q2 = *(const uint4*)(jb.x + ((size_t)s2<<6) + c8);
    uint4 q3 = *(const uint4*)(jb.x + ((size_t)s3<<6) + c8);
    uint2 w0 = *(const uint2*)(jb.coef + (size_t)e*4);
    uint2 w1 = *(const uint2*)(jb.coef + (size_t)(e+1)*4);
    uint2 w2 = *(const uint2*)(jb.coef + (size_t)(e+2)*4);
    uint2 w3 = *(const uint2*)(jb.coef + (size_t)(e+3)*4);
    agg_pair(acc, den, q0, q1, w0, w1);
    agg_pair(acc, den, q2, q3, w2, w3);
    e += 4;
  }
  if (e+1 < b1){
    int s0 = jb.ssrc[e];
    int s1 = jb.ssrc[e+1];
    uint4 q0 = *(const uint4*)(jb.x + ((size_t)s0<<6) + c8);
    uint4 q1 = *(const uint4*)(jb.x + ((size_t)s1<<6) + c8);
    uint2 w0 = *(const uint2*)(jb.coef + (size_t)e*4);
    uint2 w1 = *(const uint2*)(jb.coef + (size_t)(e+1)*4);
    agg_pair(acc, den, q0, q1, w0, w1);
    e += 2;
  }
  if (e < b1){  // odd-degree tail: single edge, scalar path
    int s = jb.ssrc[e];
    uint4 q = *(const uint4*)(jb.x + ((size_t)s<<6) + c8);
    uint2 w = *(const uint2*)(jb.coef + (size_t)e*4);
    float wf[4] = { bf2f(w.x & 0xffffu), bf2f(w.x >> 16),
                    bf2f(w.y & 0xffffu), bf2f(w.y >> 16) };
    float xf[8] = { bf2f(q.x & 0xffffu), bf2f(q.x >> 16),
                    bf2f(q.y & 0xffffu), bf2f(q.y >> 16),
                    bf2f(q.z & 0xffffu), bf2f(q.z >> 16),
                    bf2f(q.w & 0xffffu), bf2f(q.w >> 16) };
    #pragma unroll
    for (int h=0;h<4;h++){
      den[h] += wf[h];
      #pragma unroll
      for (int c=0;c<8;c++) acc[h][c] += wf[h]*xf[c];
    }
  }
  // epilogue: pack + store only (no shuffles)
  #pragma unroll
  for (int h=0;h<4;h++){
    uint2 plo = bf4_pack(make_float4(acc[h][0],acc[h][1],acc[h][2],acc[h][3]));
    uint2 phi = bf4_pack(make_float4(acc[h][4],acc[h][5],acc[h][6],acc[h][7]));
    uint4 pk = { plo.x, plo.y, phi.x, phi.y };
    *(uint4*)(jb.agg + (size_t)dst*256 + h*64 + c8) = pk;
  }
  if (cl == 0)
    *(float4*)(jb.den + (size_t)dst*4) = make_float4(den[0],den[1],den[2],den[3]);
}

// ---------------- layer-1 aggregation (aggpre-style: 8 dst/wave, shuffle-free) ----
// Unroll-8 edge loop for gather MLP depth.
struct Agg1Job {
  const int* offs; const int* ssrc;
  const unsigned short* hs;   // bf16 [NN,32]
  const float* als; const float* ald;  // layer-1 logits
  const float* bias; float* out;
};
__global__ __launch_bounds__(256) void agg1_kernel(Agg1Job ja, Agg1Job jbb){
  const Agg1Job jb = blockIdx.y ? jbb : ja;
  const int tid = threadIdx.x;
  const int lane = tid & 63, wid = tid >> 6;
  const int grp = lane >> 3;       // dst group within wave (0..7)
  const int cl  = lane & 7;        // col lane within group
  const int c4  = cl * 4;          // col base (4 f32 outputs per lane)
  const int dst = blockIdx.x*32 + wid*8 + grp;
  if (dst >= NN) return;
  const int b0 = jb.offs[dst], b1 = jb.offs[dst+1];
  const float ad = jb.ald[dst];
  float acc[4] = {0.f,0.f,0.f,0.f};
  float den = 0.f;
  int e = b0;
  for (; e+7 < b1; e += 8){
    int s0 = jb.ssrc[e];
    int s1 = jb.ssrc[e+1];
    int s2 = jb.ssrc[e+2];
    int s3 = jb.ssrc[e+3];
    int s4 = jb.ssrc[e+4];
    int s5 = jb.ssrc[e+5];
    int s6 = jb.ssrc[e+6];
    int s7 = jb.ssrc[e+7];
    float a0 = jb.als[s0];
    float a1 = jb.als[s1];
    float a2 = jb.als[s2];
    float a3 = jb.als[s3];
    float a4 = jb.als[s4];
    float a5 = jb.als[s5];
    float a6 = jb.als[s6];
    float a7 = jb.als[s7];
    float4 v0 = bf4_load(jb.hs + ((size_t)s0<<5) + c4);
    float4 v1 = bf4_load(jb.hs + ((size_t)s1<<5) + c4);
    float4 v2 = bf4_load(jb.hs + ((size_t)s2<<5) + c4);
    float4 v3 = bf4_load(jb.hs + ((size_t)s3<<5) + c4);
    float4 v4 = bf4_load(jb.hs + ((size_t)s4<<5) + c4);
    float4 v5 = bf4_load(jb.hs + ((size_t)s5<<5) + c4);
    float4 v6 = bf4_load(jb.hs + ((size_t)s6<<5) + c4);
    float4 v7 = bf4_load(jb.hs + ((size_t)s7<<5) + c4);
    float w0 = __expf(lrelu_f(a0 + ad));
    float w1 = __expf(lrelu_f(a1 + ad));
    float w2 = __expf(lrelu_f(a2 + ad));
    float w3 = __expf(lrelu_f(a3 + ad));
    float w4 = __expf(lrelu_f(a4 + ad));
    float w5 = __expf(lrelu_f(a5 + ad));
    float w6 = __expf(lrelu_f(a6 + ad));
    float w7 = __expf(lrelu_f(a7 + ad));
    acc[0] += w0*v0.x + w1*v1.x + w2*v2.x + w3*v3.x;
    acc[1] += w0*v0.y + w1*v1.y + w2*v2.y + w3*v3.y;
    acc[2] += w0*v0.z + w1*v1.z + w2*v2.z + w3*v3.z;
    acc[3] += w0*v0.w + w1*v1.w + w2*v2.w + w3*v3.w;
    acc[0] += w4*v4.x + w5*v5.x + w6*v6.x + w7*v7.x;
    acc[1] += w4*v4.y + w5*v5.y + w6*v6.y + w7*v7.y;
    acc[2] += w4*v4.z + w5*v5.z + w6*v6.z + w7*v7.z;
    acc[3] += w4*v4.w + w5*v5.w + w6*v6.w + w7*v7.w;
    den += (w0 + w1) + (w2 + w3);
    den += (w4 + w5) + (w6 + w7);
  }
  for (; e+3 < b1; e += 4){
    int s0 = jb.ssrc[e];
    int s1 = jb.ssrc[e+1];
    int s2 = jb.ssrc[e+2];
    int s3 = jb.ssrc[e+3];
    float a0 = jb.als[s0];
    float a1 = jb.als[s1];
    float a2 = jb.als[s2];
    float a3 = jb.als[s3];
    float4 v0 = bf4_load(jb.hs + ((size_t)s0<<5) + c4);
    float4 v1 = bf4_load(jb.hs + ((size_t)s1<<5) + c4);
    float4 v2 = bf4_load(jb.hs + ((size_t)s2<<5) + c4);
    float4 v3 = bf4_load(jb.hs + ((size_t)s3<<5) + c4);
    float w0 = __expf(lrelu_f(a0 + ad));
    float w1 = __expf(lrelu_f(a1 + ad));
    float w2 = __expf(lrelu_f(a2 + ad));
    float w3 = __expf(lrelu_f(a3 + ad));
    acc[0] += w0*v0.x + w1*v1.x + w2*v2.x + w3*v3.x;
    acc[1] += w0*v0.y + w1*v1.y + w2*v2.y + w3*v3.y;
    acc[2] += w0*v0.z + w1*v1.z + w2*v2.z + w3*v3.z;
    acc[3] += w0*v0.w + w1*v1.w + w2*v2.w + w3*v3.w;
    den += (w0 + w1) + (w2 + w3);
  }
  for (; e < b1; ++e){
    int s = jb.ssrc[e];
    float w = __expf(lrelu_f(jb.als[s] + ad));
    float4 v = bf4_load(jb.hs + ((size_t)s<<5) + c4);
    acc[0] += w*v.x; acc[1] += w*v.y; acc[2] += w*v.z; acc[3] += w*v.w;
    den += w;
  }
  const float inv = 1.f/(den + 1e-16f);
  float4 b = *(const float4*)(jb.bias + c4);
  float4 o = make_float4(acc[0]*inv+b.x, acc[1]*inv+b.y,
                         acc[2]*inv+b.z, acc[3]*inv+b.w);
  *(float4*)(jb.out + (size_t)dst*32 + c4) = o;
}

// ---------------- host glue ----------------
extern "C" void kernel_launch(void* const* d_in, const int* in_sizes, int n_in,
                              void* d_out, int out_size, void* d_ws, size_t ws_size,
                              hipStream_t stream)
{
  (void)in_sizes; (void)n_in; (void)out_size; (void)ws_size;
  const float* x_user   = (const float*)d_in[0];
  const float* x_item   = (const float*)d_in[1];
  const int*   e_u2i    = (const int*)  d_in[2];
  const int*   e_i2u    = (const int*)  d_in[3];
  const float* p_user_w = (const float*)d_in[4];
  const float* p_user_b = (const float*)d_in[5];
  const float* p_item_w = (const float*)d_in[6];
  const float* p_item_b = (const float*)d_in[7];
  const float* l0_u2i_ws=(const float*)d_in[8];
  const float* l0_u2i_wd=(const float*)d_in[9];
  const float* l0_u2i_as=(const float*)d_in[10];
  const float* l0_u2i_ad=(const float*)d_in[11];
  const float* l0_u2i_b =(const float*)d_in[12];
  const float* l0_i2u_ws=(const float*)d_in[13];
  const float* l0_i2u_wd=(const float*)d_in[14];
  const float* l0_i2u_as=(const float*)d_in[15];
  const float* l0_i2u_ad=(const float*)d_in[16];
  const float* l0_i2u_b =(const float*)d_in[17];
  const float* l1_u2i_ws=(const float*)d_in[18];
  const float* l1_u2i_wd=(const float*)d_in[19];
  const float* l1_u2i_as=(const float*)d_in[20];
  const float* l1_u2i_ad=(const float*)d_in[21];
  const float* l1_u2i_b =(const float*)d_in[22];
  const float* l1_i2u_ws=(const float*)d_in[23];
  const float* l1_i2u_wd=(const float*)d_in[24];
  const float* l1_i2u_as=(const float*)d_in[25];
  const float* l1_i2u_ad=(const float*)d_in[26];
  const float* l1_i2u_b =(const float*)d_in[27];

  char* base = (char*)d_ws;
  size_t off = 0;
  auto alloc = [&](size_t bytes)->void*{
    void* p = base + off;
    off += (bytes + 255) & ~(size_t)255;
    return p;
  };
  int* offs_u2i = (int*)alloc((size_t)(NN+1)*sizeof(int));
  int* offs_i2u = (int*)alloc((size_t)(NN+1)*sizeof(int));
  int* ssrc_u2i = (int*)alloc((size_t)NE*sizeof(int));
  int* ssrc_i2u = (int*)alloc((size_t)NE*sizeof(int));
  int* ghist    = (int*)alloc((size_t)2*200*sizeof(int));
  int* gbase    = (int*)alloc((size_t)2*200*sizeof(int));
  int* gcur     = (int*)alloc((size_t)2*200*sizeof(int));
  unsigned short* coef0_u2i = (unsigned short*)alloc((size_t)NE*4*sizeof(unsigned short));
  unsigned short* coef0_i2u = (unsigned short*)alloc((size_t)NE*4*sizeof(unsigned short));
  unsigned short* hu = (unsigned short*)alloc((size_t)NN*64*sizeof(unsigned short));
  unsigned short* hi = (unsigned short*)alloc((size_t)NN*64*sizeof(unsigned short));
  unsigned short* agg_u2i = (unsigned short*)alloc((size_t)NN*256*sizeof(unsigned short));
  unsigned short* agg_i2u = (unsigned short*)alloc((size_t)NN*256*sizeof(unsigned short));
  float* den_u2i = (float*)alloc((size_t)NN*4*sizeof(float));
  float* den_i2u = (float*)alloc((size_t)NN*4*sizeof(float));
  unsigned short* hu1 = (unsigned short*)alloc((size_t)NN*256*sizeof(unsigned short));
  unsigned short* hi1 = (unsigned short*)alloc((size_t)NN*256*sizeof(unsigned short));
  unsigned short* hs1_u2i = (unsigned short*)alloc((size_t)NN*32*sizeof(unsigned short));
  unsigned short* hs1_i2u = (unsigned short*)alloc((size_t)NN*32*sizeof(unsigned short));
  float* als0_u2i = (float*)alloc((size_t)NN*4*sizeof(float));
  float* ald0_u2i = (float*)alloc((size_t)NN*4*sizeof(float));
  float* als0_i2u = (float*)alloc((size_t)NN*4*sizeof(float));
  float* ald0_i2u = (float*)alloc((size_t)NN*4*sizeof(float));
  float* als1_u2i = (float*)alloc((size_t)NN*sizeof(float));
  float* ald1_u2i = (float*)alloc((size_t)NN*sizeof(float));
  float* als1_i2u = (float*)alloc((size_t)NN*sizeof(float));
  float* ald1_i2u = (float*)alloc((size_t)NN*sizeof(float));
  float* cw0s_u2i = (float*)alloc(256*sizeof(float));
  float* cw0d_u2i = (float*)alloc(256*sizeof(float));
  float* cw0s_i2u = (float*)alloc(256*sizeof(float));
  float* cw0d_i2u = (float*)alloc(256*sizeof(float));
  // transposed bf16 hi/lo weight images
  unsigned short* wt_pu_h  = (unsigned short*)alloc((size_t)64*128*sizeof(unsigned short));
  unsigned short* wt_pu_l  = (unsigned short*)alloc((size_t)64*128*sizeof(unsigned short));
  unsigned short* wt_pi_h  = (unsigned short*)alloc((size_t)64*128*sizeof(unsigned short));
  unsigned short* wt_pi_l  = (unsigned short*)alloc((size_t)64*128*sizeof(unsigned short));
  unsigned short* wt_l0u_h = (unsigned short*)alloc((size_t)256*64*sizeof(unsigned short));
  unsigned short* wt_l0u_l = (unsigned short*)alloc((size_t)256*64*sizeof(unsigned short));
  unsigned short* wt_l0i_h = (unsigned short*)alloc((size_t)256*64*sizeof(unsigned short));
  unsigned short* wt_l0i_l = (unsigned short*)alloc((size_t)256*64*sizeof(unsigned short));
  unsigned short* wt_wcu_h = (unsigned short*)alloc((size_t)48*256*sizeof(unsigned short));
  unsigned short* wt_wcu_l = (unsigned short*)alloc((size_t)48*256*sizeof(unsigned short));
  unsigned short* wt_wci_h = (unsigned short*)alloc((size_t)48*256*sizeof(unsigned short));
  unsigned short* wt_wci_l = (unsigned short*)alloc((size_t)48*256*sizeof(unsigned short));
  // pairs scratch aliases hu1/hi1: consumed by part2 (hu1/hi1 now LDS-only)
  int2* pairs_u2i = (int2*)hu1;
  int2* pairs_i2u = pairs_u2i + NE;

  const int GM = (NN + 63)/64;

  // ---- bucket sort stage A ----
  hipMemsetAsync(ghist, 0, (size_t)2*200*sizeof(int), stream);
  ghist_kernel<<<dim3(256,2), 256, 0, stream>>>(e_u2i, e_i2u, ghist);
  gscan_kernel<<<1, 256, 0, stream>>>(ghist, gbase, gcur);
  part1_kernel<<<dim3((NE+TILE1-1)/TILE1,2), 256, 0, stream>>>(
      e_u2i, e_i2u, gcur, pairs_u2i, pairs_i2u);

  // ---- weight prep (transposes + Wc builds with inline dots + cw0 collapses) ----
  WcvArgs wa;
  wa.j[0] = {p_user_w,  nullptr, nullptr, nullptr, wt_pu_h,  wt_pu_l,  nullptr, 128, 64, 0};
  wa.j[1] = {p_item_w,  nullptr, nullptr, nullptr, wt_pi_h,  wt_pi_l,  nullptr, 128, 64, 0};
  wa.j[2] = {l0_u2i_ws, nullptr, nullptr, nullptr, wt_l0u_h, wt_l0u_l, nullptr, 64, 256, 0};
  wa.j[3] = {l0_i2u_ws, nullptr, nullptr, nullptr, wt_l0i_h, wt_l0i_l, nullptr, 64, 256, 0};
  // Wc_u2i: cols 0..31 = l1_u2i_ws; col32 = dot(l1_u2i_ws[k], l1_u2i_as);
  //         col33 = dot(l1_i2u_wd[k], l1_i2u_ad)
  wa.j[4] = {l1_u2i_ws, l1_u2i_as, l1_i2u_wd, l1_i2u_ad, wt_wcu_h, wt_wcu_l, nullptr, 256, 48, 1};
  wa.j[5] = {l1_i2u_ws, l1_i2u_as, l1_u2i_wd, l1_u2i_ad, wt_wci_h, wt_wci_l, nullptr, 256, 48, 1};
  // cw0 collapses (f32 out, [H=4][K=64], sequential-c sum = old collapse)
  wa.j[6] = {l0_u2i_ws, l0_u2i_as, nullptr, nullptr, nullptr, nullptr, cw0s_u2i, 64, 4, 2};
  wa.j[7] = {l0_u2i_wd, l0_u2i_ad, nullptr, nullptr, nullptr, nullptr, cw0d_u2i, 64, 4, 2};
  wa.j[8] = {l0_i2u_ws, l0_i2u_as, nullptr, nullptr, nullptr, nullptr, cw0s_i2u, 64, 4, 2};
  wa.j[9] = {l0_i2u_wd, l0_i2u_ad, nullptr, nullptr, nullptr, nullptr, cw0d_i2u, 64, 4, 2};
  wconv_kernel<<<dim3(64,10), 256, 0, stream>>>(wa);

  // ---- input projections (+bias +ELU) -> bf16, with fused layer-0 logits ----
  mgemm_kernel<4,128,true,true,false,false,true><<<dim3(GM,1,2), 256, 0, stream>>>(
      MgJob{x_user, wt_pu_h, wt_pu_l, p_user_b, hu, als0_u2i, ald0_i2u, cw0s_u2i, cw0d_i2u},
      MgJob{x_item, wt_pi_h, wt_pi_l, p_item_b, hi, als0_i2u, ald0_u2i, cw0s_i2u, cw0d_u2i},
      NN, 64);

  // ---- bucket sort stage B ----
  part2_kernel<<<dim3(GB,2), 256, 0, stream>>>(
      Part2Job{pairs_u2i, gbase,       als0_u2i, ald0_u2i, ssrc_u2i, offs_u2i, coef0_u2i},
      Part2Job{pairs_i2u, gbase + 200, als0_i2u, ald0_i2u, ssrc_i2u, offs_i2u, coef0_i2u});

  // ---- layer 0: pre-aggregate hu/hi rows (8 dst/wave, unroll-8 gathers) ----
  aggpre_kernel<<<dim3((NN+31)/32,2), 256, 0, stream>>>(
      AggPJob{offs_u2i, ssrc_u2i, hu, coef0_u2i, agg_u2i, den_u2i},
      AggPJob{offs_i2u, ssrc_i2u, hi, coef0_i2u, agg_i2u, den_i2u});

  // ---- fused layer-0 head GEMMs + layer-1 feature GEMM (interleaved per head) ----
  l0l1_kernel<<<dim3(GM,1,2), 256, 0, stream>>>(
      FsJob{agg_i2u, wt_l0i_h, wt_l0i_l, den_i2u, l0_i2u_b,
            wt_wcu_h, wt_wcu_l, hs1_u2i, als1_u2i, ald1_i2u},
      FsJob{agg_u2i, wt_l0u_h, wt_l0u_l, den_u2i, l0_u2i_b,
            wt_wci_h, wt_wci_l, hs1_i2u, als1_i2u, ald1_u2i},
      NN);

  // ---- layer 1: aggregate (+bias), shuffle-free 8 dst/wave, unroll-8 ----
  float* hu2 = (float*)d_out;                  // first tuple element (users, i2u dst)
  float* hi2 = (float*)d_out + (size_t)NN*32;  // second tuple element (items, u2i dst)
  agg1_kernel<<<dim3((NN+31)/32,2), 256, 0, stream>>>(
      Agg1Job{offs_u2i, ssrc_u2i, hs1_u2i, als1_u2i, ald1_u2i, l1_u2i_b, hi2},
      Agg1Job{offs_i2u, ssrc_i2u, hs1_i2u, als1_i2u, ald1_i2u, l1_i2u_b, hu2});
}